// Round 2
// baseline (23134.593 us; speedup 1.0000x reference)
//
#include <hip/hip_runtime.h>
#include <hip/hip_bf16.h>
#include <math.h>

#define NI 64
#define NC 64
#define NTOK 197
#define TT 196
#define CL 32
#define DD 1024
#define SS 256
#define NN 33
#define EPSN 1e-12f
#define SMOOTHF 9.0f

// LDS layout (byte offsets)
#define OFF_ATTN   0        // [196][33] f32
#define OFF_AK     25872    // [32][132] f32 (phase A)
#define OFF_CK     42768    // [32][36]  f32 (phase A)
#define OFF_WTILE  25872    // [32][132] f32 (phase W)
#define OFF_IMGK   42768    // [16][132] f32 (phase W)
#define OFF_SEA    0        // [33][260] f32 (SGR)
#define OFF_GB     34320    // [33][68]  f32 (SGR G/H tile)
#define OFF_EMAT   43296    // [33][36]  f32
#define OFF_VBUF   48048    // [33] f32
#define OFF_WKBQ   48192    // [256] f32
#define OFF_NB     51216    // [128] f32 (norm partials)
#define OFF_NRMS   51728    // [32] f32  (1/||ctx_q||)
#define SMEM_BYTES 51856

__device__ __forceinline__ float warp_reduce_sum64(float v) {
#pragma unroll
  for (int m = 32; m > 0; m >>= 1) v += __shfl_xor(v, m, 64);
  return v;
}

// ---------------------------------------------------------------- K1: means
__global__ void k_avg(const float* __restrict__ img, const float* __restrict__ cap,
                      float* __restrict__ img_avg, float* __restrict__ cap_avg) {
  int bid = blockIdx.x;
  int tid = threadIdx.x;
  if (bid < NI) {
    int b = bid;
    for (int d = tid; d < DD; d += 256) {
      float acc = 0.f;
      const float* p = img + ((size_t)b * NTOK + 1) * DD + d;
      for (int t = 0; t < TT; ++t) acc += p[(size_t)t * DD];
      img_avg[b * DD + d] = acc * (1.0f / TT);
    }
  } else {
    int c = bid - NI;
    for (int d = tid; d < DD; d += 256) {
      float acc = 0.f;
      const float* p = cap + (size_t)c * CL * DD + d;
      for (int t = 0; t < CL; ++t) acc += p[(size_t)t * DD];
      cap_avg[c * DD + d] = acc * (1.0f / CL);
    }
  }
}

// ------------------------------------------------- K2: h = tanh(avg@Wg+bg)*Wc
__global__ void k_hvec(const float* __restrict__ avg, const float* __restrict__ Wg,
                       const float* __restrict__ bg, const float* __restrict__ Wc,
                       float* __restrict__ h) {
  __shared__ float av[DD];
  int b = blockIdx.x >> 2;
  int dc = blockIdx.x & 3;
  int tid = threadIdx.x;
  for (int i = tid; i < DD; i += 256) av[i] = avg[b * DD + i];
  __syncthreads();
  int d = dc * 256 + tid;
  float acc = 0.f;
  for (int k = 0; k < DD; k += 4) {
    float4 a4 = *(const float4*)&av[k];
    acc += a4.x * Wg[(size_t)(k + 0) * DD + d];
    acc += a4.y * Wg[(size_t)(k + 1) * DD + d];
    acc += a4.z * Wg[(size_t)(k + 2) * DD + d];
    acc += a4.w * Wg[(size_t)(k + 3) * DD + d];
  }
  h[b * DD + d] = tanhf(acc + bg[d]) * Wc[d];
}

// ---------------- K3: partial[row,ct] = sum_{d in col-tile} tanh((A@Wl)[row,d]+bl)*h[b,d]
__global__ void k_logits_partial(const float* __restrict__ Abase, long batchStride, int rowsPerBatch,
                                 const float* __restrict__ Wl, const float* __restrict__ bl,
                                 const float* __restrict__ h, float* __restrict__ partial) {
  __shared__ float a_lds[32][68];
  __shared__ float b_lds[32][68];
  int tid = threadIdx.x;
  int rb = blockIdx.x * 64;
  int c0 = blockIdx.y * 64;
  int ty = tid >> 4, tx = tid & 15;
  int s_rr = tid >> 2, s_kq = tid & 3;
  int rA = rb + s_rr;
  const float* aRow = Abase + (size_t)(rA / rowsPerBatch) * batchStride + (size_t)(rA % rowsPerBatch) * DD;
  int s_kk = tid >> 3, s_cq = tid & 7;
  float acc[4][4] = {};
  for (int k0 = 0; k0 < DD; k0 += 32) {
    float4 v0 = *(const float4*)&aRow[k0 + s_kq * 8];
    float4 v1 = *(const float4*)&aRow[k0 + s_kq * 8 + 4];
    float4 w0 = *(const float4*)&Wl[(size_t)(k0 + s_kk) * DD + c0 + s_cq * 8];
    float4 w1 = *(const float4*)&Wl[(size_t)(k0 + s_kk) * DD + c0 + s_cq * 8 + 4];
    __syncthreads();
    float va[8] = {v0.x, v0.y, v0.z, v0.w, v1.x, v1.y, v1.z, v1.w};
#pragma unroll
    for (int u = 0; u < 8; ++u) a_lds[s_kq * 8 + u][s_rr] = va[u];
    *(float4*)&b_lds[s_kk][s_cq * 8] = w0;
    *(float4*)&b_lds[s_kk][s_cq * 8 + 4] = w1;
    __syncthreads();
#pragma unroll
    for (int kk = 0; kk < 32; ++kk) {
      float4 a4 = *(const float4*)&a_lds[kk][ty * 4];
      float4 b4 = *(const float4*)&b_lds[kk][tx * 4];
      float av[4] = {a4.x, a4.y, a4.z, a4.w};
      float bv[4] = {b4.x, b4.y, b4.z, b4.w};
#pragma unroll
      for (int i = 0; i < 4; ++i)
#pragma unroll
        for (int j = 0; j < 4; ++j) acc[i][j] += av[i] * bv[j];
    }
  }
#pragma unroll
  for (int i = 0; i < 4; ++i) {
    int r = rb + ty * 4 + i;
    int bb = r / rowsPerBatch;
    float s = 0.f;
#pragma unroll
    for (int j = 0; j < 4; ++j) {
      int cc = c0 + tx * 4 + j;
      s += tanhf(acc[i][j] + bl[cc]) * h[bb * DD + cc];
    }
    s += __shfl_xor(s, 1, 64);
    s += __shfl_xor(s, 2, 64);
    s += __shfl_xor(s, 4, 64);
    s += __shfl_xor(s, 8, 64);
    if (tx == 0) partial[(size_t)r * 16 + blockIdx.y] = s;
  }
}

// -------- K4: logits -> softmax weights -> weighted sum of tokens -> l2norm
__global__ void k_finish_global(const float* __restrict__ partial, const float* __restrict__ bc,
                                const float* __restrict__ Xbase, long batchStride, int R,
                                float* __restrict__ outG) {
  __shared__ float w[200];
  __shared__ float red[8];
  int b = blockIdx.x, tid = threadIdx.x;
  for (int t = tid; t < R; t += 256) {
    const float* pp = &partial[((size_t)b * R + t) * 16];
    float s = bc[0];
#pragma unroll
    for (int u = 0; u < 16; ++u) s += pp[u];
    w[t] = s;
  }
  __syncthreads();
  float m = -1e30f;
  for (int t = tid; t < R; t += 256) m = fmaxf(m, w[t]);
#pragma unroll
  for (int mm = 32; mm; mm >>= 1) m = fmaxf(m, __shfl_xor(m, mm, 64));
  if ((tid & 63) == 0) red[tid >> 6] = m;
  __syncthreads();
  m = fmaxf(fmaxf(red[0], red[1]), fmaxf(red[2], red[3]));
  __syncthreads();
  for (int t = tid; t < R; t += 256) w[t] = expf(w[t] - m);
  __syncthreads();
  const float* xb = Xbase + (size_t)b * batchStride;
  float acc[4];
  float ss = 0.f;
#pragma unroll
  for (int c4 = 0; c4 < 4; ++c4) {
    int d = tid + c4 * 256;
    float a = 0.f;
    for (int t = 0; t < R; ++t) a += w[t] * xb[(size_t)t * DD + d];
    acc[c4] = a;
    ss += a * a;
  }
  ss = warp_reduce_sum64(ss);
  if ((tid & 63) == 0) red[tid >> 6] = ss;
  __syncthreads();
  ss = red[0] + red[1] + red[2] + red[3];
  float rn = 1.0f / fmaxf(sqrtf(ss), EPSN);
#pragma unroll
  for (int c4 = 0; c4 < 4; ++c4) outG[(size_t)b * DD + tid + c4 * 256] = acc[c4] * rn;
}

// -------- K5: sim_glo[p] = l2norm((img_g[b]-cap_g[c])^2 @ W_glo + b_glo), p=b*64+c
__global__ void k_simglo(const float* __restrict__ ig, const float* __restrict__ cg,
                         const float* __restrict__ W, const float* __restrict__ bgl,
                         float* __restrict__ simglo) {
  __shared__ float a_lds[32][20];
  __shared__ float b_lds[32][260];
  int tid = threadIdx.x;
  int p0 = blockIdx.x * 16;
  int ty = tid >> 6, tx = tid & 63;
  int s_rr = tid >> 3, s_kq = tid & 7;
  float acc[4][4] = {};
  for (int k0 = 0; k0 < DD; k0 += 32) {
    float d2[4] = {};
    if (tid < 128) {
      int p = p0 + s_rr;
      int b = p >> 6, c = p & 63;
      float4 giv = *(const float4*)&ig[b * DD + k0 + s_kq * 4];
      float4 cgv = *(const float4*)&cg[c * DD + k0 + s_kq * 4];
      float dx = giv.x - cgv.x, dy = giv.y - cgv.y, dz = giv.z - cgv.z, dw = giv.w - cgv.w;
      d2[0] = dx * dx; d2[1] = dy * dy; d2[2] = dz * dz; d2[3] = dw * dw;
    }
    float4 wv[8];
#pragma unroll
    for (int u = 0; u < 8; ++u)
      wv[u] = *(const float4*)&W[(size_t)(k0 + s_rr) * SS + s_kq * 32 + u * 4];
    __syncthreads();
    if (tid < 128) {
#pragma unroll
      for (int u = 0; u < 4; ++u) a_lds[s_kq * 4 + u][s_rr] = d2[u];
    }
#pragma unroll
    for (int u = 0; u < 8; ++u)
      *(float4*)&b_lds[s_rr][s_kq * 32 + u * 4] = wv[u];
    __syncthreads();
#pragma unroll
    for (int kk = 0; kk < 32; ++kk) {
      float4 a4 = *(const float4*)&a_lds[kk][ty * 4];
      float4 b4 = *(const float4*)&b_lds[kk][tx * 4];
      float av[4] = {a4.x, a4.y, a4.z, a4.w};
      float bv[4] = {b4.x, b4.y, b4.z, b4.w};
#pragma unroll
      for (int i = 0; i < 4; ++i)
#pragma unroll
        for (int j = 0; j < 4; ++j) acc[i][j] += av[i] * bv[j];
    }
  }
#pragma unroll
  for (int i = 0; i < 4; ++i) {
    float v[4];
    float ssq = 0.f;
#pragma unroll
    for (int j = 0; j < 4; ++j) {
      v[j] = acc[i][j] + bgl[tx * 4 + j];
      ssq += v[j] * v[j];
    }
    ssq = warp_reduce_sum64(ssq);
    float rn = 1.0f / fmaxf(sqrtf(ssq), EPSN);
    int p = p0 + ty * 4 + i;
    *(float4*)&simglo[(size_t)p * SS + tx * 4] =
        make_float4(v[0] * rn, v[1] * rn, v[2] * rn, v[3] * rn);
  }
}

// -------- K6: M[t] = Wq_t @ Wk_t^T  (256x256)
__global__ void k_mmat(const float* __restrict__ Wq, const float* __restrict__ Wk,
                       float* __restrict__ M) {
  __shared__ float a_lds[32][68];
  __shared__ float b_lds[32][68];
  int tid = threadIdx.x;
  int t = blockIdx.x >> 4;
  int dt = (blockIdx.x >> 2) & 3, et = blockIdx.x & 3;
  int d0 = dt * 64, e0 = et * 64;
  const float* wq = Wq + (size_t)t * SS * SS;
  const float* wk = Wk + (size_t)t * SS * SS;
  int ty = tid >> 4, tx = tid & 15;
  int s_rr = tid >> 2, s_kq = tid & 3;
  float acc[4][4] = {};
  for (int j0 = 0; j0 < SS; j0 += 32) {
    float4 q0 = *(const float4*)&wq[(size_t)(d0 + s_rr) * SS + j0 + s_kq * 8];
    float4 q1 = *(const float4*)&wq[(size_t)(d0 + s_rr) * SS + j0 + s_kq * 8 + 4];
    float4 k0v = *(const float4*)&wk[(size_t)(e0 + s_rr) * SS + j0 + s_kq * 8];
    float4 k1v = *(const float4*)&wk[(size_t)(e0 + s_rr) * SS + j0 + s_kq * 8 + 4];
    __syncthreads();
    float qa[8] = {q0.x, q0.y, q0.z, q0.w, q1.x, q1.y, q1.z, q1.w};
    float ka[8] = {k0v.x, k0v.y, k0v.z, k0v.w, k1v.x, k1v.y, k1v.z, k1v.w};
#pragma unroll
    for (int u = 0; u < 8; ++u) {
      a_lds[s_kq * 8 + u][s_rr] = qa[u];
      b_lds[s_kq * 8 + u][s_rr] = ka[u];
    }
    __syncthreads();
#pragma unroll
    for (int kk = 0; kk < 32; ++kk) {
      float4 a4 = *(const float4*)&a_lds[kk][ty * 4];
      float4 b4 = *(const float4*)&b_lds[kk][tx * 4];
      float av[4] = {a4.x, a4.y, a4.z, a4.w};
      float bv[4] = {b4.x, b4.y, b4.z, b4.w};
#pragma unroll
      for (int i = 0; i < 4; ++i)
#pragma unroll
        for (int j = 0; j < 4; ++j) acc[i][j] += av[i] * bv[j];
    }
  }
#pragma unroll
  for (int i = 0; i < 4; ++i)
    *(float4*)&M[(size_t)t * SS * SS + (size_t)(d0 + ty * 4 + i) * SS + e0 + tx * 4] =
        make_float4(acc[i][0], acc[i][1], acc[i][2], acc[i][3]);
}

// -------- K6b: wkbq[t] = Wk_t @ bq_t
__global__ void k_wkbq(const float* __restrict__ Wk, const float* __restrict__ bq,
                       float* __restrict__ out) {
  __shared__ float bv[SS];
  int t = blockIdx.x, tid = threadIdx.x;
  const float* wk = Wk + (size_t)t * SS * SS;
  bv[tid] = bq[t * SS + tid];
  __syncthreads();
  float acc = 0.f;
  for (int j = 0; j < SS; j += 4) {
    float4 wv = *(const float4*)&wk[(size_t)tid * SS + j];
    float4 b4 = *(const float4*)&bv[j];
    acc += wv.x * b4.x + wv.y * b4.y + wv.z * b4.z + wv.w * b4.w;
  }
  out[t * SS + tid] = acc;
}

// -------- K7: per-(img,cap) pair mega kernel (v2)
__global__ __launch_bounds__(256, 4) void k_pair(
    const float* __restrict__ img, const float* __restrict__ cap,
    const float* __restrict__ W_loc, const float* __restrict__ b_loc,
    const float* __restrict__ simglo, const float* __restrict__ M,
    const float* __restrict__ wkbq, const float* __restrict__ Wg3,
    const float* __restrict__ bg3, const float* __restrict__ W_eval,
    const float* __restrict__ b_eval, float* __restrict__ out) {
  extern __shared__ char smem[];
  float* attn = (float*)(smem + OFF_ATTN);

  int tid = threadIdx.x;
  int p = blockIdx.x;
  int b = p >> 6, c = p & 63;
  const float* imgB = img + ((size_t)b * NTOK + 1) * DD;
  const float* capC = cap + (size_t)c * CL * DD;

  // ---------------- Phase A: attn[t][q] = leaky(img_tok[t] . cap[q]), 128t x 32q tiles
  {
    float* aK = (float*)(smem + OFF_AK);
    float* cK = (float*)(smem + OFF_CK);
    int tg = tid & 31, qg = tid >> 5;
    int s_rr = tid >> 1, s_kq = tid & 1;
    int c_q = tid >> 2, c_k = tid & 3;
    for (int T0 = 0; T0 < TT; T0 += 128) {
      float acc[4][4] = {};
      for (int k0 = 0; k0 < DD; k0 += 32) {
        int trow = T0 + s_rr;
        float va[16];
        if (trow < TT) {
          const float* pr = &imgB[(size_t)trow * DD + k0 + s_kq * 16];
          float4 v0 = *(const float4*)pr;
          float4 v1 = *(const float4*)(pr + 4);
          float4 v2 = *(const float4*)(pr + 8);
          float4 v3 = *(const float4*)(pr + 12);
          va[0] = v0.x; va[1] = v0.y; va[2] = v0.z; va[3] = v0.w;
          va[4] = v1.x; va[5] = v1.y; va[6] = v1.z; va[7] = v1.w;
          va[8] = v2.x; va[9] = v2.y; va[10] = v2.z; va[11] = v2.w;
          va[12] = v3.x; va[13] = v3.y; va[14] = v3.z; va[15] = v3.w;
        } else {
#pragma unroll
          for (int u = 0; u < 16; ++u) va[u] = 0.f;
        }
        float ca[8];
        if (tid < 128) {
          const float* pc = &capC[(size_t)c_q * DD + k0 + c_k * 8];
          float4 c0v = *(const float4*)pc;
          float4 c1v = *(const float4*)(pc + 4);
          ca[0] = c0v.x; ca[1] = c0v.y; ca[2] = c0v.z; ca[3] = c0v.w;
          ca[4] = c1v.x; ca[5] = c1v.y; ca[6] = c1v.z; ca[7] = c1v.w;
        }
        __syncthreads();
#pragma unroll
        for (int u = 0; u < 16; ++u) aK[(s_kq * 16 + u) * 132 + s_rr] = va[u];
        if (tid < 128) {
#pragma unroll
          for (int u = 0; u < 8; ++u) cK[(c_k * 8 + u) * 36 + c_q] = ca[u];
        }
        __syncthreads();
#pragma unroll
        for (int kk = 0; kk < 32; ++kk) {
          float4 a4 = *(const float4*)&aK[kk * 132 + tg * 4];
          float4 c4 = *(const float4*)&cK[kk * 36 + qg * 4];
          float av[4] = {a4.x, a4.y, a4.z, a4.w};
          float cv[4] = {c4.x, c4.y, c4.z, c4.w};
#pragma unroll
          for (int i = 0; i < 4; ++i)
#pragma unroll
            for (int j = 0; j < 4; ++j) acc[i][j] += av[i] * cv[j];
        }
      }
#pragma unroll
      for (int i = 0; i < 4; ++i) {
        int t = T0 + tg * 4 + i;
        if (t < TT) {
#pragma unroll
          for (int j = 0; j < 4; ++j) {
            float v = acc[i][j];
            v = v < 0.f ? 0.1f * v : v;
            attn[t * 33 + qg * 4 + j] = v;
          }
        }
      }
      __syncthreads();
    }
  }

  // ---------------- Phase A2: l2norm over q per token row t
  if (tid < TT) {
    float ss = 0.f;
#pragma unroll
    for (int q = 0; q < 32; ++q) {
      float v = attn[tid * 33 + q];
      ss += v * v;
    }
    float rn = 1.0f / fmaxf(sqrtf(ss), EPSN);
#pragma unroll
    for (int q = 0; q < 32; ++q) attn[tid * 33 + q] *= rn;
  }
  __syncthreads();

  // ---------------- Phase A3: softmax (x9) over t per q (denominator dropped;
  //                  exact because ctx is l2-normalized downstream)
  {
    int q = tid >> 3, sub = tid & 7;
    float m = -1e30f;
    for (int t = sub; t < TT; t += 8) m = fmaxf(m, attn[t * 33 + q]);
    m = fmaxf(m, __shfl_xor(m, 1, 64));
    m = fmaxf(m, __shfl_xor(m, 2, 64));
    m = fmaxf(m, __shfl_xor(m, 4, 64));
    for (int t = sub; t < TT; t += 8)
      attn[t * 33 + q] = expf(SMOOTHF * (attn[t * 33 + q] - m));
  }
  __syncthreads();

  // ---------------- Phase W: weighted ctx (2 sweeps: norms, then normalized diff^2 @ W_loc)
  float sl[4][8] = {};
  {
    float* wtile = (float*)(smem + OFF_WTILE);
    float* imgK = (float*)(smem + OFF_IMGK);
    float* nb = (float*)(smem + OFF_NB);
    float* nrmS = (float*)(smem + OFF_NRMS);
    int qg = tid & 7, dg = tid >> 3;
    int s_tt = tid >> 4, s_dq = tid & 15;
    int sq = tid >> 5, sg = tid & 31;

    auto weighted_pass = [&](int d0, float (&wa)[4][4]) {
      for (int t0 = 0; t0 < TT; t0 += 16) {
        int trow = t0 + s_tt;
        float4 i0 = {}, i1 = {};
        if (trow < TT) {
          const float* pr = &imgB[(size_t)trow * DD + d0 + s_dq * 8];
          i0 = *(const float4*)pr;
          i1 = *(const float4*)(pr + 4);
        }
        __syncthreads();
        *(float4*)&imgK[s_tt * 132 + s_dq * 8] = i0;
        *(float4*)&imgK[s_tt * 132 + s_dq * 8 + 4] = i1;
        __syncthreads();
        int kn = TT - t0;
        if (kn > 16) kn = 16;
        for (int kk = 0; kk < kn; ++kk) {
          float av[4];
#pragma unroll
          for (int j = 0; j < 4; ++j) av[j] = attn[(t0 + kk) * 33 + qg * 4 + j];
          float4 i4 = *(const float4*)&imgK[kk * 132 + dg * 4];
          float iv[4] = {i4.x, i4.y, i4.z, i4.w};
#pragma unroll
          for (int i = 0; i < 4; ++i)
#pragma unroll
            for (int j = 0; j < 4; ++j) wa[i][j] += av[i] * iv[j];
        }
      }
    };

    // sweep 1: accumulate ||ctx_q||^2 only
    float nrm[4] = {};
    for (int d0 = 0; d0 < DD; d0 += 128) {
      float wa[4][4] = {};
      weighted_pass(d0, wa);
#pragma unroll
      for (int i = 0; i < 4; ++i)
#pragma unroll
        for (int j = 0; j < 4; ++j) nrm[i] += wa[i][j] * wa[i][j];
    }
#pragma unroll
    for (int i = 0; i < 4; ++i) {
      nrm[i] += __shfl_xor(nrm[i], 8, 64);
      nrm[i] += __shfl_xor(nrm[i], 16, 64);
      nrm[i] += __shfl_xor(nrm[i], 32, 64);
    }
    {
      int wv = tid >> 6;
      if ((tid & 63) < 8) {
#pragma unroll
        for (int i = 0; i < 4; ++i) nb[wv * 32 + qg * 4 + i] = nrm[i];
      }
    }
    __syncthreads();
    if (tid < 32) {
      float s = nb[tid] + nb[32 + tid] + nb[64 + tid] + nb[96 + tid];
      nrmS[tid] = 1.0f / fmaxf(sqrtf(s), EPSN);
    }
    __syncthreads();

    // sweep 2: recompute ctx chunk, normalize, diff^2, W_loc GEMM
    for (int d0 = 0; d0 < DD; d0 += 128) {
      float wa[4][4] = {};
      weighted_pass(d0, wa);
#pragma unroll
      for (int i = 0; i < 4; ++i)
        *(float4*)&wtile[(qg * 4 + i) * 132 + dg * 4] =
            make_float4(wa[i][0], wa[i][1], wa[i][2], wa[i][3]);
      __syncthreads();
      for (int idx = tid; idx < 32 * 128; idx += 256) {
        int q = idx >> 7, d = idx & 127;
        float w = wtile[q * 132 + d] * nrmS[q] - capC[(size_t)q * DD + d0 + d];
        wtile[q * 132 + d] = w * w;
      }
      __syncthreads();
      for (int dd = 0; dd < 128; dd += 4) {
        float d2a[4][4];
#pragma unroll
        for (int i = 0; i < 4; ++i) {
          float4 t4 = *(const float4*)&wtile[(sq * 4 + i) * 132 + dd];
          d2a[i][0] = t4.x; d2a[i][1] = t4.y; d2a[i][2] = t4.z; d2a[i][3] = t4.w;
        }
#pragma unroll
        for (int u = 0; u < 4; ++u) {
          const float* wp = &W_loc[(size_t)(d0 + dd + u) * SS + sg * 8];
          float4 w0 = *(const float4*)wp;
          float4 w1 = *(const float4*)(wp + 4);
          float wv8[8] = {w0.x, w0.y, w0.z, w0.w, w1.x, w1.y, w1.z, w1.w};
#pragma unroll
          for (int i = 0; i < 4; ++i)
#pragma unroll
            for (int j = 0; j < 8; ++j) sl[i][j] += d2a[i][u] * wv8[j];
        }
      }
      __syncthreads();
    }
  }

  // ---------------- sim_emb assembly: l2norm(sim_loc)+bias -> seA rows 1..32; sim_glo row 0
  {
    float* seA = (float*)(smem + OFF_SEA);
    int sq = tid >> 5, sg = tid & 31;
#pragma unroll
    for (int i = 0; i < 4; ++i) {
      float v[8];
      float ssq = 0.f;
#pragma unroll
      for (int j = 0; j < 8; ++j) {
        v[j] = sl[i][j] + b_loc[sg * 8 + j];
        ssq += v[j] * v[j];
      }
      ssq += __shfl_xor(ssq, 1, 64);
      ssq += __shfl_xor(ssq, 2, 64);
      ssq += __shfl_xor(ssq, 4, 64);
      ssq += __shfl_xor(ssq, 8, 64);
      ssq += __shfl_xor(ssq, 16, 64);
      float rn = 1.0f / fmaxf(sqrtf(ssq), EPSN);
      int q = sq * 4 + i;
      *(float4*)&seA[(1 + q) * 260 + sg * 8] =
          make_float4(v[0] * rn, v[1] * rn, v[2] * rn, v[3] * rn);
      *(float4*)&seA[(1 + q) * 260 + sg * 8 + 4] =
          make_float4(v[4] * rn, v[5] * rn, v[6] * rn, v[7] * rn);
    }
    if (tid < 64)
      *(float4*)&seA[tid * 4] = *(const float4*)&simglo[(size_t)p * SS + tid * 4];
  }
  __syncthreads();

  // ---------------- SGR x3 (fused register-tiled: G=seA@M -> E; H=E@seA -> out@Wg)
  {
    float* seA = (float*)(smem + OFF_SEA);
    float* Gb = (float*)(smem + OFF_GB);
    float* Emat = (float*)(smem + OFF_EMAT);
    float* vbuf = (float*)(smem + OFF_VBUF);
    float* wkq = (float*)(smem + OFF_WKBQ);
    int gy = tid >> 5, gx = tid & 31;   // G phase
    int e_n = tid >> 3, e_m = tid & 7;  // E phase
    int h_r = tid >> 4, h_c = tid & 15; // H phase
    int wy = tid >> 6, wx = tid & 63;   // Wg phase

    for (int step = 0; step < 3; ++step) {
      const float* Ms = M + (size_t)step * SS * SS;
      const float* Wgs = Wg3 + (size_t)step * SS * SS;
      const float* bgs = bg3 + (size_t)step * SS;
      if (tid < 64)
        *(float4*)&wkq[tid * 4] = *(const float4*)&wkbq[step * SS + tid * 4];
      __syncthreads();
      // vbuf[m] = seA[m] . (Wk@bq)
      if (tid < 132) {
        int m = tid >> 2, qq = tid & 3;
        float a = 0.f;
        for (int e = qq * 64; e < qq * 64 + 64; e += 4) {
          float4 s4 = *(const float4*)&seA[m * 260 + e];
          float4 w4 = *(const float4*)&wkq[e];
          a += s4.x * w4.x + s4.y * w4.y + s4.z * w4.z + s4.w * w4.w;
        }
        a += __shfl_xor(a, 1, 64);
        a += __shfl_xor(a, 2, 64);
        if (qq == 0) vbuf[m] = a;
      }

      float eacc[5] = {0.f, 0.f, 0.f, 0.f, 0.f};
      float eacc2[5] = {0.f, 0.f, 0.f, 0.f, 0.f};
      for (int k0 = 0; k0 < SS; k0 += 64) {
        // --- G tile: G[n][k-k0] for k in [k0,k0+64)
        float ga[4][2] = {};
        float gxe[2] = {};
        {
          const float* mp = Ms + k0 + gx * 2;
          for (int j = 0; j < SS; j += 4) {
            float s[4][4];
#pragma unroll
            for (int u = 0; u < 4; ++u) {
              float4 s4 = *(const float4*)&seA[(gy + 8 * u) * 260 + j];
              s[u][0] = s4.x; s[u][1] = s4.y; s[u][2] = s4.z; s[u][3] = s4.w;
            }
            float mv[4][2];
#pragma unroll
            for (int jj = 0; jj < 4; ++jj) {
              float2 m2 = *(const float2*)&mp[(size_t)(j + jj) * SS];
              mv[jj][0] = m2.x; mv[jj][1] = m2.y;
            }
#pragma unroll
            for (int u = 0; u < 4; ++u)
#pragma unroll
              for (int jj = 0; jj < 4; ++jj) {
                ga[u][0] += s[u][jj] * mv[jj][0];
                ga[u][1] += s[u][jj] * mv[jj][1];
              }
            if (gy == 0) {
              float4 sx4 = *(const float4*)&seA[32 * 260 + j];
              float sx[4] = {sx4.x, sx4.y, sx4.z, sx4.w};
#pragma unroll
              for (int jj = 0; jj < 4; ++jj) {
                gxe[0] += sx[jj] * mv[jj][0];
                gxe[1] += sx[jj] * mv[jj][1];
              }
            }
          }
        }
        __syncthreads();  // previous E readers of Gb are done
#pragma unroll
        for (int u = 0; u < 4; ++u)
          *(float2*)&Gb[(gy + 8 * u) * 68 + gx * 2] = make_float2(ga[u][0], ga[u][1]);
        if (gy == 0) *(float2*)&Gb[32 * 68 + gx * 2] = make_float2(gxe[0], gxe[1]);
        __syncthreads();
        // --- E accumulate: E[n][m] += sum_k G[n][k]*seA[m][k]
        for (int kk = 0; kk < 64; kk += 4) {
          float4 g4 = *(const float4*)&Gb[e_n * 68 + kk];
          float gv[4] = {g4.x, g4.y, g4.z, g4.w};
          float gbv[4] = {0.f, 0.f, 0.f, 0.f};
          if (e_n == 0) {
            float4 gb4 = *(const float4*)&Gb[32 * 68 + kk];
            gbv[0] = gb4.x; gbv[1] = gb4.y; gbv[2] = gb4.z; gbv[3] = gb4.w;
          }
#pragma unroll
          for (int j = 0; j < 4; ++j) {
            float4 s4 = *(const float4*)&seA[(e_m * 4 + j) * 260 + k0 + kk];
            float sv[4] = {s4.x, s4.y, s4.z, s4.w};
            eacc[j] += gv[0] * sv[0] + gv[1] * sv[1] + gv[2] * sv[2] + gv[3] * sv[3];
            if (e_n == 0)
              eacc2[j] += gbv[0] * sv[0] + gbv[1] * sv[1] + gbv[2] * sv[2] + gbv[3] * sv[3];
          }
          if (e_m == 7) {
            float4 s4 = *(const float4*)&seA[32 * 260 + k0 + kk];
            float sv[4] = {s4.x, s4.y, s4.z, s4.w};
            eacc[4] += gv[0] * sv[0] + gv[1] * sv[1] + gv[2] * sv[2] + gv[3] * sv[3];
            if (e_n == 0)
              eacc2[4] += gbv[0] * sv[0] + gbv[1] * sv[1] + gbv[2] * sv[2] + gbv[3] * sv[3];
          }
        }
      }
      __syncthreads();  // all E reads done (also covers vbuf availability)
#pragma unroll
      for (int j = 0; j < 4; ++j)
        Emat[e_n * 36 + e_m * 4 + j] = eacc[j] + vbuf[e_m * 4 + j];
      if (e_m == 7) Emat[e_n * 36 + 32] = eacc[4] + vbuf[32];
      if (e_n == 0) {
#pragma unroll
        for (int j = 0; j < 4; ++j)
          Emat[32 * 36 + e_m * 4 + j] = eacc2[j] + vbuf[e_m * 4 + j];
        if (e_m == 7) Emat[32 * 36 + 32] = eacc2[4] + vbuf[32];
      }
      __syncthreads();
      // row softmax of E
      if (tid < NN) {
        float mx = -1e30f;
        for (int mm = 0; mm < NN; ++mm) mx = fmaxf(mx, Emat[tid * 36 + mm]);
        float sum = 0.f;
        for (int mm = 0; mm < NN; ++mm) {
          float e = expf(Emat[tid * 36 + mm] - mx);
          Emat[tid * 36 + mm] = e;
          sum += e;
        }
        float rs = 1.0f / sum;
        for (int mm = 0; mm < NN; ++mm) Emat[tid * 36 + mm] *= rs;
      }
      __syncthreads();
      // --- phase 2: out = relu((E@seA)@Wg + bg)
      float oacc[8][4] = {};
      float oxe[4] = {};
      for (int k0 = 0; k0 < SS; k0 += 64) {
        // H tile
        float ha[2][4] = {};
        float hx[4] = {};
        for (int mm = 0; mm < NN; ++mm) {
          float e0 = Emat[h_r * 36 + mm];
          float e1 = Emat[(h_r + 16) * 36 + mm];
          float4 s4 = *(const float4*)&seA[mm * 260 + k0 + h_c * 4];
          float sv[4] = {s4.x, s4.y, s4.z, s4.w};
#pragma unroll
          for (int cc = 0; cc < 4; ++cc) {
            ha[0][cc] += e0 * sv[cc];
            ha[1][cc] += e1 * sv[cc];
          }
          if (h_r == 0) {
            float e2 = Emat[32 * 36 + mm];
#pragma unroll
            for (int cc = 0; cc < 4; ++cc) hx[cc] += e2 * sv[cc];
          }
        }
        __syncthreads();  // previous Wg readers of Gb are done
        *(float4*)&Gb[h_r * 68 + h_c * 4] = make_float4(ha[0][0], ha[0][1], ha[0][2], ha[0][3]);
        *(float4*)&Gb[(h_r + 16) * 68 + h_c * 4] =
            make_float4(ha[1][0], ha[1][1], ha[1][2], ha[1][3]);
        if (h_r == 0)
          *(float4*)&Gb[32 * 68 + h_c * 4] = make_float4(hx[0], hx[1], hx[2], hx[3]);
        __syncthreads();
        // Wg accumulate
        const float* wp = Wgs + (size_t)k0 * SS + wx * 4;
        for (int kk = 0; kk < 64; kk += 4) {
          float hv[8][4];
#pragma unroll
          for (int u = 0; u < 8; ++u) {
            float4 h4 = *(const float4*)&Gb[(wy * 8 + u) * 68 + kk];
            hv[u][0] = h4.x; hv[u][1] = h4.y; hv[u][2] = h4.z; hv[u][3] = h4.w;
          }
          float hxv[4] = {0.f, 0.f, 0.f, 0.f};
          if (wy == 0) {
            float4 h4 = *(const float4*)&Gb[32 * 68 + kk];
            hxv[0] = h4.x; hxv[1] = h4.y; hxv[2] = h4.z; hxv[3] = h4.w;
          }
#pragma unroll
          for (int cc = 0; cc < 4; ++cc) {
            float4 w4 = *(const float4*)&wp[(size_t)(kk + cc) * SS];
            float wv[4] = {w4.x, w4.y, w4.z, w4.w};
#pragma unroll
            for (int u = 0; u < 8; ++u)
#pragma unroll
              for (int cx = 0; cx < 4; ++cx) oacc[u][cx] += hv[u][cc] * wv[cx];
            if (wy == 0) {
#pragma unroll
              for (int cx = 0; cx < 4; ++cx) oxe[cx] += hxv[cc] * wv[cx];
            }
          }
        }
        __syncthreads();  // Wg reads done before next H write
      }
      // seA = relu(out + bg)
#pragma unroll
      for (int u = 0; u < 8; ++u) {
        float v[4];
#pragma unroll
        for (int cx = 0; cx < 4; ++cx) {
          float t = oacc[u][cx] + bgs[wx * 4 + cx];
          v[cx] = t > 0.f ? t : 0.f;
        }
        *(float4*)&seA[(wy * 8 + u) * 260 + wx * 4] = make_float4(v[0], v[1], v[2], v[3]);
      }
      if (wy == 0) {
        float v[4];
#pragma unroll
        for (int cx = 0; cx < 4; ++cx) {
          float t = oxe[cx] + bgs[wx * 4 + cx];
          v[cx] = t > 0.f ? t : 0.f;
        }
        *(float4*)&seA[32 * 260 + wx * 4] = make_float4(v[0], v[1], v[2], v[3]);
      }
      __syncthreads();
    }
  }

  // ---------------- eval: sigmoid(seA[0] @ W_eval + b_eval)
  if (tid < 64) {
    float* seA = (float*)(smem + OFF_SEA);
    float4 s4 = *(const float4*)&seA[tid * 4];
    float4 w4 = *(const float4*)&W_eval[tid * 4];
    float s = s4.x * w4.x + s4.y * w4.y + s4.z * w4.z + s4.w * w4.w;
    s = warp_reduce_sum64(s);
    if (tid == 0) out[b * 64 + c] = 1.0f / (1.0f + expf(-(s + b_eval[0])));
  }
}

extern "C" void kernel_launch(void* const* d_in, const int* in_sizes, int n_in,
                              void* d_out, int out_size, void* d_ws, size_t ws_size,
                              hipStream_t stream) {
  (void)in_sizes; (void)n_in; (void)out_size; (void)ws_size;
  const float* img = (const float*)d_in[0];
  const float* cap = (const float*)d_in[1];
  const float* vG_Wl = (const float*)d_in[3];
  const float* vG_bl = (const float*)d_in[4];
  const float* vG_Wg = (const float*)d_in[5];
  const float* vG_bg = (const float*)d_in[6];
  const float* vG_Wc = (const float*)d_in[7];
  const float* vG_bc = (const float*)d_in[8];
  const float* tG_Wl = (const float*)d_in[9];
  const float* tG_bl = (const float*)d_in[10];
  const float* tG_Wg = (const float*)d_in[11];
  const float* tG_bg = (const float*)d_in[12];
  const float* tG_Wc = (const float*)d_in[13];
  const float* tG_bc = (const float*)d_in[14];
  const float* W_loc = (const float*)d_in[15];
  const float* b_loc = (const float*)d_in[16];
  const float* W_glo = (const float*)d_in[17];
  const float* b_glo = (const float*)d_in[18];
  const float* W_eval = (const float*)d_in[19];
  const float* b_eval = (const float*)d_in[20];
  const float* sgr_Wq = (const float*)d_in[21];
  const float* sgr_bq = (const float*)d_in[22];
  const float* sgr_Wk = (const float*)d_in[23];
  const float* sgr_Wg = (const float*)d_in[25];
  const float* sgr_bg = (const float*)d_in[26];
  float* out = (float*)d_out;
  float* ws = (float*)d_ws;
  float* img_avg = ws;
  float* cap_avg = ws + 65536;
  float* h_img = ws + 131072;
  float* h_cap = ws + 196608;
  float* part_img = ws + 262144;
  float* part_cap = ws + 462848;
  float* img_glob = ws + 495616;
  float* cap_glob = ws + 561152;
  float* simglo = ws + 626688;
  float* Mmat = ws + 1675264;
  float* wkbqv = ws + 1871872;

  k_avg<<<128, 256, 0, stream>>>(img, cap, img_avg, cap_avg);
  k_hvec<<<256, 256, 0, stream>>>(img_avg, vG_Wg, vG_bg, vG_Wc, h_img);
  k_hvec<<<256, 256, 0, stream>>>(cap_avg, tG_Wg, tG_bg, tG_Wc, h_cap);
  k_logits_partial<<<dim3(196, 16), 256, 0, stream>>>(img + DD, (long)NTOK * DD, TT, vG_Wl,
                                                      vG_bl, h_img, part_img);
  k_logits_partial<<<dim3(32, 16), 256, 0, stream>>>(cap, (long)CL * DD, CL, tG_Wl, tG_bl,
                                                     h_cap, part_cap);
  k_finish_global<<<64, 256, 0, stream>>>(part_img, vG_bc, img + DD, (long)NTOK * DD, TT,
                                          img_glob);
  k_finish_global<<<64, 256, 0, stream>>>(part_cap, tG_bc, cap, (long)CL * DD, CL, cap_glob);
  k_simglo<<<256, 256, 0, stream>>>(img_glob, cap_glob, W_glo, b_glo, simglo);
  k_mmat<<<48, 256, 0, stream>>>(sgr_Wq, sgr_Wk, Mmat);
  k_wkbq<<<3, 256, 0, stream>>>(sgr_Wk, sgr_bq, wkbqv);
  hipFuncSetAttribute((const void*)k_pair, hipFuncAttributeMaxDynamicSharedMemorySize,
                      SMEM_BYTES);
  k_pair<<<4096, 256, SMEM_BYTES, stream>>>(img, cap, W_loc, b_loc, simglo, Mmat, wkbqv,
                                            sgr_Wg, sgr_bg, W_eval, b_eval, out);
}

// Round 3
// 18665.189 us; speedup vs baseline: 1.2395x; 1.2395x over previous
//
#include <hip/hip_runtime.h>
#include <hip/hip_bf16.h>
#include <math.h>

#define NI 64
#define NC 64
#define NTOK 197
#define TT 196
#define CL 32
#define DD 1024
#define SS 256
#define NN 33
#define EPSN 1e-12f
#define SMOOTHF 9.0f

// LDS layout (byte offsets)
#define OFF_ATTN   0        // [196][33] f32 = 25872
#define OFF_WTILE  25872    // [32][132] f32 = 16896 (phase A img staging / phase W wtile)
#define OFF_CK     42768    // [32][36]  f32 = 4608  (phase A cap staging)
#define OFF_SEA    0        // [33][260] f32 = 34320 (SGR)
#define OFF_GB     34320    // [33][68]  f32 = 8976
#define OFF_EMAT   43296    // [33][36]  f32 = 4752
#define OFF_VBUF   48048    // [33] f32
#define OFF_WKQ    48192    // [256] f32
#define OFF_NB     49216    // [128] f32
#define OFF_NRMS   49728    // [32] f32
#define SMEM_BYTES 49856

__device__ __forceinline__ float warp_reduce_sum64(float v) {
#pragma unroll
  for (int m = 32; m > 0; m >>= 1) v += __shfl_xor(v, m, 64);
  return v;
}

// ---------------------------------------------------------------- K1: means
__global__ void k_avg(const float* __restrict__ img, const float* __restrict__ cap,
                      float* __restrict__ img_avg, float* __restrict__ cap_avg) {
  int bid = blockIdx.x;
  int tid = threadIdx.x;
  if (bid < NI) {
    int b = bid;
    for (int d = tid; d < DD; d += 256) {
      float acc = 0.f;
      const float* p = img + ((size_t)b * NTOK + 1) * DD + d;
      for (int t = 0; t < TT; ++t) acc += p[(size_t)t * DD];
      img_avg[b * DD + d] = acc * (1.0f / TT);
    }
  } else {
    int c = bid - NI;
    for (int d = tid; d < DD; d += 256) {
      float acc = 0.f;
      const float* p = cap + (size_t)c * CL * DD + d;
      for (int t = 0; t < CL; ++t) acc += p[(size_t)t * DD];
      cap_avg[c * DD + d] = acc * (1.0f / CL);
    }
  }
}

// ------------------------------------------------- K2: h = tanh(avg@Wg+bg)*Wc
__global__ void k_hvec(const float* __restrict__ avg, const float* __restrict__ Wg,
                       const float* __restrict__ bg, const float* __restrict__ Wc,
                       float* __restrict__ h) {
  __shared__ float av[DD];
  int b = blockIdx.x >> 2;
  int dc = blockIdx.x & 3;
  int tid = threadIdx.x;
  for (int i = tid; i < DD; i += 256) av[i] = avg[b * DD + i];
  __syncthreads();
  int d = dc * 256 + tid;
  float acc = 0.f;
  for (int k = 0; k < DD; k += 4) {
    float4 a4 = *(const float4*)&av[k];
    acc += a4.x * Wg[(size_t)(k + 0) * DD + d];
    acc += a4.y * Wg[(size_t)(k + 1) * DD + d];
    acc += a4.z * Wg[(size_t)(k + 2) * DD + d];
    acc += a4.w * Wg[(size_t)(k + 3) * DD + d];
  }
  h[b * DD + d] = tanhf(acc + bg[d]) * Wc[d];
}

// ---------------- K3: partial[row,ct] = sum_{d in col-tile} tanh((A@Wl)[row,d]+bl)*h[b,d]
__global__ void k_logits_partial(const float* __restrict__ Abase, long batchStride, int rowsPerBatch,
                                 const float* __restrict__ Wl, const float* __restrict__ bl,
                                 const float* __restrict__ h, float* __restrict__ partial) {
  __shared__ float a_lds[32][68];
  __shared__ float b_lds[32][68];
  int tid = threadIdx.x;
  int rb = blockIdx.x * 64;
  int c0 = blockIdx.y * 64;
  int ty = tid >> 4, tx = tid & 15;
  int s_rr = tid >> 2, s_kq = tid & 3;
  int rA = rb + s_rr;
  const float* aRow = Abase + (size_t)(rA / rowsPerBatch) * batchStride + (size_t)(rA % rowsPerBatch) * DD;
  int s_kk = tid >> 3, s_cq = tid & 7;
  float acc[4][4] = {};
  for (int k0 = 0; k0 < DD; k0 += 32) {
    float4 v0 = *(const float4*)&aRow[k0 + s_kq * 8];
    float4 v1 = *(const float4*)&aRow[k0 + s_kq * 8 + 4];
    float4 w0 = *(const float4*)&Wl[(size_t)(k0 + s_kk) * DD + c0 + s_cq * 8];
    float4 w1 = *(const float4*)&Wl[(size_t)(k0 + s_kk) * DD + c0 + s_cq * 8 + 4];
    __syncthreads();
    float va[8] = {v0.x, v0.y, v0.z, v0.w, v1.x, v1.y, v1.z, v1.w};
#pragma unroll
    for (int u = 0; u < 8; ++u) a_lds[s_kq * 8 + u][s_rr] = va[u];
    *(float4*)&b_lds[s_kk][s_cq * 8] = w0;
    *(float4*)&b_lds[s_kk][s_cq * 8 + 4] = w1;
    __syncthreads();
#pragma unroll
    for (int kk = 0; kk < 32; ++kk) {
      float4 a4 = *(const float4*)&a_lds[kk][ty * 4];
      float4 b4 = *(const float4*)&b_lds[kk][tx * 4];
      float av[4] = {a4.x, a4.y, a4.z, a4.w};
      float bv[4] = {b4.x, b4.y, b4.z, b4.w};
#pragma unroll
      for (int i = 0; i < 4; ++i)
#pragma unroll
        for (int j = 0; j < 4; ++j) acc[i][j] += av[i] * bv[j];
    }
  }
#pragma unroll
  for (int i = 0; i < 4; ++i) {
    int r = rb + ty * 4 + i;
    int bb = r / rowsPerBatch;
    float s = 0.f;
#pragma unroll
    for (int j = 0; j < 4; ++j) {
      int cc = c0 + tx * 4 + j;
      s += tanhf(acc[i][j] + bl[cc]) * h[bb * DD + cc];
    }
    s += __shfl_xor(s, 1, 64);
    s += __shfl_xor(s, 2, 64);
    s += __shfl_xor(s, 4, 64);
    s += __shfl_xor(s, 8, 64);
    if (tx == 0) partial[(size_t)r * 16 + blockIdx.y] = s;
  }
}

// -------- K4: logits -> softmax weights -> weighted sum of tokens -> l2norm
__global__ void k_finish_global(const float* __restrict__ partial, const float* __restrict__ bc,
                                const float* __restrict__ Xbase, long batchStride, int R,
                                float* __restrict__ outG) {
  __shared__ float w[200];
  __shared__ float red[8];
  int b = blockIdx.x, tid = threadIdx.x;
  for (int t = tid; t < R; t += 256) {
    const float* pp = &partial[((size_t)b * R + t) * 16];
    float s = bc[0];
#pragma unroll
    for (int u = 0; u < 16; ++u) s += pp[u];
    w[t] = s;
  }
  __syncthreads();
  float m = -1e30f;
  for (int t = tid; t < R; t += 256) m = fmaxf(m, w[t]);
#pragma unroll
  for (int mm = 32; mm; mm >>= 1) m = fmaxf(m, __shfl_xor(m, mm, 64));
  if ((tid & 63) == 0) red[tid >> 6] = m;
  __syncthreads();
  m = fmaxf(fmaxf(red[0], red[1]), fmaxf(red[2], red[3]));
  __syncthreads();
  for (int t = tid; t < R; t += 256) w[t] = expf(w[t] - m);
  __syncthreads();
  const float* xb = Xbase + (size_t)b * batchStride;
  float acc[4];
  float ss = 0.f;
#pragma unroll
  for (int c4 = 0; c4 < 4; ++c4) {
    int d = tid + c4 * 256;
    float a = 0.f;
    for (int t = 0; t < R; ++t) a += w[t] * xb[(size_t)t * DD + d];
    acc[c4] = a;
    ss += a * a;
  }
  ss = warp_reduce_sum64(ss);
  if ((tid & 63) == 0) red[tid >> 6] = ss;
  __syncthreads();
  ss = red[0] + red[1] + red[2] + red[3];
  float rn = 1.0f / fmaxf(sqrtf(ss), EPSN);
#pragma unroll
  for (int c4 = 0; c4 < 4; ++c4) outG[(size_t)b * DD + tid + c4 * 256] = acc[c4] * rn;
}

// -------- K5: sim_glo[p] = l2norm((img_g[b]-cap_g[c])^2 @ W_glo + b_glo), p=b*64+c
__global__ void k_simglo(const float* __restrict__ ig, const float* __restrict__ cg,
                         const float* __restrict__ W, const float* __restrict__ bgl,
                         float* __restrict__ simglo) {
  __shared__ float a_lds[32][20];
  __shared__ float b_lds[32][260];
  int tid = threadIdx.x;
  int p0 = blockIdx.x * 16;
  int ty = tid >> 6, tx = tid & 63;
  int s_rr = tid >> 3, s_kq = tid & 7;
  float acc[4][4] = {};
  for (int k0 = 0; k0 < DD; k0 += 32) {
    float d2[4] = {};
    if (tid < 128) {
      int p = p0 + s_rr;
      int b = p >> 6, c = p & 63;
      float4 giv = *(const float4*)&ig[b * DD + k0 + s_kq * 4];
      float4 cgv = *(const float4*)&cg[c * DD + k0 + s_kq * 4];
      float dx = giv.x - cgv.x, dy = giv.y - cgv.y, dz = giv.z - cgv.z, dw = giv.w - cgv.w;
      d2[0] = dx * dx; d2[1] = dy * dy; d2[2] = dz * dz; d2[3] = dw * dw;
    }
    float4 wv[8];
#pragma unroll
    for (int u = 0; u < 8; ++u)
      wv[u] = *(const float4*)&W[(size_t)(k0 + s_rr) * SS + s_kq * 32 + u * 4];
    __syncthreads();
    if (tid < 128) {
#pragma unroll
      for (int u = 0; u < 4; ++u) a_lds[s_kq * 4 + u][s_rr] = d2[u];
    }
#pragma unroll
    for (int u = 0; u < 8; ++u)
      *(float4*)&b_lds[s_rr][s_kq * 32 + u * 4] = wv[u];
    __syncthreads();
#pragma unroll
    for (int kk = 0; kk < 32; ++kk) {
      float4 a4 = *(const float4*)&a_lds[kk][ty * 4];
      float4 b4 = *(const float4*)&b_lds[kk][tx * 4];
      float av[4] = {a4.x, a4.y, a4.z, a4.w};
      float bv[4] = {b4.x, b4.y, b4.z, b4.w};
#pragma unroll
      for (int i = 0; i < 4; ++i)
#pragma unroll
        for (int j = 0; j < 4; ++j) acc[i][j] += av[i] * bv[j];
    }
  }
#pragma unroll
  for (int i = 0; i < 4; ++i) {
    float v[4];
    float ssq = 0.f;
#pragma unroll
    for (int j = 0; j < 4; ++j) {
      v[j] = acc[i][j] + bgl[tx * 4 + j];
      ssq += v[j] * v[j];
    }
    ssq = warp_reduce_sum64(ssq);
    float rn = 1.0f / fmaxf(sqrtf(ssq), EPSN);
    int p = p0 + ty * 4 + i;
    *(float4*)&simglo[(size_t)p * SS + tx * 4] =
        make_float4(v[0] * rn, v[1] * rn, v[2] * rn, v[3] * rn);
  }
}

// -------- K6: M[t] = Wq_t @ Wk_t^T  (256x256)
__global__ void k_mmat(const float* __restrict__ Wq, const float* __restrict__ Wk,
                       float* __restrict__ M) {
  __shared__ float a_lds[32][68];
  __shared__ float b_lds[32][68];
  int tid = threadIdx.x;
  int t = blockIdx.x >> 4;
  int dt = (blockIdx.x >> 2) & 3, et = blockIdx.x & 3;
  int d0 = dt * 64, e0 = et * 64;
  const float* wq = Wq + (size_t)t * SS * SS;
  const float* wk = Wk + (size_t)t * SS * SS;
  int ty = tid >> 4, tx = tid & 15;
  int s_rr = tid >> 2, s_kq = tid & 3;
  float acc[4][4] = {};
  for (int j0 = 0; j0 < SS; j0 += 32) {
    float4 q0 = *(const float4*)&wq[(size_t)(d0 + s_rr) * SS + j0 + s_kq * 8];
    float4 q1 = *(const float4*)&wq[(size_t)(d0 + s_rr) * SS + j0 + s_kq * 8 + 4];
    float4 k0v = *(const float4*)&wk[(size_t)(e0 + s_rr) * SS + j0 + s_kq * 8];
    float4 k1v = *(const float4*)&wk[(size_t)(e0 + s_rr) * SS + j0 + s_kq * 8 + 4];
    __syncthreads();
    float qa[8] = {q0.x, q0.y, q0.z, q0.w, q1.x, q1.y, q1.z, q1.w};
    float ka[8] = {k0v.x, k0v.y, k0v.z, k0v.w, k1v.x, k1v.y, k1v.z, k1v.w};
#pragma unroll
    for (int u = 0; u < 8; ++u) {
      a_lds[s_kq * 8 + u][s_rr] = qa[u];
      b_lds[s_kq * 8 + u][s_rr] = ka[u];
    }
    __syncthreads();
#pragma unroll
    for (int kk = 0; kk < 32; ++kk) {
      float4 a4 = *(const float4*)&a_lds[kk][ty * 4];
      float4 b4 = *(const float4*)&b_lds[kk][tx * 4];
      float av[4] = {a4.x, a4.y, a4.z, a4.w};
      float bv[4] = {b4.x, b4.y, b4.z, b4.w};
#pragma unroll
      for (int i = 0; i < 4; ++i)
#pragma unroll
        for (int j = 0; j < 4; ++j) acc[i][j] += av[i] * bv[j];
    }
  }
#pragma unroll
  for (int i = 0; i < 4; ++i)
    *(float4*)&M[(size_t)t * SS * SS + (size_t)(d0 + ty * 4 + i) * SS + e0 + tx * 4] =
        make_float4(acc[i][0], acc[i][1], acc[i][2], acc[i][3]);
}

// -------- K6b: wkbq[t] = Wk_t @ bq_t
__global__ void k_wkbq(const float* __restrict__ Wk, const float* __restrict__ bq,
                       float* __restrict__ out) {
  __shared__ float bv[SS];
  int t = blockIdx.x, tid = threadIdx.x;
  const float* wk = Wk + (size_t)t * SS * SS;
  bv[tid] = bq[t * SS + tid];
  __syncthreads();
  float acc = 0.f;
  for (int j = 0; j < SS; j += 4) {
    float4 wv = *(const float4*)&wk[(size_t)tid * SS + j];
    float4 b4 = *(const float4*)&bv[j];
    acc += wv.x * b4.x + wv.y * b4.y + wv.z * b4.z + wv.w * b4.w;
  }
  out[t * SS + tid] = acc;
}

// -------- K6c: gram[b] = imgTok_b @ imgTok_b^T (196x196)
__global__ void k_gram(const float* __restrict__ img, float* __restrict__ gram) {
  __shared__ float a_lds[32][68];
  __shared__ float b_lds[32][68];
  int tid = threadIdx.x;
  int bimg = blockIdx.x;
  int rb = blockIdx.y * 64;
  int cb = blockIdx.z * 64;
  const float* X = img + ((size_t)bimg * NTOK + 1) * DD;
  int ty = tid >> 4, tx = tid & 15;
  int s_rr = tid >> 2, s_kq = tid & 3;
  int rA = rb + s_rr; if (rA > TT - 1) rA = TT - 1;
  int rB = cb + s_rr; if (rB > TT - 1) rB = TT - 1;
  const float* aRow = X + (size_t)rA * DD;
  const float* bRow = X + (size_t)rB * DD;
  float acc[4][4] = {};
  for (int k0 = 0; k0 < DD; k0 += 32) {
    float4 v0 = *(const float4*)&aRow[k0 + s_kq * 8];
    float4 v1 = *(const float4*)&aRow[k0 + s_kq * 8 + 4];
    float4 w0 = *(const float4*)&bRow[k0 + s_kq * 8];
    float4 w1 = *(const float4*)&bRow[k0 + s_kq * 8 + 4];
    __syncthreads();
    float va[8] = {v0.x, v0.y, v0.z, v0.w, v1.x, v1.y, v1.z, v1.w};
    float wa[8] = {w0.x, w0.y, w0.z, w0.w, w1.x, w1.y, w1.z, w1.w};
#pragma unroll
    for (int u = 0; u < 8; ++u) {
      a_lds[s_kq * 8 + u][s_rr] = va[u];
      b_lds[s_kq * 8 + u][s_rr] = wa[u];
    }
    __syncthreads();
#pragma unroll
    for (int kk = 0; kk < 32; ++kk) {
      float4 a4 = *(const float4*)&a_lds[kk][ty * 4];
      float4 b4 = *(const float4*)&b_lds[kk][tx * 4];
      float av[4] = {a4.x, a4.y, a4.z, a4.w};
      float bv[4] = {b4.x, b4.y, b4.z, b4.w};
#pragma unroll
      for (int i = 0; i < 4; ++i)
#pragma unroll
        for (int j = 0; j < 4; ++j) acc[i][j] += av[i] * bv[j];
    }
  }
  float* Gp = gram + (size_t)bimg * TT * TT;
#pragma unroll
  for (int i = 0; i < 4; ++i) {
    int r = rb + ty * 4 + i;
    if (r < TT) {
#pragma unroll
      for (int j = 0; j < 4; ++j) {
        int c2 = cb + tx * 4 + j;
        if (c2 < TT) Gp[(size_t)r * TT + c2] = acc[i][j];
      }
    }
  }
}

// -------- K7: per-(img,cap) pair mega kernel (v3: spill-safe, Gram norm, in-place SGR)
__global__ __launch_bounds__(256) void k_pair(
    const float* __restrict__ img, const float* __restrict__ cap,
    const float* __restrict__ W_loc, const float* __restrict__ b_loc,
    const float* __restrict__ simglo, const float* __restrict__ M,
    const float* __restrict__ wkbq, const float* __restrict__ Wg3,
    const float* __restrict__ bg3, const float* __restrict__ W_eval,
    const float* __restrict__ b_eval, const float* __restrict__ gram,
    float* __restrict__ out) {
  extern __shared__ char smem[];
  float* attn = (float*)(smem + OFF_ATTN);

  int tid = threadIdx.x;
  int p = blockIdx.x;
  int b = p >> 6, c = p & 63;
  const float* imgB = img + ((size_t)b * NTOK + 1) * DD;
  const float* capC = cap + (size_t)c * CL * DD;

  // ---------------- Phase A: attn[t][q] = leaky(img_tok[t] . cap[q]), 128t x 32q tiles
  {
    float* aK = (float*)(smem + OFF_WTILE);
    float* cK = (float*)(smem + OFF_CK);
    int tg = tid & 31, qg = tid >> 5;
    int s_rr = tid >> 1, s_kq = tid & 1;
    int c_q = tid >> 2, c_k = tid & 3;
    for (int T0 = 0; T0 < TT; T0 += 128) {
      float acc[4][4] = {};
      for (int k0 = 0; k0 < DD; k0 += 32) {
        int trow = T0 + s_rr;
        float va[16];
        if (trow < TT) {
          const float* pr = &imgB[(size_t)trow * DD + k0 + s_kq * 16];
          float4 v0 = *(const float4*)pr;
          float4 v1 = *(const float4*)(pr + 4);
          float4 v2 = *(const float4*)(pr + 8);
          float4 v3 = *(const float4*)(pr + 12);
          va[0] = v0.x; va[1] = v0.y; va[2] = v0.z; va[3] = v0.w;
          va[4] = v1.x; va[5] = v1.y; va[6] = v1.z; va[7] = v1.w;
          va[8] = v2.x; va[9] = v2.y; va[10] = v2.z; va[11] = v2.w;
          va[12] = v3.x; va[13] = v3.y; va[14] = v3.z; va[15] = v3.w;
        } else {
#pragma unroll
          for (int u = 0; u < 16; ++u) va[u] = 0.f;
        }
        float ca[8];
        if (tid < 128) {
          const float* pc = &capC[(size_t)c_q * DD + k0 + c_k * 8];
          float4 c0v = *(const float4*)pc;
          float4 c1v = *(const float4*)(pc + 4);
          ca[0] = c0v.x; ca[1] = c0v.y; ca[2] = c0v.z; ca[3] = c0v.w;
          ca[4] = c1v.x; ca[5] = c1v.y; ca[6] = c1v.z; ca[7] = c1v.w;
        }
        __syncthreads();
#pragma unroll
        for (int u = 0; u < 16; ++u) aK[(s_kq * 16 + u) * 132 + s_rr] = va[u];
        if (tid < 128) {
#pragma unroll
          for (int u = 0; u < 8; ++u) cK[(c_k * 8 + u) * 36 + c_q] = ca[u];
        }
        __syncthreads();
#pragma unroll
        for (int kk = 0; kk < 32; ++kk) {
          float4 a4 = *(const float4*)&aK[kk * 132 + tg * 4];
          float4 c4 = *(const float4*)&cK[kk * 36 + qg * 4];
          float av[4] = {a4.x, a4.y, a4.z, a4.w};
          float cv[4] = {c4.x, c4.y, c4.z, c4.w};
#pragma unroll
          for (int i = 0; i < 4; ++i)
#pragma unroll
            for (int j = 0; j < 4; ++j) acc[i][j] += av[i] * cv[j];
        }
      }
#pragma unroll
      for (int i = 0; i < 4; ++i) {
        int t = T0 + tg * 4 + i;
        if (t < TT) {
#pragma unroll
          for (int j = 0; j < 4; ++j) {
            float v = acc[i][j];
            v = v < 0.f ? 0.1f * v : v;
            attn[t * 33 + qg * 4 + j] = v;
          }
        }
      }
      __syncthreads();
    }
  }

  // ---------------- Phase A2: l2norm over q per token row t
  if (tid < TT) {
    float ss = 0.f;
#pragma unroll
    for (int q = 0; q < 32; ++q) {
      float v = attn[tid * 33 + q];
      ss += v * v;
    }
    float rn = 1.0f / fmaxf(sqrtf(ss), EPSN);
#pragma unroll
    for (int q = 0; q < 32; ++q) attn[tid * 33 + q] *= rn;
  }
  __syncthreads();

  // ---------------- Phase A3: softmax (x9) over t per q (denominator dropped;
  //                  exact because ctx is l2-normalized downstream)
  {
    int q = tid >> 3, sub = tid & 7;
    float m = -1e30f;
    for (int t = sub; t < TT; t += 8) m = fmaxf(m, attn[t * 33 + q]);
    m = fmaxf(m, __shfl_xor(m, 1, 64));
    m = fmaxf(m, __shfl_xor(m, 2, 64));
    m = fmaxf(m, __shfl_xor(m, 4, 64));
    for (int t = sub; t < TT; t += 8)
      attn[t * 33 + q] = expf(SMOOTHF * (attn[t * 33 + q] - m));
  }
  __syncthreads();

  // ---------------- Norm via Gram: ||ctx_q||^2 = e_q^T G e_q
  {
    float* nb = (float*)(smem + OFF_NB);
    float* nrmS = (float*)(smem + OFF_NRMS);
    int ty8 = tid >> 5, q = tid & 31;
    float part = 0.f;
    const float* Grow = gram + (size_t)b * TT * TT;
    for (int i = 0; i < 25; ++i) {
      int t = ty8 + i * 8;
      if (t < TT) {
        const float* gr = Grow + (size_t)t * TT;
        float rd = 0.f;
        for (int tp = 0; tp < TT; tp += 4) {
          float4 g4 = *(const float4*)&gr[tp];
          rd += g4.x * attn[tp * 33 + q] + g4.y * attn[(tp + 1) * 33 + q] +
                g4.z * attn[(tp + 2) * 33 + q] + g4.w * attn[(tp + 3) * 33 + q];
        }
        part += attn[t * 33 + q] * rd;
      }
    }
    part += __shfl_xor(part, 32, 64);
    if ((tid & 63) < 32) nb[(tid >> 6) * 32 + q] = part;
    __syncthreads();
    if (tid < 32) {
      float s = nb[tid] + nb[32 + tid] + nb[64 + tid] + nb[96 + tid];
      nrmS[tid] = 1.0f / fmaxf(sqrtf(s), EPSN);
    }
    __syncthreads();
  }

  // ---------------- Phase W: weighted ctx (direct-global img), normalize, diff^2, @W_loc
  float sl[4][8] = {};
  {
    float* wtile = (float*)(smem + OFF_WTILE);
    float* nrmS = (float*)(smem + OFF_NRMS);
    int qg = tid & 7, dg = tid >> 3;
    int sq = tid >> 5, sg = tid & 31;
    for (int d0 = 0; d0 < DD; d0 += 128) {
      float wa[4][4] = {};
      const float* ip = imgB + d0 + dg * 4;
#pragma unroll 2
      for (int t = 0; t < TT; ++t) {
        float4 i4 = *(const float4*)&ip[(size_t)t * DD];
        float a0 = attn[t * 33 + qg * 4 + 0];
        float a1 = attn[t * 33 + qg * 4 + 1];
        float a2 = attn[t * 33 + qg * 4 + 2];
        float a3 = attn[t * 33 + qg * 4 + 3];
        wa[0][0] += a0 * i4.x; wa[0][1] += a0 * i4.y; wa[0][2] += a0 * i4.z; wa[0][3] += a0 * i4.w;
        wa[1][0] += a1 * i4.x; wa[1][1] += a1 * i4.y; wa[1][2] += a1 * i4.z; wa[1][3] += a1 * i4.w;
        wa[2][0] += a2 * i4.x; wa[2][1] += a2 * i4.y; wa[2][2] += a2 * i4.z; wa[2][3] += a2 * i4.w;
        wa[3][0] += a3 * i4.x; wa[3][1] += a3 * i4.y; wa[3][2] += a3 * i4.z; wa[3][3] += a3 * i4.w;
      }
      __syncthreads();  // prev chunk's wtile readers done
#pragma unroll
      for (int i = 0; i < 4; ++i) {
        int q = qg * 4 + i;
        float rn = nrmS[q];
        float4 c4 = *(const float4*)&capC[(size_t)q * DD + d0 + dg * 4];
        float v0 = wa[i][0] * rn - c4.x;
        float v1 = wa[i][1] * rn - c4.y;
        float v2 = wa[i][2] * rn - c4.z;
        float v3 = wa[i][3] * rn - c4.w;
        *(float4*)&wtile[q * 132 + dg * 4] = make_float4(v0 * v0, v1 * v1, v2 * v2, v3 * v3);
      }
      __syncthreads();
      for (int dd = 0; dd < 128; dd += 2) {
        float2 d2a[4];
#pragma unroll
        for (int i = 0; i < 4; ++i) d2a[i] = *(const float2*)&wtile[(sq * 4 + i) * 132 + dd];
#pragma unroll
        for (int u = 0; u < 2; ++u) {
          const float* wp = &W_loc[(size_t)(d0 + dd + u) * SS + sg * 8];
          float4 w0 = *(const float4*)wp;
          float4 w1 = *(const float4*)(wp + 4);
          float wv[8] = {w0.x, w0.y, w0.z, w0.w, w1.x, w1.y, w1.z, w1.w};
#pragma unroll
          for (int i = 0; i < 4; ++i) {
            float dv = u ? d2a[i].y : d2a[i].x;
#pragma unroll
            for (int j = 0; j < 8; ++j) sl[i][j] += dv * wv[j];
          }
        }
      }
      // next iteration's leading sync protects wtile
    }
  }
  __syncthreads();

  // ---------------- sim_emb assembly: l2norm(sim_loc)+bias -> seA rows 1..32; sim_glo row 0
  {
    float* seA = (float*)(smem + OFF_SEA);
    int sq = tid >> 5, sg = tid & 31;
#pragma unroll
    for (int i = 0; i < 4; ++i) {
      float v[8];
      float ssq = 0.f;
#pragma unroll
      for (int j = 0; j < 8; ++j) {
        v[j] = sl[i][j] + b_loc[sg * 8 + j];
        ssq += v[j] * v[j];
      }
      ssq += __shfl_xor(ssq, 1, 64);
      ssq += __shfl_xor(ssq, 2, 64);
      ssq += __shfl_xor(ssq, 4, 64);
      ssq += __shfl_xor(ssq, 8, 64);
      ssq += __shfl_xor(ssq, 16, 64);
      float rn = 1.0f / fmaxf(sqrtf(ssq), EPSN);
      int q = sq * 4 + i;
      *(float4*)&seA[(1 + q) * 260 + sg * 8] =
          make_float4(v[0] * rn, v[1] * rn, v[2] * rn, v[3] * rn);
      *(float4*)&seA[(1 + q) * 260 + sg * 8 + 4] =
          make_float4(v[4] * rn, v[5] * rn, v[6] * rn, v[7] * rn);
    }
    if (tid < 64)
      *(float4*)&seA[tid * 4] = *(const float4*)&simglo[(size_t)p * SS + tid * 4];
  }
  __syncthreads();

  // ---------------- SGR x3 (E via G-tiles; X=seA@Wg in-place; out=E@X in-place)
  {
    float* seA = (float*)(smem + OFF_SEA);
    float* Gb = (float*)(smem + OFF_GB);
    float* Emat = (float*)(smem + OFF_EMAT);
    float* vbuf = (float*)(smem + OFF_VBUF);
    float* wkq = (float*)(smem + OFF_WKQ);
    int gy = tid >> 5, gx = tid & 31;
    int e_n = tid >> 3, e_m = tid & 7;
    int h_r = tid >> 4, h_c = tid & 15;
    int xg = tid >> 6, xc = tid & 63;

    for (int step = 0; step < 3; ++step) {
      const float* Ms = M + (size_t)step * SS * SS;
      const float* Wgs = Wg3 + (size_t)step * SS * SS;
      const float* bgs = bg3 + (size_t)step * SS;
      if (tid < 64)
        *(float4*)&wkq[tid * 4] = *(const float4*)&wkbq[step * SS + tid * 4];
      __syncthreads();
      // vbuf[m] = seA[m] . (Wk@bq)
      if (tid < 132) {
        int m = tid >> 2, qq = tid & 3;
        float a = 0.f;
        for (int e = qq * 64; e < qq * 64 + 64; e += 4) {
          float4 s4 = *(const float4*)&seA[m * 260 + e];
          float4 w4 = *(const float4*)&wkq[e];
          a += s4.x * w4.x + s4.y * w4.y + s4.z * w4.z + s4.w * w4.w;
        }
        a += __shfl_xor(a, 1, 64);
        a += __shfl_xor(a, 2, 64);
        if (qq == 0) vbuf[m] = a;
      }
      // E accumulation over 4 G-tiles of 64 cols
      float eacc[5] = {}, eacc2[5] = {};
      for (int k0 = 0; k0 < SS; k0 += 64) {
        float ga[4][2] = {};
        float gxe[2] = {0.f, 0.f};
        const float* mp = Ms + k0 + gx * 2;
        for (int j = 0; j < SS; j += 4) {
          float4 s4a[4];
#pragma unroll
          for (int u = 0; u < 4; ++u) s4a[u] = *(const float4*)&seA[(gy + 8 * u) * 260 + j];
          float2 mv[4];
#pragma unroll
          for (int jj = 0; jj < 4; ++jj) mv[jj] = *(const float2*)&mp[(size_t)(j + jj) * SS];
#pragma unroll
          for (int u = 0; u < 4; ++u) {
            const float* sp = (const float*)&s4a[u];
#pragma unroll
            for (int jj = 0; jj < 4; ++jj) {
              ga[u][0] += sp[jj] * mv[jj].x;
              ga[u][1] += sp[jj] * mv[jj].y;
            }
          }
          if (gy == 0) {
            float4 sx = *(const float4*)&seA[32 * 260 + j];
            const float* sxp = (const float*)&sx;
#pragma unroll
            for (int jj = 0; jj < 4; ++jj) {
              gxe[0] += sxp[jj] * mv[jj].x;
              gxe[1] += sxp[jj] * mv[jj].y;
            }
          }
        }
        __syncthreads();  // prior Gb readers done
#pragma unroll
        for (int u = 0; u < 4; ++u)
          *(float2*)&Gb[(gy + 8 * u) * 68 + gx * 2] = make_float2(ga[u][0], ga[u][1]);
        if (gy == 0) *(float2*)&Gb[32 * 68 + gx * 2] = make_float2(gxe[0], gxe[1]);
        __syncthreads();
        for (int kk = 0; kk < 64; kk += 4) {
          float4 g4 = *(const float4*)&Gb[e_n * 68 + kk];
          float4 gb4 = make_float4(0.f, 0.f, 0.f, 0.f);
          if (e_n == 0) gb4 = *(const float4*)&Gb[32 * 68 + kk];
#pragma unroll
          for (int j2 = 0; j2 < 4; ++j2) {
            float4 s4 = *(const float4*)&seA[(e_m * 4 + j2) * 260 + k0 + kk];
            eacc[j2] += g4.x * s4.x + g4.y * s4.y + g4.z * s4.z + g4.w * s4.w;
            if (e_n == 0)
              eacc2[j2] += gb4.x * s4.x + gb4.y * s4.y + gb4.z * s4.z + gb4.w * s4.w;
          }
          if (e_m == 7) {
            float4 s4 = *(const float4*)&seA[32 * 260 + k0 + kk];
            eacc[4] += g4.x * s4.x + g4.y * s4.y + g4.z * s4.z + g4.w * s4.w;
            if (e_n == 0)
              eacc2[4] += gb4.x * s4.x + gb4.y * s4.y + gb4.z * s4.z + gb4.w * s4.w;
          }
        }
      }
      // Emat assembly (+vbuf)
#pragma unroll
      for (int j2 = 0; j2 < 4; ++j2)
        Emat[e_n * 36 + e_m * 4 + j2] = eacc[j2] + vbuf[e_m * 4 + j2];
      if (e_m == 7) Emat[e_n * 36 + 32] = eacc[4] + vbuf[32];
      if (e_n == 0) {
#pragma unroll
        for (int j2 = 0; j2 < 4; ++j2)
          Emat[32 * 36 + e_m * 4 + j2] = eacc2[j2] + vbuf[e_m * 4 + j2];
        if (e_m == 7) Emat[32 * 36 + 32] = eacc2[4] + vbuf[32];
      }
      __syncthreads();
      // row softmax of E
      if (tid < NN) {
        float mx = -1e30f;
        for (int mm = 0; mm < NN; ++mm) mx = fmaxf(mx, Emat[tid * 36 + mm]);
        float sum = 0.f;
        for (int mm = 0; mm < NN; ++mm) {
          float e = expf(Emat[tid * 36 + mm] - mx);
          Emat[tid * 36 + mm] = e;
          sum += e;
        }
        float rs = 1.0f / sum;
        for (int mm = 0; mm < NN; ++mm) Emat[tid * 36 + mm] *= rs;
      }
      __syncthreads();
      // X = seA @ Wg, in-place per-row (wave owns row; in-wave read-then-write)
      for (int bi = 0; bi < 9; ++bi) {
        int r = bi * 4 + xg;
        if (r < NN) {
          float xacc[4] = {};
          const float* wp = Wgs + xc * 4;
          for (int k = 0; k < SS; k += 4) {
            float4 s4 = *(const float4*)&seA[r * 260 + k];
            const float* sp = (const float*)&s4;
#pragma unroll
            for (int kk2 = 0; kk2 < 4; ++kk2) {
              float sv = sp[kk2];
              float4 w4 = *(const float4*)&wp[(size_t)(k + kk2) * SS];
              xacc[0] += sv * w4.x;
              xacc[1] += sv * w4.y;
              xacc[2] += sv * w4.z;
              xacc[3] += sv * w4.w;
            }
          }
          *(float4*)&seA[r * 260 + xc * 4] = make_float4(xacc[0], xacc[1], xacc[2], xacc[3]);
        }
      }
      __syncthreads();
      // out = relu(E @ X + bg), in-place per 64-col chunk (col-disjoint)
      for (int k0 = 0; k0 < SS; k0 += 64) {
        float ha[2][4] = {};
        float hx[4] = {0.f, 0.f, 0.f, 0.f};
        for (int mm = 0; mm < NN; ++mm) {
          float e0 = Emat[h_r * 36 + mm];
          float e1 = Emat[(h_r + 16) * 36 + mm];
          float4 x4 = *(const float4*)&seA[mm * 260 + k0 + h_c * 4];
          ha[0][0] += e0 * x4.x; ha[0][1] += e0 * x4.y; ha[0][2] += e0 * x4.z; ha[0][3] += e0 * x4.w;
          ha[1][0] += e1 * x4.x; ha[1][1] += e1 * x4.y; ha[1][2] += e1 * x4.z; ha[1][3] += e1 * x4.w;
          if (h_r == 0) {
            float e2 = Emat[32 * 36 + mm];
            hx[0] += e2 * x4.x; hx[1] += e2 * x4.y; hx[2] += e2 * x4.z; hx[3] += e2 * x4.w;
          }
        }
        float4 b4 = *(const float4*)&bgs[k0 + h_c * 4];
        __syncthreads();  // all X reads of this chunk done
        {
          float v0 = ha[0][0] + b4.x, v1 = ha[0][1] + b4.y, v2 = ha[0][2] + b4.z, v3 = ha[0][3] + b4.w;
          *(float4*)&seA[h_r * 260 + k0 + h_c * 4] =
              make_float4(v0 > 0.f ? v0 : 0.f, v1 > 0.f ? v1 : 0.f, v2 > 0.f ? v2 : 0.f,
                          v3 > 0.f ? v3 : 0.f);
          v0 = ha[1][0] + b4.x; v1 = ha[1][1] + b4.y; v2 = ha[1][2] + b4.z; v3 = ha[1][3] + b4.w;
          *(float4*)&seA[(h_r + 16) * 260 + k0 + h_c * 4] =
              make_float4(v0 > 0.f ? v0 : 0.f, v1 > 0.f ? v1 : 0.f, v2 > 0.f ? v2 : 0.f,
                          v3 > 0.f ? v3 : 0.f);
          if (h_r == 0) {
            v0 = hx[0] + b4.x; v1 = hx[1] + b4.y; v2 = hx[2] + b4.z; v3 = hx[3] + b4.w;
            *(float4*)&seA[32 * 260 + k0 + h_c * 4] =
                make_float4(v0 > 0.f ? v0 : 0.f, v1 > 0.f ? v1 : 0.f, v2 > 0.f ? v2 : 0.f,
                            v3 > 0.f ? v3 : 0.f);
          }
        }
      }
      __syncthreads();
    }
  }

  // ---------------- eval: sigmoid(seA[0] @ W_eval + b_eval)
  if (tid < 64) {
    float* seA = (float*)(smem + OFF_SEA);
    float4 s4 = *(const float4*)&seA[tid * 4];
    float4 w4 = *(const float4*)&W_eval[tid * 4];
    float s = s4.x * w4.x + s4.y * w4.y + s4.z * w4.z + s4.w * w4.w;
    s = warp_reduce_sum64(s);
    if (tid == 0) out[b * 64 + c] = 1.0f / (1.0f + expf(-(s + b_eval[0])));
  }
}

extern "C" void kernel_launch(void* const* d_in, const int* in_sizes, int n_in,
                              void* d_out, int out_size, void* d_ws, size_t ws_size,
                              hipStream_t stream) {
  (void)in_sizes; (void)n_in; (void)out_size; (void)ws_size;
  const float* img = (const float*)d_in[0];
  const float* cap = (const float*)d_in[1];
  const float* vG_Wl = (const float*)d_in[3];
  const float* vG_bl = (const float*)d_in[4];
  const float* vG_Wg = (const float*)d_in[5];
  const float* vG_bg = (const float*)d_in[6];
  const float* vG_Wc = (const float*)d_in[7];
  const float* vG_bc = (const float*)d_in[8];
  const float* tG_Wl = (const float*)d_in[9];
  const float* tG_bl = (const float*)d_in[10];
  const float* tG_Wg = (const float*)d_in[11];
  const float* tG_bg = (const float*)d_in[12];
  const float* tG_Wc = (const float*)d_in[13];
  const float* tG_bc = (const float*)d_in[14];
  const float* W_loc = (const float*)d_in[15];
  const float* b_loc = (const float*)d_in[16];
  const float* W_glo = (const float*)d_in[17];
  const float* b_glo = (const float*)d_in[18];
  const float* W_eval = (const float*)d_in[19];
  const float* b_eval = (const float*)d_in[20];
  const float* sgr_Wq = (const float*)d_in[21];
  const float* sgr_bq = (const float*)d_in[22];
  const float* sgr_Wk = (const float*)d_in[23];
  const float* sgr_Wg = (const float*)d_in[25];
  const float* sgr_bg = (const float*)d_in[26];
  float* out = (float*)d_out;
  float* ws = (float*)d_ws;
  float* img_avg = ws;
  float* cap_avg = ws + 65536;
  float* h_img = ws + 131072;
  float* h_cap = ws + 196608;
  float* part_img = ws + 262144;
  float* part_cap = ws + 462848;
  float* img_glob = ws + 495616;
  float* cap_glob = ws + 561152;
  float* simglo = ws + 626688;
  float* Mmat = ws + 1675264;
  float* wkbqv = ws + 1871872;
  float* gramb = ws + 1875968;  // 64*196*196 = 2458624 floats

  k_avg<<<128, 256, 0, stream>>>(img, cap, img_avg, cap_avg);
  k_hvec<<<256, 256, 0, stream>>>(img_avg, vG_Wg, vG_bg, vG_Wc, h_img);
  k_hvec<<<256, 256, 0, stream>>>(cap_avg, tG_Wg, tG_bg, tG_Wc, h_cap);
  k_logits_partial<<<dim3(196, 16), 256, 0, stream>>>(img + DD, (long)NTOK * DD, TT, vG_Wl,
                                                      vG_bl, h_img, part_img);
  k_logits_partial<<<dim3(32, 16), 256, 0, stream>>>(cap, (long)CL * DD, CL, tG_Wl, tG_bl,
                                                     h_cap, part_cap);
  k_finish_global<<<64, 256, 0, stream>>>(part_img, vG_bc, img + DD, (long)NTOK * DD, TT,
                                          img_glob);
  k_finish_global<<<64, 256, 0, stream>>>(part_cap, tG_bc, cap, (long)CL * DD, CL, cap_glob);
  k_simglo<<<256, 256, 0, stream>>>(img_glob, cap_glob, W_glo, b_glo, simglo);
  k_mmat<<<48, 256, 0, stream>>>(sgr_Wq, sgr_Wk, Mmat);
  k_wkbq<<<3, 256, 0, stream>>>(sgr_Wk, sgr_bq, wkbqv);
  k_gram<<<dim3(64, 4, 4), 256, 0, stream>>>(img, gramb);
  hipFuncSetAttribute((const void*)k_pair, hipFuncAttributeMaxDynamicSharedMemorySize,
                      SMEM_BYTES);
  k_pair<<<4096, 256, SMEM_BYTES, stream>>>(img, cap, W_loc, b_loc, simglo, Mmat, wkbqv,
                                            sgr_Wg, sgr_bg, W_eval, b_eval, gramb, out);
}

// Round 4
// 9919.930 us; speedup vs baseline: 2.3321x; 1.8816x over previous
//
#include <hip/hip_runtime.h>
#include <hip/hip_bf16.h>
#include <math.h>

#define NI 64
#define NC 64
#define NTOK 197
#define TT 196
#define CL 32
#define DD 1024
#define SS 256
#define NN 33
#define EPSN 1e-12f
#define SMOOTHF 9.0f

// LDS layout (byte offsets)
#define OFF_ATTN   0        // [196][33] f32 = 25872 (phases A..W)
#define OFF_STG    25872    // 16896 B: aK[32][132] (A) / Gt[16][200] (norm) / wtile[32][132] (W)
#define OFF_STG2   42768    // 8448 B:  cK[32][36] (A) / imgK[16][132] (W)
#define OFF_NB     51216    // [128] f32
#define OFF_NRMS   51728    // [32] f32
// SGR overlays (attn/stg dead by then)
#define OFF_SEA    0        // [33][260] f32 = 34320
#define OFF_GB     34320    // [33][68]  f32 = 8976
#define OFF_EMAT   43296    // [33][36]  f32 = 4752
#define OFF_VBUF   48048    // [33] f32 (pad to 144)
#define OFF_WKQ    48192    // [256] f32
#define SMEM_BYTES 51856

__device__ __forceinline__ float warp_reduce_sum64(float v) {
#pragma unroll
  for (int m = 32; m > 0; m >>= 1) v += __shfl_xor(v, m, 64);
  return v;
}

// ---------------------------------------------------------------- K1: means
__global__ void k_avg(const float* __restrict__ img, const float* __restrict__ cap,
                      float* __restrict__ img_avg, float* __restrict__ cap_avg) {
  int bid = blockIdx.x;
  int tid = threadIdx.x;
  if (bid < NI) {
    int b = bid;
    for (int d = tid; d < DD; d += 256) {
      float acc = 0.f;
      const float* p = img + ((size_t)b * NTOK + 1) * DD + d;
      for (int t = 0; t < TT; ++t) acc += p[(size_t)t * DD];
      img_avg[b * DD + d] = acc * (1.0f / TT);
    }
  } else {
    int c = bid - NI;
    for (int d = tid; d < DD; d += 256) {
      float acc = 0.f;
      const float* p = cap + (size_t)c * CL * DD + d;
      for (int t = 0; t < CL; ++t) acc += p[(size_t)t * DD];
      cap_avg[c * DD + d] = acc * (1.0f / CL);
    }
  }
}

// ------------------------------------------------- K2: h = tanh(avg@Wg+bg)*Wc
__global__ void k_hvec(const float* __restrict__ avg, const float* __restrict__ Wg,
                       const float* __restrict__ bg, const float* __restrict__ Wc,
                       float* __restrict__ h) {
  __shared__ float av[DD];
  int b = blockIdx.x >> 2;
  int dc = blockIdx.x & 3;
  int tid = threadIdx.x;
  for (int i = tid; i < DD; i += 256) av[i] = avg[b * DD + i];
  __syncthreads();
  int d = dc * 256 + tid;
  float acc = 0.f;
  for (int k = 0; k < DD; k += 4) {
    float4 a4 = *(const float4*)&av[k];
    acc += a4.x * Wg[(size_t)(k + 0) * DD + d];
    acc += a4.y * Wg[(size_t)(k + 1) * DD + d];
    acc += a4.z * Wg[(size_t)(k + 2) * DD + d];
    acc += a4.w * Wg[(size_t)(k + 3) * DD + d];
  }
  h[b * DD + d] = tanhf(acc + bg[d]) * Wc[d];
}

// ---------------- K3: partial[row,ct] = sum_{d in col-tile} tanh((A@Wl)[row,d]+bl)*h[b,d]
__global__ void k_logits_partial(const float* __restrict__ Abase, long batchStride, int rowsPerBatch,
                                 const float* __restrict__ Wl, const float* __restrict__ bl,
                                 const float* __restrict__ h, float* __restrict__ partial) {
  __shared__ float a_lds[32][68];
  __shared__ float b_lds[32][68];
  int tid = threadIdx.x;
  int rb = blockIdx.x * 64;
  int c0 = blockIdx.y * 64;
  int ty = tid >> 4, tx = tid & 15;
  int s_rr = tid >> 2, s_kq = tid & 3;
  int rA = rb + s_rr;
  const float* aRow = Abase + (size_t)(rA / rowsPerBatch) * batchStride + (size_t)(rA % rowsPerBatch) * DD;
  int s_kk = tid >> 3, s_cq = tid & 7;
  float acc[4][4] = {};
  for (int k0 = 0; k0 < DD; k0 += 32) {
    float4 v0 = *(const float4*)&aRow[k0 + s_kq * 8];
    float4 v1 = *(const float4*)&aRow[k0 + s_kq * 8 + 4];
    float4 w0 = *(const float4*)&Wl[(size_t)(k0 + s_kk) * DD + c0 + s_cq * 8];
    float4 w1 = *(const float4*)&Wl[(size_t)(k0 + s_kk) * DD + c0 + s_cq * 8 + 4];
    __syncthreads();
    float va[8] = {v0.x, v0.y, v0.z, v0.w, v1.x, v1.y, v1.z, v1.w};
#pragma unroll
    for (int u = 0; u < 8; ++u) a_lds[s_kq * 8 + u][s_rr] = va[u];
    *(float4*)&b_lds[s_kk][s_cq * 8] = w0;
    *(float4*)&b_lds[s_kk][s_cq * 8 + 4] = w1;
    __syncthreads();
#pragma unroll
    for (int kk = 0; kk < 32; ++kk) {
      float4 a4 = *(const float4*)&a_lds[kk][ty * 4];
      float4 b4 = *(const float4*)&b_lds[kk][tx * 4];
      float av[4] = {a4.x, a4.y, a4.z, a4.w};
      float bv[4] = {b4.x, b4.y, b4.z, b4.w};
#pragma unroll
      for (int i = 0; i < 4; ++i)
#pragma unroll
        for (int j = 0; j < 4; ++j) acc[i][j] += av[i] * bv[j];
    }
  }
#pragma unroll
  for (int i = 0; i < 4; ++i) {
    int r = rb + ty * 4 + i;
    int bb = r / rowsPerBatch;
    float s = 0.f;
#pragma unroll
    for (int j = 0; j < 4; ++j) {
      int cc = c0 + tx * 4 + j;
      s += tanhf(acc[i][j] + bl[cc]) * h[bb * DD + cc];
    }
    s += __shfl_xor(s, 1, 64);
    s += __shfl_xor(s, 2, 64);
    s += __shfl_xor(s, 4, 64);
    s += __shfl_xor(s, 8, 64);
    if (tx == 0) partial[(size_t)r * 16 + blockIdx.y] = s;
  }
}

// -------- K4: logits -> softmax weights -> weighted sum of tokens -> l2norm
__global__ void k_finish_global(const float* __restrict__ partial, const float* __restrict__ bc,
                                const float* __restrict__ Xbase, long batchStride, int R,
                                float* __restrict__ outG) {
  __shared__ float w[200];
  __shared__ float red[8];
  int b = blockIdx.x, tid = threadIdx.x;
  for (int t = tid; t < R; t += 256) {
    const float* pp = &partial[((size_t)b * R + t) * 16];
    float s = bc[0];
#pragma unroll
    for (int u = 0; u < 16; ++u) s += pp[u];
    w[t] = s;
  }
  __syncthreads();
  float m = -1e30f;
  for (int t = tid; t < R; t += 256) m = fmaxf(m, w[t]);
#pragma unroll
  for (int mm = 32; mm; mm >>= 1) m = fmaxf(m, __shfl_xor(m, mm, 64));
  if ((tid & 63) == 0) red[tid >> 6] = m;
  __syncthreads();
  m = fmaxf(fmaxf(red[0], red[1]), fmaxf(red[2], red[3]));
  __syncthreads();
  for (int t = tid; t < R; t += 256) w[t] = expf(w[t] - m);
  __syncthreads();
  const float* xb = Xbase + (size_t)b * batchStride;
  float acc[4];
  float ss = 0.f;
#pragma unroll
  for (int c4 = 0; c4 < 4; ++c4) {
    int d = tid + c4 * 256;
    float a = 0.f;
    for (int t = 0; t < R; ++t) a += w[t] * xb[(size_t)t * DD + d];
    acc[c4] = a;
    ss += a * a;
  }
  ss = warp_reduce_sum64(ss);
  if ((tid & 63) == 0) red[tid >> 6] = ss;
  __syncthreads();
  ss = red[0] + red[1] + red[2] + red[3];
  float rn = 1.0f / fmaxf(sqrtf(ss), EPSN);
#pragma unroll
  for (int c4 = 0; c4 < 4; ++c4) outG[(size_t)b * DD + tid + c4 * 256] = acc[c4] * rn;
}

// -------- K5: sim_glo[p] = l2norm((img_g[b]-cap_g[c])^2 @ W_glo + b_glo), p=b*64+c
__global__ void k_simglo(const float* __restrict__ ig, const float* __restrict__ cg,
                         const float* __restrict__ W, const float* __restrict__ bgl,
                         float* __restrict__ simglo) {
  __shared__ float a_lds[32][20];
  __shared__ float b_lds[32][260];
  int tid = threadIdx.x;
  int p0 = blockIdx.x * 16;
  int ty = tid >> 6, tx = tid & 63;
  int s_rr = tid >> 3, s_kq = tid & 7;
  float acc[4][4] = {};
  for (int k0 = 0; k0 < DD; k0 += 32) {
    float d2[4] = {};
    if (tid < 128) {
      int p = p0 + s_rr;
      int b = p >> 6, c = p & 63;
      float4 giv = *(const float4*)&ig[b * DD + k0 + s_kq * 4];
      float4 cgv = *(const float4*)&cg[c * DD + k0 + s_kq * 4];
      float dx = giv.x - cgv.x, dy = giv.y - cgv.y, dz = giv.z - cgv.z, dw = giv.w - cgv.w;
      d2[0] = dx * dx; d2[1] = dy * dy; d2[2] = dz * dz; d2[3] = dw * dw;
    }
    float4 wv[8];
#pragma unroll
    for (int u = 0; u < 8; ++u)
      wv[u] = *(const float4*)&W[(size_t)(k0 + s_rr) * SS + s_kq * 32 + u * 4];
    __syncthreads();
    if (tid < 128) {
#pragma unroll
      for (int u = 0; u < 4; ++u) a_lds[s_kq * 4 + u][s_rr] = d2[u];
    }
#pragma unroll
    for (int u = 0; u < 8; ++u)
      *(float4*)&b_lds[s_rr][s_kq * 32 + u * 4] = wv[u];
    __syncthreads();
#pragma unroll
    for (int kk = 0; kk < 32; ++kk) {
      float4 a4 = *(const float4*)&a_lds[kk][ty * 4];
      float4 b4 = *(const float4*)&b_lds[kk][tx * 4];
      float av[4] = {a4.x, a4.y, a4.z, a4.w};
      float bv[4] = {b4.x, b4.y, b4.z, b4.w};
#pragma unroll
      for (int i = 0; i < 4; ++i)
#pragma unroll
        for (int j = 0; j < 4; ++j) acc[i][j] += av[i] * bv[j];
    }
  }
#pragma unroll
  for (int i = 0; i < 4; ++i) {
    float v[4];
    float ssq = 0.f;
#pragma unroll
    for (int j = 0; j < 4; ++j) {
      v[j] = acc[i][j] + bgl[tx * 4 + j];
      ssq += v[j] * v[j];
    }
    ssq = warp_reduce_sum64(ssq);
    float rn = 1.0f / fmaxf(sqrtf(ssq), EPSN);
    int p = p0 + ty * 4 + i;
    *(float4*)&simglo[(size_t)p * SS + tx * 4] =
        make_float4(v[0] * rn, v[1] * rn, v[2] * rn, v[3] * rn);
  }
}

// -------- K6: M[t] = Wq_t @ Wk_t^T  (256x256)
__global__ void k_mmat(const float* __restrict__ Wq, const float* __restrict__ Wk,
                       float* __restrict__ M) {
  __shared__ float a_lds[32][68];
  __shared__ float b_lds[32][68];
  int tid = threadIdx.x;
  int t = blockIdx.x >> 4;
  int dt = (blockIdx.x >> 2) & 3, et = blockIdx.x & 3;
  int d0 = dt * 64, e0 = et * 64;
  const float* wq = Wq + (size_t)t * SS * SS;
  const float* wk = Wk + (size_t)t * SS * SS;
  int ty = tid >> 4, tx = tid & 15;
  int s_rr = tid >> 2, s_kq = tid & 3;
  float acc[4][4] = {};
  for (int j0 = 0; j0 < SS; j0 += 32) {
    float4 q0 = *(const float4*)&wq[(size_t)(d0 + s_rr) * SS + j0 + s_kq * 8];
    float4 q1 = *(const float4*)&wq[(size_t)(d0 + s_rr) * SS + j0 + s_kq * 8 + 4];
    float4 k0v = *(const float4*)&wk[(size_t)(e0 + s_rr) * SS + j0 + s_kq * 8];
    float4 k1v = *(const float4*)&wk[(size_t)(e0 + s_rr) * SS + j0 + s_kq * 8 + 4];
    __syncthreads();
    float qa[8] = {q0.x, q0.y, q0.z, q0.w, q1.x, q1.y, q1.z, q1.w};
    float ka[8] = {k0v.x, k0v.y, k0v.z, k0v.w, k1v.x, k1v.y, k1v.z, k1v.w};
#pragma unroll
    for (int u = 0; u < 8; ++u) {
      a_lds[s_kq * 8 + u][s_rr] = qa[u];
      b_lds[s_kq * 8 + u][s_rr] = ka[u];
    }
    __syncthreads();
#pragma unroll
    for (int kk = 0; kk < 32; ++kk) {
      float4 a4 = *(const float4*)&a_lds[kk][ty * 4];
      float4 b4 = *(const float4*)&b_lds[kk][tx * 4];
      float av[4] = {a4.x, a4.y, a4.z, a4.w};
      float bv[4] = {b4.x, b4.y, b4.z, b4.w};
#pragma unroll
      for (int i = 0; i < 4; ++i)
#pragma unroll
        for (int j = 0; j < 4; ++j) acc[i][j] += av[i] * bv[j];
    }
  }
#pragma unroll
  for (int i = 0; i < 4; ++i)
    *(float4*)&M[(size_t)t * SS * SS + (size_t)(d0 + ty * 4 + i) * SS + e0 + tx * 4] =
        make_float4(acc[i][0], acc[i][1], acc[i][2], acc[i][3]);
}

// -------- K6b: wkbq[t] = Wk_t @ bq_t
__global__ void k_wkbq(const float* __restrict__ Wk, const float* __restrict__ bq,
                       float* __restrict__ out) {
  __shared__ float bv[SS];
  int t = blockIdx.x, tid = threadIdx.x;
  const float* wk = Wk + (size_t)t * SS * SS;
  bv[tid] = bq[t * SS + tid];
  __syncthreads();
  float acc = 0.f;
  for (int j = 0; j < SS; j += 4) {
    float4 wv = *(const float4*)&wk[(size_t)tid * SS + j];
    float4 b4 = *(const float4*)&bv[j];
    acc += wv.x * b4.x + wv.y * b4.y + wv.z * b4.z + wv.w * b4.w;
  }
  out[t * SS + tid] = acc;
}

// -------- K6c: gram[b] = imgTok_b @ imgTok_b^T (196x196)
__global__ void k_gram(const float* __restrict__ img, float* __restrict__ gram) {
  __shared__ float a_lds[32][68];
  __shared__ float b_lds[32][68];
  int tid = threadIdx.x;
  int bimg = blockIdx.x;
  int rb = blockIdx.y * 64;
  int cb = blockIdx.z * 64;
  const float* X = img + ((size_t)bimg * NTOK + 1) * DD;
  int ty = tid >> 4, tx = tid & 15;
  int s_rr = tid >> 2, s_kq = tid & 3;
  int rA = rb + s_rr; if (rA > TT - 1) rA = TT - 1;
  int rB = cb + s_rr; if (rB > TT - 1) rB = TT - 1;
  const float* aRow = X + (size_t)rA * DD;
  const float* bRow = X + (size_t)rB * DD;
  float acc[4][4] = {};
  for (int k0 = 0; k0 < DD; k0 += 32) {
    float4 v0 = *(const float4*)&aRow[k0 + s_kq * 8];
    float4 v1 = *(const float4*)&aRow[k0 + s_kq * 8 + 4];
    float4 w0 = *(const float4*)&bRow[k0 + s_kq * 8];
    float4 w1 = *(const float4*)&bRow[k0 + s_kq * 8 + 4];
    __syncthreads();
    float va[8] = {v0.x, v0.y, v0.z, v0.w, v1.x, v1.y, v1.z, v1.w};
    float wa[8] = {w0.x, w0.y, w0.z, w0.w, w1.x, w1.y, w1.z, w1.w};
#pragma unroll
    for (int u = 0; u < 8; ++u) {
      a_lds[s_kq * 8 + u][s_rr] = va[u];
      b_lds[s_kq * 8 + u][s_rr] = wa[u];
    }
    __syncthreads();
#pragma unroll
    for (int kk = 0; kk < 32; ++kk) {
      float4 a4 = *(const float4*)&a_lds[kk][ty * 4];
      float4 b4 = *(const float4*)&b_lds[kk][tx * 4];
      float av[4] = {a4.x, a4.y, a4.z, a4.w};
      float bv[4] = {b4.x, b4.y, b4.z, b4.w};
#pragma unroll
      for (int i = 0; i < 4; ++i)
#pragma unroll
        for (int j = 0; j < 4; ++j) acc[i][j] += av[i] * bv[j];
    }
  }
  float* Gp = gram + (size_t)bimg * TT * TT;
#pragma unroll
  for (int i = 0; i < 4; ++i) {
    int r = rb + ty * 4 + i;
    if (r < TT) {
#pragma unroll
      for (int j = 0; j < 4; ++j) {
        int c2 = cb + tx * 4 + j;
        if (c2 < TT) Gp[(size_t)r * TT + c2] = acc[i][j];
      }
    }
  }
}

// -------- K7: per-(img,cap) pair mega kernel (v4: fully LDS-staged, 3 blk/CU)
__global__ __launch_bounds__(256, 3) void k_pair(
    const float* __restrict__ img, const float* __restrict__ cap,
    const float* __restrict__ W_loc, const float* __restrict__ b_loc,
    const float* __restrict__ simglo, const float* __restrict__ M,
    const float* __restrict__ wkbq, const float* __restrict__ Wg3,
    const float* __restrict__ bg3, const float* __restrict__ W_eval,
    const float* __restrict__ b_eval, const float* __restrict__ gram,
    float* __restrict__ out) {
  extern __shared__ char smem[];
  float* attn = (float*)(smem + OFF_ATTN);

  int tid = threadIdx.x;
  int p = blockIdx.x;
  int b = p >> 6, c = p & 63;
  const float* imgB = img + ((size_t)b * NTOK + 1) * DD;
  const float* capC = cap + (size_t)c * CL * DD;

  // ---------------- Phase A: attn[t][q] = leaky(img_tok[t] . cap[q]), 128t x 32q tiles
  {
    float* aK = (float*)(smem + OFF_STG);   // [32][132] k-major
    float* cK = (float*)(smem + OFF_STG2);  // [32][36]  k-major
    int tg = tid & 31, qg = tid >> 5;
    int s_rr = tid >> 1, s_kq = tid & 1;
    int c_q = tid >> 2, c_k = tid & 3;
    for (int T0 = 0; T0 < TT; T0 += 128) {
      float acc[4][4] = {};
      for (int k0 = 0; k0 < DD; k0 += 32) {
        int trow = T0 + s_rr;
        float va[16];
        if (trow < TT) {
          const float* pr = &imgB[(size_t)trow * DD + k0 + s_kq * 16];
          float4 v0 = *(const float4*)pr;
          float4 v1 = *(const float4*)(pr + 4);
          float4 v2 = *(const float4*)(pr + 8);
          float4 v3 = *(const float4*)(pr + 12);
          va[0] = v0.x; va[1] = v0.y; va[2] = v0.z; va[3] = v0.w;
          va[4] = v1.x; va[5] = v1.y; va[6] = v1.z; va[7] = v1.w;
          va[8] = v2.x; va[9] = v2.y; va[10] = v2.z; va[11] = v2.w;
          va[12] = v3.x; va[13] = v3.y; va[14] = v3.z; va[15] = v3.w;
        } else {
#pragma unroll
          for (int u = 0; u < 16; ++u) va[u] = 0.f;
        }
        float ca[8];
        if (tid < 128) {
          const float* pc = &capC[(size_t)c_q * DD + k0 + c_k * 8];
          float4 c0v = *(const float4*)pc;
          float4 c1v = *(const float4*)(pc + 4);
          ca[0] = c0v.x; ca[1] = c0v.y; ca[2] = c0v.z; ca[3] = c0v.w;
          ca[4] = c1v.x; ca[5] = c1v.y; ca[6] = c1v.z; ca[7] = c1v.w;
        }
        __syncthreads();
#pragma unroll
        for (int u = 0; u < 16; ++u) aK[(s_kq * 16 + u) * 132 + s_rr] = va[u];
        if (tid < 128) {
#pragma unroll
          for (int u = 0; u < 8; ++u) cK[(c_k * 8 + u) * 36 + c_q] = ca[u];
        }
        __syncthreads();
#pragma unroll
        for (int kk = 0; kk < 32; ++kk) {
          float4 a4 = *(const float4*)&aK[kk * 132 + tg * 4];
          float4 c4 = *(const float4*)&cK[kk * 36 + qg * 4];
          float av[4] = {a4.x, a4.y, a4.z, a4.w};
          float cv[4] = {c4.x, c4.y, c4.z, c4.w};
#pragma unroll
          for (int i = 0; i < 4; ++i)
#pragma unroll
            for (int j = 0; j < 4; ++j) acc[i][j] += av[i] * cv[j];
        }
      }
#pragma unroll
      for (int i = 0; i < 4; ++i) {
        int t = T0 + tg * 4 + i;
        if (t < TT) {
#pragma unroll
          for (int j = 0; j < 4; ++j) {
            float v = acc[i][j];
            v = v < 0.f ? 0.1f * v : v;
            attn[t * 33 + qg * 4 + j] = v;
          }
        }
      }
      __syncthreads();
    }
  }

  // ---------------- Phase A2: l2norm over q per token row t
  if (tid < TT) {
    float ss = 0.f;
#pragma unroll
    for (int q = 0; q < 32; ++q) {
      float v = attn[tid * 33 + q];
      ss += v * v;
    }
    float rn = 1.0f / fmaxf(sqrtf(ss), EPSN);
#pragma unroll
    for (int q = 0; q < 32; ++q) attn[tid * 33 + q] *= rn;
  }
  __syncthreads();

  // ---------------- Phase A3: softmax (x9) over t per q (denominator dropped;
  //                  exact because ctx is l2-normalized downstream)
  {
    int q = tid >> 3, sub = tid & 7;
    float m = -1e30f;
    for (int t = sub; t < TT; t += 8) m = fmaxf(m, attn[t * 33 + q]);
    m = fmaxf(m, __shfl_xor(m, 1, 64));
    m = fmaxf(m, __shfl_xor(m, 2, 64));
    m = fmaxf(m, __shfl_xor(m, 4, 64));
    for (int t = sub; t < TT; t += 8)
      attn[t * 33 + q] = expf(SMOOTHF * (attn[t * 33 + q] - m));
  }
  __syncthreads();

  // ---------------- Norm via Gram (LDS-tiled): ||ctx_q||^2 = e_q^T G e_q
  {
    float* Gt = (float*)(smem + OFF_STG);   // [16][200]
    float* nb = (float*)(smem + OFF_NB);
    float* nrmS = (float*)(smem + OFF_NRMS);
    int q = tid & 31, tr = tid >> 5;  // tr in [0,8)
    const float* Grow = gram + (size_t)b * TT * TT;
    float part = 0.f;
    for (int t0 = 0; t0 < TT; t0 += 16) {
      int nrow = TT - t0;
      if (nrow > 16) nrow = 16;
      __syncthreads();  // prior readers of Gt done
      for (int i = tid; i < nrow * 49; i += 256) {
        int r = i / 49, c4 = i - r * 49;
        *(float4*)&Gt[r * 200 + c4 * 4] = *(const float4*)&Grow[(size_t)(t0 + r) * TT + c4 * 4];
      }
      __syncthreads();
      float s0 = 0.f, s1 = 0.f;
      for (int tp = 0; tp < TT; tp += 4) {
        float4 g0 = *(const float4*)&Gt[tr * 200 + tp];
        float4 g1 = *(const float4*)&Gt[(tr + 8) * 200 + tp];
        float e0 = attn[tp * 33 + q];
        float e1 = attn[(tp + 1) * 33 + q];
        float e2 = attn[(tp + 2) * 33 + q];
        float e3 = attn[(tp + 3) * 33 + q];
        s0 += g0.x * e0 + g0.y * e1 + g0.z * e2 + g0.w * e3;
        s1 += g1.x * e0 + g1.y * e1 + g1.z * e2 + g1.w * e3;
      }
      if (t0 + tr < TT) part += attn[(t0 + tr) * 33 + q] * s0;
      if (t0 + tr + 8 < TT) part += attn[(t0 + tr + 8) * 33 + q] * s1;
    }
    part += __shfl_xor(part, 32, 64);
    if ((tid & 63) < 32) nb[(tid >> 6) * 32 + q] = part;
    __syncthreads();
    if (tid < 32) {
      float s = nb[tid] + nb[32 + tid] + nb[64 + tid] + nb[96 + tid];
      nrmS[tid] = 1.0f / fmaxf(sqrtf(s), EPSN);
    }
    __syncthreads();
  }

  // ---------------- Phase W: staged weighted ctx, normalize, diff^2, @W_loc
  float sl[4][8] = {};
  {
    float* wtile = (float*)(smem + OFF_STG);   // [32][132]
    float* imgK = (float*)(smem + OFF_STG2);   // [16][132]
    float* nrmS = (float*)(smem + OFF_NRMS);
    int qg = tid & 7, dg = tid >> 3;           // weighted-pass mapping
    int s_tt = tid >> 4, s_dq = tid & 15;      // staging mapping
    int sq = tid >> 5, sg = tid & 31;          // W_loc mapping
    for (int d0 = 0; d0 < DD; d0 += 128) {
      float wa[4][4] = {};
      for (int t0 = 0; t0 < TT; t0 += 16) {
        int trow = t0 + s_tt;
        float4 i0 = {}, i1 = {};
        if (trow < TT) {
          const float* pr = &imgB[(size_t)trow * DD + d0 + s_dq * 8];
          i0 = *(const float4*)pr;
          i1 = *(const float4*)(pr + 4);
        }
        __syncthreads();
        *(float4*)&imgK[s_tt * 132 + s_dq * 8] = i0;
        *(float4*)&imgK[s_tt * 132 + s_dq * 8 + 4] = i1;
        __syncthreads();
        int kn = TT - t0;
        if (kn > 16) kn = 16;
        for (int kk = 0; kk < kn; ++kk) {
          float av[4];
#pragma unroll
          for (int j = 0; j < 4; ++j) av[j] = attn[(t0 + kk) * 33 + qg * 4 + j];
          float4 i4 = *(const float4*)&imgK[kk * 132 + dg * 4];
          float iv[4] = {i4.x, i4.y, i4.z, i4.w};
#pragma unroll
          for (int i = 0; i < 4; ++i)
#pragma unroll
            for (int j = 0; j < 4; ++j) wa[i][j] += av[i] * iv[j];
        }
      }
      __syncthreads();  // prev-chunk W_loc readers of wtile done
#pragma unroll
      for (int i = 0; i < 4; ++i) {
        int q = qg * 4 + i;
        float rn = nrmS[q];
        float4 c4 = *(const float4*)&capC[(size_t)q * DD + d0 + dg * 4];
        float v0 = wa[i][0] * rn - c4.x;
        float v1 = wa[i][1] * rn - c4.y;
        float v2 = wa[i][2] * rn - c4.z;
        float v3 = wa[i][3] * rn - c4.w;
        *(float4*)&wtile[q * 132 + dg * 4] = make_float4(v0 * v0, v1 * v1, v2 * v2, v3 * v3);
      }
      __syncthreads();
      for (int dd = 0; dd < 128; dd += 2) {
        float2 d2a[4];
#pragma unroll
        for (int i = 0; i < 4; ++i) d2a[i] = *(const float2*)&wtile[(sq * 4 + i) * 132 + dd];
#pragma unroll
        for (int u = 0; u < 2; ++u) {
          const float* wp = &W_loc[(size_t)(d0 + dd + u) * SS + sg * 8];
          float4 w0 = *(const float4*)wp;
          float4 w1 = *(const float4*)(wp + 4);
          float wv[8] = {w0.x, w0.y, w0.z, w0.w, w1.x, w1.y, w1.z, w1.w};
#pragma unroll
          for (int i = 0; i < 4; ++i) {
            float dv = u ? d2a[i].y : d2a[i].x;
#pragma unroll
            for (int j = 0; j < 8; ++j) sl[i][j] += dv * wv[j];
          }
        }
      }
      __syncthreads();  // wtile reads done before next chunk overwrites
    }
  }
  __syncthreads();

  // ---------------- sim_emb assembly: l2norm(sim_loc)+bias -> seA rows 1..32; sim_glo row 0
  {
    float* seA = (float*)(smem + OFF_SEA);
    int sq = tid >> 5, sg = tid & 31;
#pragma unroll
    for (int i = 0; i < 4; ++i) {
      float v[8];
      float ssq = 0.f;
#pragma unroll
      for (int j = 0; j < 8; ++j) {
        v[j] = sl[i][j] + b_loc[sg * 8 + j];
        ssq += v[j] * v[j];
      }
      ssq += __shfl_xor(ssq, 1, 64);
      ssq += __shfl_xor(ssq, 2, 64);
      ssq += __shfl_xor(ssq, 4, 64);
      ssq += __shfl_xor(ssq, 8, 64);
      ssq += __shfl_xor(ssq, 16, 64);
      float rn = 1.0f / fmaxf(sqrtf(ssq), EPSN);
      int q = sq * 4 + i;
      *(float4*)&seA[(1 + q) * 260 + sg * 8] =
          make_float4(v[0] * rn, v[1] * rn, v[2] * rn, v[3] * rn);
      *(float4*)&seA[(1 + q) * 260 + sg * 8 + 4] =
          make_float4(v[4] * rn, v[5] * rn, v[6] * rn, v[7] * rn);
    }
    if (tid < 64)
      *(float4*)&seA[tid * 4] = *(const float4*)&simglo[(size_t)p * SS + tid * 4];
  }
  __syncthreads();

  // ---------------- SGR x3 (E via G-tiles; X=seA@Wg in-place; out=E@X in-place)
  {
    float* seA = (float*)(smem + OFF_SEA);
    float* Gb = (float*)(smem + OFF_GB);
    float* Emat = (float*)(smem + OFF_EMAT);
    float* vbuf = (float*)(smem + OFF_VBUF);
    float* wkq = (float*)(smem + OFF_WKQ);
    int gy = tid >> 5, gx = tid & 31;
    int e_n = tid >> 3, e_m = tid & 7;
    int h_r = tid >> 4, h_c = tid & 15;
    int xg = tid >> 6, xc = tid & 63;

    for (int step = 0; step < 3; ++step) {
      const float* Ms = M + (size_t)step * SS * SS;
      const float* Wgs = Wg3 + (size_t)step * SS * SS;
      const float* bgs = bg3 + (size_t)step * SS;
      if (tid < 64)
        *(float4*)&wkq[tid * 4] = *(const float4*)&wkbq[step * SS + tid * 4];
      __syncthreads();
      // vbuf[m] = seA[m] . (Wk@bq)
      if (tid < 132) {
        int m = tid >> 2, qq = tid & 3;
        float a = 0.f;
        for (int e = qq * 64; e < qq * 64 + 64; e += 4) {
          float4 s4 = *(const float4*)&seA[m * 260 + e];
          float4 w4 = *(const float4*)&wkq[e];
          a += s4.x * w4.x + s4.y * w4.y + s4.z * w4.z + s4.w * w4.w;
        }
        a += __shfl_xor(a, 1, 64);
        a += __shfl_xor(a, 2, 64);
        if (qq == 0) vbuf[m] = a;
      }
      // E accumulation over 4 G-tiles of 64 cols
      float eacc[5] = {}, eacc2[5] = {};
      for (int k0 = 0; k0 < SS; k0 += 64) {
        float ga[4][2] = {};
        float gxe[2] = {0.f, 0.f};
        const float* mp = Ms + k0 + gx * 2;
        for (int j = 0; j < SS; j += 4) {
          float4 s4a[4];
#pragma unroll
          for (int u = 0; u < 4; ++u) s4a[u] = *(const float4*)&seA[(gy + 8 * u) * 260 + j];
          float2 mv[4];
#pragma unroll
          for (int jj = 0; jj < 4; ++jj) mv[jj] = *(const float2*)&mp[(size_t)(j + jj) * SS];
#pragma unroll
          for (int u = 0; u < 4; ++u) {
            const float* sp = (const float*)&s4a[u];
#pragma unroll
            for (int jj = 0; jj < 4; ++jj) {
              ga[u][0] += sp[jj] * mv[jj].x;
              ga[u][1] += sp[jj] * mv[jj].y;
            }
          }
          if (gy == 0) {
            float4 sx = *(const float4*)&seA[32 * 260 + j];
            const float* sxp = (const float*)&sx;
#pragma unroll
            for (int jj = 0; jj < 4; ++jj) {
              gxe[0] += sxp[jj] * mv[jj].x;
              gxe[1] += sxp[jj] * mv[jj].y;
            }
          }
        }
        __syncthreads();  // prior Gb readers done
#pragma unroll
        for (int u = 0; u < 4; ++u)
          *(float2*)&Gb[(gy + 8 * u) * 68 + gx * 2] = make_float2(ga[u][0], ga[u][1]);
        if (gy == 0) *(float2*)&Gb[32 * 68 + gx * 2] = make_float2(gxe[0], gxe[1]);
        __syncthreads();
        for (int kk = 0; kk < 64; kk += 4) {
          float4 g4 = *(const float4*)&Gb[e_n * 68 + kk];
          float4 gb4 = make_float4(0.f, 0.f, 0.f, 0.f);
          if (e_n == 0) gb4 = *(const float4*)&Gb[32 * 68 + kk];
#pragma unroll
          for (int j2 = 0; j2 < 4; ++j2) {
            float4 s4 = *(const float4*)&seA[(e_m * 4 + j2) * 260 + k0 + kk];
            eacc[j2] += g4.x * s4.x + g4.y * s4.y + g4.z * s4.z + g4.w * s4.w;
            if (e_n == 0)
              eacc2[j2] += gb4.x * s4.x + gb4.y * s4.y + gb4.z * s4.z + gb4.w * s4.w;
          }
          if (e_m == 7) {
            float4 s4 = *(const float4*)&seA[32 * 260 + k0 + kk];
            eacc[4] += g4.x * s4.x + g4.y * s4.y + g4.z * s4.z + g4.w * s4.w;
            if (e_n == 0)
              eacc2[4] += gb4.x * s4.x + gb4.y * s4.y + gb4.z * s4.z + gb4.w * s4.w;
          }
        }
      }
#pragma unroll
      for (int j2 = 0; j2 < 4; ++j2)
        Emat[e_n * 36 + e_m * 4 + j2] = eacc[j2] + vbuf[e_m * 4 + j2];
      if (e_m == 7) Emat[e_n * 36 + 32] = eacc[4] + vbuf[32];
      if (e_n == 0) {
#pragma unroll
        for (int j2 = 0; j2 < 4; ++j2)
          Emat[32 * 36 + e_m * 4 + j2] = eacc2[j2] + vbuf[e_m * 4 + j2];
        if (e_m == 7) Emat[32 * 36 + 32] = eacc2[4] + vbuf[32];
      }
      __syncthreads();
      // row softmax of E
      if (tid < NN) {
        float mx = -1e30f;
        for (int mm = 0; mm < NN; ++mm) mx = fmaxf(mx, Emat[tid * 36 + mm]);
        float sum = 0.f;
        for (int mm = 0; mm < NN; ++mm) {
          float e = expf(Emat[tid * 36 + mm] - mx);
          Emat[tid * 36 + mm] = e;
          sum += e;
        }
        float rs = 1.0f / sum;
        for (int mm = 0; mm < NN; ++mm) Emat[tid * 36 + mm] *= rs;
      }
      __syncthreads();
      // X = seA @ Wg, in-place per-row (wave owns row; in-wave read-then-write)
      for (int bi = 0; bi < 9; ++bi) {
        int r = bi * 4 + xg;
        if (r < NN) {
          float xacc[4] = {};
          const float* wp = Wgs + xc * 4;
          for (int k = 0; k < SS; k += 4) {
            float4 s4 = *(const float4*)&seA[r * 260 + k];
            const float* sp = (const float*)&s4;
#pragma unroll
            for (int kk2 = 0; kk2 < 4; ++kk2) {
              float sv = sp[kk2];
              float4 w4 = *(const float4*)&wp[(size_t)(k + kk2) * SS];
              xacc[0] += sv * w4.x;
              xacc[1] += sv * w4.y;
              xacc[2] += sv * w4.z;
              xacc[3] += sv * w4.w;
            }
          }
          *(float4*)&seA[r * 260 + xc * 4] = make_float4(xacc[0], xacc[1], xacc[2], xacc[3]);
        }
      }
      __syncthreads();
      // out = relu(E @ X + bg), in-place per 64-col chunk (col-disjoint)
      for (int k0 = 0; k0 < SS; k0 += 64) {
        float ha[2][4] = {};
        float hx[4] = {0.f, 0.f, 0.f, 0.f};
        for (int mm = 0; mm < NN; ++mm) {
          float e0 = Emat[h_r * 36 + mm];
          float e1 = Emat[(h_r + 16) * 36 + mm];
          float4 x4 = *(const float4*)&seA[mm * 260 + k0 + h_c * 4];
          ha[0][0] += e0 * x4.x; ha[0][1] += e0 * x4.y; ha[0][2] += e0 * x4.z; ha[0][3] += e0 * x4.w;
          ha[1][0] += e1 * x4.x; ha[1][1] += e1 * x4.y; ha[1][2] += e1 * x4.z; ha[1][3] += e1 * x4.w;
          if (h_r == 0) {
            float e2 = Emat[32 * 36 + mm];
            hx[0] += e2 * x4.x; hx[1] += e2 * x4.y; hx[2] += e2 * x4.z; hx[3] += e2 * x4.w;
          }
        }
        float4 b4 = *(const float4*)&bgs[k0 + h_c * 4];
        __syncthreads();  // all X reads of this chunk done
        {
          float v0 = ha[0][0] + b4.x, v1 = ha[0][1] + b4.y, v2 = ha[0][2] + b4.z, v3 = ha[0][3] + b4.w;
          *(float4*)&seA[h_r * 260 + k0 + h_c * 4] =
              make_float4(v0 > 0.f ? v0 : 0.f, v1 > 0.f ? v1 : 0.f, v2 > 0.f ? v2 : 0.f,
                          v3 > 0.f ? v3 : 0.f);
          v0 = ha[1][0] + b4.x; v1 = ha[1][1] + b4.y; v2 = ha[1][2] + b4.z; v3 = ha[1][3] + b4.w;
          *(float4*)&seA[(h_r + 16) * 260 + k0 + h_c * 4] =
              make_float4(v0 > 0.f ? v0 : 0.f, v1 > 0.f ? v1 : 0.f, v2 > 0.f ? v2 : 0.f,
                          v3 > 0.f ? v3 : 0.f);
          if (h_r == 0) {
            v0 = hx[0] + b4.x; v1 = hx[1] + b4.y; v2 = hx[2] + b4.z; v3 = hx[3] + b4.w;
            *(float4*)&seA[32 * 260 + k0 + h_c * 4] =
                make_float4(v0 > 0.f ? v0 : 0.f, v1 > 0.f ? v1 : 0.f, v2 > 0.f ? v2 : 0.f,
                            v3 > 0.f ? v3 : 0.f);
          }
        }
      }
      __syncthreads();
    }
  }

  // ---------------- eval: sigmoid(seA[0] @ W_eval + b_eval)
  if (tid < 64) {
    float* seA = (float*)(smem + OFF_SEA);
    float4 s4 = *(const float4*)&seA[tid * 4];
    float4 w4 = *(const float4*)&W_eval[tid * 4];
    float s = s4.x * w4.x + s4.y * w4.y + s4.z * w4.z + s4.w * w4.w;
    s = warp_reduce_sum64(s);
    if (tid == 0) out[b * 64 + c] = 1.0f / (1.0f + expf(-(s + b_eval[0])));
  }
}

extern "C" void kernel_launch(void* const* d_in, const int* in_sizes, int n_in,
                              void* d_out, int out_size, void* d_ws, size_t ws_size,
                              hipStream_t stream) {
  (void)in_sizes; (void)n_in; (void)out_size; (void)ws_size;
  const float* img = (const float*)d_in[0];
  const float* cap = (const float*)d_in[1];
  const float* vG_Wl = (const float*)d_in[3];
  const float* vG_bl = (const float*)d_in[4];
  const float* vG_Wg = (const float*)d_in[5];
  const float* vG_bg = (const float*)d_in[6];
  const float* vG_Wc = (const float*)d_in[7];
  const float* vG_bc = (const float*)d_in[8];
  const float* tG_Wl = (const float*)d_in[9];
  const float* tG_bl = (const float*)d_in[10];
  const float* tG_Wg = (const float*)d_in[11];
  const float* tG_bg = (const float*)d_in[12];
  const float* tG_Wc = (const float*)d_in[13];
  const float* tG_bc = (const float*)d_in[14];
  const float* W_loc = (const float*)d_in[15];
  const float* b_loc = (const float*)d_in[16];
  const float* W_glo = (const float*)d_in[17];
  const float* b_glo = (const float*)d_in[18];
  const float* W_eval = (const float*)d_in[19];
  const float* b_eval = (const float*)d_in[20];
  const float* sgr_Wq = (const float*)d_in[21];
  const float* sgr_bq = (const float*)d_in[22];
  const float* sgr_Wk = (const float*)d_in[23];
  const float* sgr_Wg = (const float*)d_in[25];
  const float* sgr_bg = (const float*)d_in[26];
  float* out = (float*)d_out;
  float* ws = (float*)d_ws;
  float* img_avg = ws;
  float* cap_avg = ws + 65536;
  float* h_img = ws + 131072;
  float* h_cap = ws + 196608;
  float* part_img = ws + 262144;
  float* part_cap = ws + 462848;
  float* img_glob = ws + 495616;
  float* cap_glob = ws + 561152;
  float* simglo = ws + 626688;
  float* Mmat = ws + 1675264;
  float* wkbqv = ws + 1871872;
  float* gramb = ws + 1875968;  // 64*196*196 = 2458624 floats

  k_avg<<<128, 256, 0, stream>>>(img, cap, img_avg, cap_avg);
  k_hvec<<<256, 256, 0, stream>>>(img_avg, vG_Wg, vG_bg, vG_Wc, h_img);
  k_hvec<<<256, 256, 0, stream>>>(cap_avg, tG_Wg, tG_bg, tG_Wc, h_cap);
  k_logits_partial<<<dim3(196, 16), 256, 0, stream>>>(img + DD, (long)NTOK * DD, TT, vG_Wl,
                                                      vG_bl, h_img, part_img);
  k_logits_partial<<<dim3(32, 16), 256, 0, stream>>>(cap, (long)CL * DD, CL, tG_Wl, tG_bl,
                                                     h_cap, part_cap);
  k_finish_global<<<64, 256, 0, stream>>>(part_img, vG_bc, img + DD, (long)NTOK * DD, TT,
                                          img_glob);
  k_finish_global<<<64, 256, 0, stream>>>(part_cap, tG_bc, cap, (long)CL * DD, CL, cap_glob);
  k_simglo<<<256, 256, 0, stream>>>(img_glob, cap_glob, W_glo, b_glo, simglo);
  k_mmat<<<48, 256, 0, stream>>>(sgr_Wq, sgr_Wk, Mmat);
  k_wkbq<<<3, 256, 0, stream>>>(sgr_Wk, sgr_bq, wkbqv);
  k_gram<<<dim3(64, 4, 4), 256, 0, stream>>>(img, gramb);
  hipFuncSetAttribute((const void*)k_pair, hipFuncAttributeMaxDynamicSharedMemorySize,
                      SMEM_BYTES);
  k_pair<<<4096, 256, SMEM_BYTES, stream>>>(img, cap, W_loc, b_loc, simglo, Mmat, wkbqv,
                                            sgr_Wg, sgr_bg, W_eval, b_eval, gramb, out);
}

// Round 5
// 2777.067 us; speedup vs baseline: 8.3306x; 3.5721x over previous
//
#include <hip/hip_runtime.h>
#include <hip/hip_bf16.h>
#include <math.h>

#define NI 64
#define NC 64
#define NTOK 197
#define TT 196
#define CL 32
#define DD 1024
#define SS 256
#define NN 33
#define EPSN 1e-12f
#define SMOOTHF 9.0f
#define TP 224   // padded token dim for MFMA K

typedef __attribute__((ext_vector_type(8))) short bfrag;
typedef __attribute__((ext_vector_type(4))) float f32x4;
#define MFMA(a, b, c) __builtin_amdgcn_mfma_f32_16x16x32_bf16((a), (b), (c), 0, 0, 0)

// LDS layout (byte offsets) — phase A/W region
#define OFF_ATTN   0        // [196][34] f32 = 26656
#define OFF_ATTNT  26656    // [32][232] u16 = 14848 -> 41504
#define OFF_WTILE  41504    // [32][136] u16 = 8704 -> 50208
#define OFF_NRMS   50720    // [32] f32
#define OFF_QN     50848    // [128] f32
#define OFF_RNQ    51360    // [32] f32
// SGR overlays
#define OFF_SEA    0        // [48][264] u16 = 25344
#define OFF_GXT    25344    // G [48][264]u16 (25344) / XT [256][72]u16 (36864) -> 62208
#define OFF_EF     62208    // [33][36] f32 = 4752 -> 66960
#define OFF_EB     66960    // [48][72] u16 = 6912 -> 73872
#define OFF_WKQ    73872    // [256] f32 -> 74896
#define OFF_VBUF   74896    // [36] f32 -> 75040
#define SMEM_BYTES 75040

__device__ __forceinline__ float warp_reduce_sum64(float v) {
#pragma unroll
  for (int m = 32; m > 0; m >>= 1) v += __shfl_xor(v, m, 64);
  return v;
}
__device__ __forceinline__ unsigned short f2b(float f) {
  __hip_bfloat16 h = __float2bfloat16(f);
  return *reinterpret_cast<unsigned short*>(&h);
}
__device__ __forceinline__ float b2f(unsigned short u) {
  union { unsigned int i; float f; } v;
  v.i = ((unsigned int)u) << 16;
  return v.f;
}

// ---------------------------------------------------------------- K1: means
__global__ void k_avg(const float* __restrict__ img, const float* __restrict__ cap,
                      float* __restrict__ img_avg, float* __restrict__ cap_avg) {
  int bid = blockIdx.x;
  int tid = threadIdx.x;
  if (bid < NI) {
    int b = bid;
    for (int d = tid; d < DD; d += 256) {
      float acc = 0.f;
      const float* p = img + ((size_t)b * NTOK + 1) * DD + d;
      for (int t = 0; t < TT; ++t) acc += p[(size_t)t * DD];
      img_avg[b * DD + d] = acc * (1.0f / TT);
    }
  } else {
    int c = bid - NI;
    for (int d = tid; d < DD; d += 256) {
      float acc = 0.f;
      const float* p = cap + (size_t)c * CL * DD + d;
      for (int t = 0; t < CL; ++t) acc += p[(size_t)t * DD];
      cap_avg[c * DD + d] = acc * (1.0f / CL);
    }
  }
}

// ------------------------------------------------- K2: h = tanh(avg@Wg+bg)*Wc
__global__ void k_hvec(const float* __restrict__ avg, const float* __restrict__ Wg,
                       const float* __restrict__ bg, const float* __restrict__ Wc,
                       float* __restrict__ h) {
  __shared__ float av[DD];
  int b = blockIdx.x >> 2;
  int dc = blockIdx.x & 3;
  int tid = threadIdx.x;
  for (int i = tid; i < DD; i += 256) av[i] = avg[b * DD + i];
  __syncthreads();
  int d = dc * 256 + tid;
  float acc = 0.f;
  for (int k = 0; k < DD; k += 4) {
    float4 a4 = *(const float4*)&av[k];
    acc += a4.x * Wg[(size_t)(k + 0) * DD + d];
    acc += a4.y * Wg[(size_t)(k + 1) * DD + d];
    acc += a4.z * Wg[(size_t)(k + 2) * DD + d];
    acc += a4.w * Wg[(size_t)(k + 3) * DD + d];
  }
  h[b * DD + d] = tanhf(acc + bg[d]) * Wc[d];
}

// ---------------- K3: partial logits
__global__ void k_logits_partial(const float* __restrict__ Abase, long batchStride, int rowsPerBatch,
                                 const float* __restrict__ Wl, const float* __restrict__ bl,
                                 const float* __restrict__ h, float* __restrict__ partial) {
  __shared__ float a_lds[32][68];
  __shared__ float b_lds[32][68];
  int tid = threadIdx.x;
  int rb = blockIdx.x * 64;
  int c0 = blockIdx.y * 64;
  int ty = tid >> 4, tx = tid & 15;
  int s_rr = tid >> 2, s_kq = tid & 3;
  int rA = rb + s_rr;
  const float* aRow = Abase + (size_t)(rA / rowsPerBatch) * batchStride + (size_t)(rA % rowsPerBatch) * DD;
  int s_kk = tid >> 3, s_cq = tid & 7;
  float acc[4][4] = {};
  for (int k0 = 0; k0 < DD; k0 += 32) {
    float4 v0 = *(const float4*)&aRow[k0 + s_kq * 8];
    float4 v1 = *(const float4*)&aRow[k0 + s_kq * 8 + 4];
    float4 w0 = *(const float4*)&Wl[(size_t)(k0 + s_kk) * DD + c0 + s_cq * 8];
    float4 w1 = *(const float4*)&Wl[(size_t)(k0 + s_kk) * DD + c0 + s_cq * 8 + 4];
    __syncthreads();
    float va[8] = {v0.x, v0.y, v0.z, v0.w, v1.x, v1.y, v1.z, v1.w};
#pragma unroll
    for (int u = 0; u < 8; ++u) a_lds[s_kq * 8 + u][s_rr] = va[u];
    *(float4*)&b_lds[s_kk][s_cq * 8] = w0;
    *(float4*)&b_lds[s_kk][s_cq * 8 + 4] = w1;
    __syncthreads();
#pragma unroll
    for (int kk = 0; kk < 32; ++kk) {
      float4 a4 = *(const float4*)&a_lds[kk][ty * 4];
      float4 b4 = *(const float4*)&b_lds[kk][tx * 4];
      float av[4] = {a4.x, a4.y, a4.z, a4.w};
      float bv[4] = {b4.x, b4.y, b4.z, b4.w};
#pragma unroll
      for (int i = 0; i < 4; ++i)
#pragma unroll
        for (int j = 0; j < 4; ++j) acc[i][j] += av[i] * bv[j];
    }
  }
#pragma unroll
  for (int i = 0; i < 4; ++i) {
    int r = rb + ty * 4 + i;
    int bb = r / rowsPerBatch;
    float s = 0.f;
#pragma unroll
    for (int j = 0; j < 4; ++j) {
      int cc = c0 + tx * 4 + j;
      s += tanhf(acc[i][j] + bl[cc]) * h[bb * DD + cc];
    }
    s += __shfl_xor(s, 1, 64);
    s += __shfl_xor(s, 2, 64);
    s += __shfl_xor(s, 4, 64);
    s += __shfl_xor(s, 8, 64);
    if (tx == 0) partial[(size_t)r * 16 + blockIdx.y] = s;
  }
}

// -------- K4: finish global attention pooling
__global__ void k_finish_global(const float* __restrict__ partial, const float* __restrict__ bc,
                                const float* __restrict__ Xbase, long batchStride, int R,
                                float* __restrict__ outG) {
  __shared__ float w[200];
  __shared__ float red[8];
  int b = blockIdx.x, tid = threadIdx.x;
  for (int t = tid; t < R; t += 256) {
    const float* pp = &partial[((size_t)b * R + t) * 16];
    float s = bc[0];
#pragma unroll
    for (int u = 0; u < 16; ++u) s += pp[u];
    w[t] = s;
  }
  __syncthreads();
  float m = -1e30f;
  for (int t = tid; t < R; t += 256) m = fmaxf(m, w[t]);
#pragma unroll
  for (int mm = 32; mm; mm >>= 1) m = fmaxf(m, __shfl_xor(m, mm, 64));
  if ((tid & 63) == 0) red[tid >> 6] = m;
  __syncthreads();
  m = fmaxf(fmaxf(red[0], red[1]), fmaxf(red[2], red[3]));
  __syncthreads();
  for (int t = tid; t < R; t += 256) w[t] = expf(w[t] - m);
  __syncthreads();
  const float* xb = Xbase + (size_t)b * batchStride;
  float acc[4];
  float ss = 0.f;
#pragma unroll
  for (int c4 = 0; c4 < 4; ++c4) {
    int d = tid + c4 * 256;
    float a = 0.f;
    for (int t = 0; t < R; ++t) a += w[t] * xb[(size_t)t * DD + d];
    acc[c4] = a;
    ss += a * a;
  }
  ss = warp_reduce_sum64(ss);
  if ((tid & 63) == 0) red[tid >> 6] = ss;
  __syncthreads();
  ss = red[0] + red[1] + red[2] + red[3];
  float rn = 1.0f / fmaxf(sqrtf(ss), EPSN);
#pragma unroll
  for (int c4 = 0; c4 < 4; ++c4) outG[(size_t)b * DD + tid + c4 * 256] = acc[c4] * rn;
}

// -------- K5: sim_glo
__global__ void k_simglo(const float* __restrict__ ig, const float* __restrict__ cg,
                         const float* __restrict__ W, const float* __restrict__ bgl,
                         float* __restrict__ simglo) {
  __shared__ float a_lds[32][20];
  __shared__ float b_lds[32][260];
  int tid = threadIdx.x;
  int p0 = blockIdx.x * 16;
  int ty = tid >> 6, tx = tid & 63;
  int s_rr = tid >> 3, s_kq = tid & 7;
  float acc[4][4] = {};
  for (int k0 = 0; k0 < DD; k0 += 32) {
    float d2[4] = {};
    if (tid < 128) {
      int p = p0 + s_rr;
      int b = p >> 6, c = p & 63;
      float4 giv = *(const float4*)&ig[b * DD + k0 + s_kq * 4];
      float4 cgv = *(const float4*)&cg[c * DD + k0 + s_kq * 4];
      float dx = giv.x - cgv.x, dy = giv.y - cgv.y, dz = giv.z - cgv.z, dw = giv.w - cgv.w;
      d2[0] = dx * dx; d2[1] = dy * dy; d2[2] = dz * dz; d2[3] = dw * dw;
    }
    float4 wv[8];
#pragma unroll
    for (int u = 0; u < 8; ++u)
      wv[u] = *(const float4*)&W[(size_t)(k0 + s_rr) * SS + s_kq * 32 + u * 4];
    __syncthreads();
    if (tid < 128) {
#pragma unroll
      for (int u = 0; u < 4; ++u) a_lds[s_kq * 4 + u][s_rr] = d2[u];
    }
#pragma unroll
    for (int u = 0; u < 8; ++u)
      *(float4*)&b_lds[s_rr][s_kq * 32 + u * 4] = wv[u];
    __syncthreads();
#pragma unroll
    for (int kk = 0; kk < 32; ++kk) {
      float4 a4 = *(const float4*)&a_lds[kk][ty * 4];
      float4 b4 = *(const float4*)&b_lds[kk][tx * 4];
      float av[4] = {a4.x, a4.y, a4.z, a4.w};
      float bv[4] = {b4.x, b4.y, b4.z, b4.w};
#pragma unroll
      for (int i = 0; i < 4; ++i)
#pragma unroll
        for (int j = 0; j < 4; ++j) acc[i][j] += av[i] * bv[j];
    }
  }
#pragma unroll
  for (int i = 0; i < 4; ++i) {
    float v[4];
    float ssq = 0.f;
#pragma unroll
    for (int j = 0; j < 4; ++j) {
      v[j] = acc[i][j] + bgl[tx * 4 + j];
      ssq += v[j] * v[j];
    }
    ssq = warp_reduce_sum64(ssq);
    float rn = 1.0f / fmaxf(sqrtf(ssq), EPSN);
    int p = p0 + ty * 4 + i;
    *(float4*)&simglo[(size_t)p * SS + tx * 4] =
        make_float4(v[0] * rn, v[1] * rn, v[2] * rn, v[3] * rn);
  }
}

// -------- K6: MT_bf16[t] = A_t @ B_t^T (256x256), bf16 out. Called with (Wk,Wq) -> M^T.
__global__ void k_mmatb(const float* __restrict__ Wa, const float* __restrict__ Wb,
                        unsigned short* __restrict__ M) {
  __shared__ float a_lds[32][68];
  __shared__ float b_lds[32][68];
  int tid = threadIdx.x;
  int t = blockIdx.x >> 4;
  int dt = (blockIdx.x >> 2) & 3, et = blockIdx.x & 3;
  int d0 = dt * 64, e0 = et * 64;
  const float* wq = Wa + (size_t)t * SS * SS;
  const float* wk = Wb + (size_t)t * SS * SS;
  int ty = tid >> 4, tx = tid & 15;
  int s_rr = tid >> 2, s_kq = tid & 3;
  float acc[4][4] = {};
  for (int j0 = 0; j0 < SS; j0 += 32) {
    float4 q0 = *(const float4*)&wq[(size_t)(d0 + s_rr) * SS + j0 + s_kq * 8];
    float4 q1 = *(const float4*)&wq[(size_t)(d0 + s_rr) * SS + j0 + s_kq * 8 + 4];
    float4 k0v = *(const float4*)&wk[(size_t)(e0 + s_rr) * SS + j0 + s_kq * 8];
    float4 k1v = *(const float4*)&wk[(size_t)(e0 + s_rr) * SS + j0 + s_kq * 8 + 4];
    __syncthreads();
    float qa[8] = {q0.x, q0.y, q0.z, q0.w, q1.x, q1.y, q1.z, q1.w};
    float ka[8] = {k0v.x, k0v.y, k0v.z, k0v.w, k1v.x, k1v.y, k1v.z, k1v.w};
#pragma unroll
    for (int u = 0; u < 8; ++u) {
      a_lds[s_kq * 8 + u][s_rr] = qa[u];
      b_lds[s_kq * 8 + u][s_rr] = ka[u];
    }
    __syncthreads();
#pragma unroll
    for (int kk = 0; kk < 32; ++kk) {
      float4 a4 = *(const float4*)&a_lds[kk][ty * 4];
      float4 b4 = *(const float4*)&b_lds[kk][tx * 4];
      float av[4] = {a4.x, a4.y, a4.z, a4.w};
      float bv[4] = {b4.x, b4.y, b4.z, b4.w};
#pragma unroll
      for (int i = 0; i < 4; ++i)
#pragma unroll
        for (int j = 0; j < 4; ++j) acc[i][j] += av[i] * bv[j];
    }
  }
#pragma unroll
  for (int i = 0; i < 4; ++i) {
    unsigned int lo = (unsigned int)f2b(acc[i][0]) | ((unsigned int)f2b(acc[i][1]) << 16);
    unsigned int hi = (unsigned int)f2b(acc[i][2]) | ((unsigned int)f2b(acc[i][3]) << 16);
    uint2 o = make_uint2(lo, hi);
    *(uint2*)(M + (size_t)t * SS * SS + (size_t)(d0 + ty * 4 + i) * SS + e0 + tx * 4) = o;
  }
}

// -------- K6b: wkbq[t] = Wk_t @ bq_t
__global__ void k_wkbq(const float* __restrict__ Wk, const float* __restrict__ bq,
                       float* __restrict__ out) {
  __shared__ float bv[SS];
  int t = blockIdx.x, tid = threadIdx.x;
  const float* wk = Wk + (size_t)t * SS * SS;
  bv[tid] = bq[t * SS + tid];
  __syncthreads();
  float acc = 0.f;
  for (int j = 0; j < SS; j += 4) {
    float4 wv = *(const float4*)&wk[(size_t)tid * SS + j];
    float4 b4 = *(const float4*)&bv[j];
    acc += wv.x * b4.x + wv.y * b4.y + wv.z * b4.z + wv.w * b4.w;
  }
  out[t * SS + tid] = acc;
}

// -------- K6c: gram_bf16[b] = imgTok_b @ imgTok_b^T in [208][224] zero-padded bf16
__global__ void k_gramb(const float* __restrict__ img, unsigned short* __restrict__ gram) {
  __shared__ float a_lds[32][68];
  __shared__ float b_lds[32][68];
  int tid = threadIdx.x;
  int bimg = blockIdx.x;
  int rb = blockIdx.y * 64;
  int cb = blockIdx.z * 64;
  const float* X = img + ((size_t)bimg * NTOK + 1) * DD;
  int ty = tid >> 4, tx = tid & 15;
  int s_rr = tid >> 2, s_kq = tid & 3;
  int rA = rb + s_rr; if (rA > TT - 1) rA = TT - 1;
  int rB = cb + s_rr; if (rB > TT - 1) rB = TT - 1;
  const float* aRow = X + (size_t)rA * DD;
  const float* bRow = X + (size_t)rB * DD;
  float acc[4][4] = {};
  for (int k0 = 0; k0 < DD; k0 += 32) {
    float4 v0 = *(const float4*)&aRow[k0 + s_kq * 8];
    float4 v1 = *(const float4*)&aRow[k0 + s_kq * 8 + 4];
    float4 w0 = *(const float4*)&bRow[k0 + s_kq * 8];
    float4 w1 = *(const float4*)&bRow[k0 + s_kq * 8 + 4];
    __syncthreads();
    float va[8] = {v0.x, v0.y, v0.z, v0.w, v1.x, v1.y, v1.z, v1.w};
    float wa[8] = {w0.x, w0.y, w0.z, w0.w, w1.x, w1.y, w1.z, w1.w};
#pragma unroll
    for (int u = 0; u < 8; ++u) {
      a_lds[s_kq * 8 + u][s_rr] = va[u];
      b_lds[s_kq * 8 + u][s_rr] = wa[u];
    }
    __syncthreads();
#pragma unroll
    for (int kk = 0; kk < 32; ++kk) {
      float4 a4 = *(const float4*)&a_lds[kk][ty * 4];
      float4 b4 = *(const float4*)&b_lds[kk][tx * 4];
      float av[4] = {a4.x, a4.y, a4.z, a4.w};
      float bv[4] = {b4.x, b4.y, b4.z, b4.w};
#pragma unroll
      for (int i = 0; i < 4; ++i)
#pragma unroll
        for (int j = 0; j < 4; ++j) acc[i][j] += av[i] * bv[j];
    }
  }
  unsigned short* Gp = gram + (size_t)bimg * 208 * TP;
#pragma unroll
  for (int i = 0; i < 4; ++i) {
    int r = rb + ty * 4 + i;
    if (r < 208) {
#pragma unroll
      for (int j = 0; j < 4; ++j) {
        int c2 = cb + tx * 4 + j;
        if (c2 < TP) {
          float v = (r < TT && c2 < TT) ? acc[i][j] : 0.f;
          Gp[(size_t)r * TP + c2] = f2b(v);
        }
      }
    }
  }
}

// -------- cast f32 -> bf16 (same layout)
__global__ void k_castb(const float* __restrict__ s, unsigned short* __restrict__ d, int n4) {
  int i = blockIdx.x * 256 + threadIdx.x;
  if (i < n4) {
    float4 v = *(const float4*)(s + (size_t)i * 4);
    uint2 o;
    o.x = (unsigned int)f2b(v.x) | ((unsigned int)f2b(v.y) << 16);
    o.y = (unsigned int)f2b(v.z) | ((unsigned int)f2b(v.w) << 16);
    *(uint2*)(d + (size_t)i * 4) = o;
  }
}

// -------- transpose-cast: src[R][C] f32 -> dst[C][R] bf16 (batched via z)
__global__ void k_tcast(const float* __restrict__ src, unsigned short* __restrict__ dst,
                        int R, int C, long sB, long dB) {
  __shared__ float t[32][33];
  const float* s = src + (size_t)blockIdx.z * sB;
  unsigned short* d = dst + (size_t)blockIdx.z * dB;
  int r0 = blockIdx.y * 32, c0 = blockIdx.x * 32;
  int tx = threadIdx.x & 31, ty = threadIdx.x >> 5;
#pragma unroll
  for (int u = 0; u < 4; ++u)
    t[ty + u * 8][tx] = s[(size_t)(r0 + ty + u * 8) * C + c0 + tx];
  __syncthreads();
#pragma unroll
  for (int u = 0; u < 4; ++u)
    d[(size_t)(c0 + ty + u * 8) * R + r0 + tx] = f2b(t[tx][ty + u * 8]);
}

// -------- imgT_bf16[b][d][t(224 pad0)] = img[b][1+t][d]
__global__ void k_imgt(const float* __restrict__ img, unsigned short* __restrict__ dst) {
  __shared__ float t[32][33];
  int b = blockIdx.z;
  int t0 = blockIdx.y * 32, d0 = blockIdx.x * 32;
  int tx = threadIdx.x & 31, ty = threadIdx.x >> 5;
#pragma unroll
  for (int u = 0; u < 4; ++u) {
    int tt = t0 + ty + u * 8;
    t[ty + u * 8][tx] = (tt < TT) ? img[((size_t)b * NTOK + 1 + tt) * DD + d0 + tx] : 0.f;
  }
  __syncthreads();
#pragma unroll
  for (int u = 0; u < 4; ++u)
    dst[((size_t)b * DD + d0 + ty + u * 8) * TP + t0 + tx] = f2b(t[tx][ty + u * 8]);
}

// -------- K7: per-(img,cap) pair mega kernel (v5: MFMA bf16)
__global__ __launch_bounds__(256) void k_pair(
    const float* __restrict__ img, const float* __restrict__ cap,
    const float* __restrict__ b_loc, const float* __restrict__ simglo,
    const float* __restrict__ wkbq, const float* __restrict__ bg3,
    const float* __restrict__ W_eval, const float* __restrict__ b_eval,
    const unsigned short* __restrict__ cap_bf, const unsigned short* __restrict__ imgT_bf,
    const unsigned short* __restrict__ gram_bf, const unsigned short* __restrict__ wlocT_bf,
    const unsigned short* __restrict__ mt_bf, const unsigned short* __restrict__ wgT_bf,
    float* __restrict__ out) {
  extern __shared__ char smem[];
  float* attn = (float*)(smem + OFF_ATTN);

  int tid = threadIdx.x;
  int lane = tid & 63, w = tid >> 6;
  int lrow = lane & 15;        // MFMA row/col select
  int lk = (lane >> 4) * 8;    // MFMA k-offset
  int rsub = (lane >> 4) * 4;  // D-frag row base
  int p = blockIdx.x;
  int b = p >> 6, c = p & 63;
  const float* imgB = img + ((size_t)b * NTOK + 1) * DD;
  const unsigned short* capB = cap_bf + (size_t)c * CL * DD;

  // ================ Phase A: S[t][q] = leaky(imgTok . cap) via MFMA
  {
    f32x4 acc[4][2] = {};
    for (int k0 = 0; k0 < DD; k0 += 32) {
      bfrag bq0 = *(const bfrag*)(capB + (size_t)lrow * DD + k0 + lk);
      bfrag bq1 = *(const bfrag*)(capB + (size_t)(16 + lrow) * DD + k0 + lk);
#pragma unroll
      for (int i = 0; i < 4; ++i) {
        int tt = w + 4 * i;
        if (tt < 13) {
          int t = tt * 16 + lrow;
          bfrag a = {0, 0, 0, 0, 0, 0, 0, 0};
          if (t < TT) {
            const float* pr = imgB + (size_t)t * DD + k0 + lk;
            float4 f0 = *(const float4*)pr;
            float4 f1 = *(const float4*)(pr + 4);
            a[0] = (short)f2b(f0.x); a[1] = (short)f2b(f0.y);
            a[2] = (short)f2b(f0.z); a[3] = (short)f2b(f0.w);
            a[4] = (short)f2b(f1.x); a[5] = (short)f2b(f1.y);
            a[6] = (short)f2b(f1.z); a[7] = (short)f2b(f1.w);
          }
          acc[i][0] = MFMA(a, bq0, acc[i][0]);
          acc[i][1] = MFMA(a, bq1, acc[i][1]);
        }
      }
    }
#pragma unroll
    for (int i = 0; i < 4; ++i) {
      int tt = w + 4 * i;
      if (tt < 13) {
#pragma unroll
        for (int qt = 0; qt < 2; ++qt)
#pragma unroll
          for (int r = 0; r < 4; ++r) {
            int t = tt * 16 + rsub + r;
            if (t < TT) {
              float v = acc[i][qt][r];
              attn[t * 34 + qt * 16 + lrow] = v < 0.f ? 0.1f * v : v;
            }
          }
      }
    }
  }
  __syncthreads();

  // ================ A2: l2norm over q per token row
  if (tid < TT) {
    float ss = 0.f;
#pragma unroll
    for (int q = 0; q < 32; ++q) {
      float v = attn[tid * 34 + q];
      ss += v * v;
    }
    float rn = 1.0f / fmaxf(sqrtf(ss), EPSN);
#pragma unroll
    for (int q = 0; q < 32; ++q) attn[tid * 34 + q] *= rn;
  }
  __syncthreads();

  // ================ A3: softmax-exp (x9) over t per q (denominator dropped)
  {
    int q = tid >> 3, sub = tid & 7;
    float m = -1e30f;
    for (int t = sub; t < TT; t += 8) m = fmaxf(m, attn[t * 34 + q]);
    m = fmaxf(m, __shfl_xor(m, 1, 64));
    m = fmaxf(m, __shfl_xor(m, 2, 64));
    m = fmaxf(m, __shfl_xor(m, 4, 64));
    for (int t = sub; t < TT; t += 8)
      attn[t * 34 + q] = expf(SMOOTHF * (attn[t * 34 + q] - m));
  }
  __syncthreads();

  // ================ build attnT_bf16[q][t] (exp weights, zero-padded to 224)
  {
    char* attnT_b = smem + OFF_ATTNT;
    for (int idx = tid; idx < 32 * 116; idx += 256) {
      int q = idx / 116, tp2 = (idx - q * 116) * 2;
      unsigned int lo = (tp2 < TT) ? (unsigned int)f2b(attn[tp2 * 34 + q]) : 0u;
      unsigned int hi = (tp2 + 1 < TT) ? (unsigned int)f2b(attn[(tp2 + 1) * 34 + q]) : 0u;
      *(unsigned int*)(attnT_b + q * 464 + tp2 * 2) = lo | (hi << 16);
    }
  }
  __syncthreads();

  // ================ norm via Gram (MFMA): Y = G@E, norm2[q] = sum_t w[t][q]*Y[t][q]
  {
    const char* attnT_b = smem + OFF_ATTNT;
    float* qn = (float*)(smem + OFF_QN);
    float* nrmS = (float*)(smem + OFF_NRMS);
    const unsigned short* gb = gram_bf + (size_t)b * 208 * TP;
    float part0 = 0.f, part1 = 0.f;
#pragma unroll
    for (int i = 0; i < 4; ++i) {
      int tt = w + 4 * i;
      if (tt < 13) {
        f32x4 y0 = {0.f, 0.f, 0.f, 0.f}, y1 = {0.f, 0.f, 0.f, 0.f};
        for (int t0 = 0; t0 < TP; t0 += 32) {
          bfrag a = *(const bfrag*)(gb + (size_t)(tt * 16 + lrow) * TP + t0 + lk);
          bfrag b0 = *(const bfrag*)(attnT_b + lrow * 464 + (t0 + lk) * 2);
          bfrag b1 = *(const bfrag*)(attnT_b + (16 + lrow) * 464 + (t0 + lk) * 2);
          y0 = MFMA(a, b0, y0);
          y1 = MFMA(a, b1, y1);
        }
#pragma unroll
        for (int r = 0; r < 4; ++r) {
          int t = tt * 16 + rsub + r;
          if (t < TT) {
            part0 += y0[r] * attn[t * 34 + lrow];
            part1 += y1[r] * attn[t * 34 + 16 + lrow];
          }
        }
      }
    }
    part0 += __shfl_xor(part0, 16, 64); part0 += __shfl_xor(part0, 32, 64);
    part1 += __shfl_xor(part1, 16, 64); part1 += __shfl_xor(part1, 32, 64);
    if ((lane >> 4) == 0) {
      qn[w * 32 + lrow] = part0;
      qn[w * 32 + 16 + lrow] = part1;
    }
    __syncthreads();
    if (tid < 32)
      nrmS[tid] = 1.0f / fmaxf(sqrtf(qn[tid] + qn[32 + tid] + qn[64 + tid] + qn[96 + tid]), EPSN);
    __syncthreads();
  }

  // ================ Phase W: ctx (MFMA) -> diff^2 -> @W_loc (MFMA)
  f32x4 accW[2][4] = {};
  {
    const char* attnT_b = smem + OFF_ATTNT;
    char* wtile_b = smem + OFF_WTILE;
    float* nrmS = (float*)(smem + OFF_NRMS);
    float nrm0 = nrmS[lrow], nrm1 = nrmS[16 + lrow];
    for (int d0 = 0; d0 < DD; d0 += 128) {
      // ctx^T tiles: wave owns d-tiles {w, w+4}
      f32x4 c2[2][2] = {};
      for (int t0 = 0; t0 < TP; t0 += 32) {
        bfrag b0 = *(const bfrag*)(attnT_b + lrow * 464 + (t0 + lk) * 2);
        bfrag b1 = *(const bfrag*)(attnT_b + (16 + lrow) * 464 + (t0 + lk) * 2);
#pragma unroll
        for (int i = 0; i < 2; ++i) {
          int dt = w + 4 * i;
          bfrag a = *(const bfrag*)(imgT_bf + ((size_t)b * DD + d0 + dt * 16 + lrow) * TP + t0 + lk);
          c2[i][0] = MFMA(a, b0, c2[i][0]);
          c2[i][1] = MFMA(a, b1, c2[i][1]);
        }
      }
      __syncthreads();  // prev W_loc readers of wtile done
#pragma unroll
      for (int i = 0; i < 2; ++i) {
        int dl = (w + 4 * i) * 16 + rsub;
#pragma unroll
        for (int qt = 0; qt < 2; ++qt) {
          int q = qt * 16 + lrow;
          uint2 cu = *(const uint2*)(capB + (size_t)q * DD + d0 + dl);
          float cf0 = b2f(cu.x & 0xffff), cf1 = b2f(cu.x >> 16);
          float cf2 = b2f(cu.y & 0xffff), cf3 = b2f(cu.y >> 16);
          float rn = qt ? nrm1 : nrm0;
          float v0 = c2[i][qt][0] * rn - cf0;
          float v1 = c2[i][qt][1] * rn - cf1;
          float v2 = c2[i][qt][2] * rn - cf2;
          float v3 = c2[i][qt][3] * rn - cf3;
          unsigned int lo = (unsigned int)f2b(v0 * v0) | ((unsigned int)f2b(v1 * v1) << 16);
          unsigned int hi = (unsigned int)f2b(v2 * v2) | ((unsigned int)f2b(v3 * v3) << 16);
          *(uint2*)(wtile_b + q * 272 + dl * 2) = make_uint2(lo, hi);
        }
      }
      __syncthreads();
      // W_loc accumulate
      for (int kc = 0; kc < 4; ++kc) {
        bfrag a0 = *(const bfrag*)(wtile_b + lrow * 272 + (kc * 32 + lk) * 2);
        bfrag a1 = *(const bfrag*)(wtile_b + (16 + lrow) * 272 + (kc * 32 + lk) * 2);
#pragma unroll
        for (int sti = 0; sti < 4; ++sti) {
          int s = (w * 4 + sti) * 16 + lrow;
          bfrag bb = *(const bfrag*)(wlocT_bf + (size_t)s * DD + d0 + kc * 32 + lk);
          accW[0][sti] = MFMA(a0, bb, accW[0][sti]);
          accW[1][sti] = MFMA(a1, bb, accW[1][sti]);
        }
      }
    }
  }

  // ================ assembly: l2norm(sim_loc)+bias -> seA_bf16 rows 1..32; row 0 simglo
  {
    char* seA_b = smem + OFF_SEA;
    float* qn = (float*)(smem + OFF_QN);
    float* rnq = (float*)(smem + OFF_RNQ);
    __syncthreads();
    for (int i2 = tid; i2 < 6336; i2 += 256) ((unsigned int*)smem)[i2] = 0;  // zero seA
    __syncthreads();
    float blv[4];
#pragma unroll
    for (int sti = 0; sti < 4; ++sti) blv[sti] = b_loc[(w * 4 + sti) * 16 + lrow];
    float ss[2][4];
#pragma unroll
    for (int qt = 0; qt < 2; ++qt)
#pragma unroll
      for (int r = 0; r < 4; ++r) {
        float s2 = 0.f;
#pragma unroll
        for (int sti = 0; sti < 4; ++sti) {
          float v = accW[qt][sti][r] + blv[sti];
          s2 += v * v;
        }
        s2 += __shfl_xor(s2, 1, 64);
        s2 += __shfl_xor(s2, 2, 64);
        s2 += __shfl_xor(s2, 4, 64);
        s2 += __shfl_xor(s2, 8, 64);
        ss[qt][r] = s2;
      }
    if (lrow == 0) {
#pragma unroll
      for (int qt = 0; qt < 2; ++qt)
#pragma unroll
        for (int r = 0; r < 4; ++r)
          qn[w * 32 + qt * 16 + rsub + r] = ss[qt][r];
    }
    __syncthreads();
    if (tid < 32)
      rnq[tid] = 1.0f / fmaxf(sqrtf(qn[tid] + qn[32 + tid] + qn[64 + tid] + qn[96 + tid]), EPSN);
    __syncthreads();
#pragma unroll
    for (int qt = 0; qt < 2; ++qt)
#pragma unroll
      for (int r = 0; r < 4; ++r) {
        int q = qt * 16 + rsub + r;
        float rn = rnq[q];
#pragma unroll
        for (int sti = 0; sti < 4; ++sti) {
          int s = (w * 4 + sti) * 16 + lrow;
          float v = (accW[qt][sti][r] + blv[sti]) * rn;
          *(unsigned short*)(seA_b + (1 + q) * 528 + s * 2) = f2b(v);
        }
      }
    if (tid < 64) {
      float4 g4 = *(const float4*)&simglo[(size_t)p * SS + tid * 4];
      unsigned int lo = (unsigned int)f2b(g4.x) | ((unsigned int)f2b(g4.y) << 16);
      unsigned int hi = (unsigned int)f2b(g4.z) | ((unsigned int)f2b(g4.w) << 16);
      *(uint2*)(seA_b + tid * 8) = make_uint2(lo, hi);
    }
    __syncthreads();
  }

  // ================ SGR x3 (all GEMMs MFMA)
  {
    char* seA_b = smem + OFF_SEA;
    char* G_b = smem + OFF_GXT;
    char* XT_b = smem + OFF_GXT;
    float* Ef = (float*)(smem + OFF_EF);
    char* Eb = smem + OFF_EB;
    float* wkq = (float*)(smem + OFF_WKQ);
    float* vbuf = (float*)(smem + OFF_VBUF);

    for (int step = 0; step < 3; ++step) {
      const unsigned short* mstep = mt_bf + (size_t)step * SS * SS;
      const unsigned short* wstep = wgT_bf + (size_t)step * SS * SS;
      wkq[tid] = wkbq[step * SS + tid];
      __syncthreads();
      // vbuf[m] = seA[m] . (Wk@bq)
      if (tid < 132) {
        int m = tid >> 2, qq = tid & 3;
        float a = 0.f;
        for (int e = qq * 64; e < qq * 64 + 64; e += 2) {
          unsigned int u = *(const unsigned int*)(seA_b + m * 528 + e * 2);
          a += b2f(u & 0xffff) * wkq[e] + b2f(u >> 16) * wkq[e + 1];
        }
        a += __shfl_xor(a, 1, 64);
        a += __shfl_xor(a, 2, 64);
        if (qq == 0) vbuf[m] = a;
      }
      // G = seA @ M  (48 x 256)
      f32x4 aG[3][4] = {};
      for (int kc = 0; kc < 8; ++kc) {
        int k = kc * 32 + lk;
        bfrag af[3];
#pragma unroll
        for (int mt = 0; mt < 3; ++mt)
          af[mt] = *(const bfrag*)(seA_b + (mt * 16 + lrow) * 528 + k * 2);
#pragma unroll
        for (int i = 0; i < 4; ++i) {
          bfrag bb = *(const bfrag*)(mstep + (size_t)((w * 4 + i) * 16 + lrow) * SS + k);
#pragma unroll
          for (int mt = 0; mt < 3; ++mt) aG[mt][i] = MFMA(af[mt], bb, aG[mt][i]);
        }
      }
      __syncthreads();  // prev-step XT/E readers done; vbuf written
#pragma unroll
      for (int mt = 0; mt < 3; ++mt)
#pragma unroll
        for (int i = 0; i < 4; ++i) {
          int row = mt * 16 + rsub, col = (w * 4 + i) * 16 + lrow;
#pragma unroll
          for (int r = 0; r < 4; ++r)
            *(unsigned short*)(G_b + (row + r) * 528 + col * 2) = f2b(aG[mt][i][r]);
        }
      __syncthreads();
      // E = G @ seA^T (+vbuf)
      {
        f32x4 aE[3] = {};
        for (int kc = 0; kc < 8; ++kc) {
          int k = kc * 32 + lk;
#pragma unroll
          for (int ti = 0; ti < 3; ++ti) {
            int tile = w + ti * 4;
            if (tile < 9) {
              int mtE = tile / 3, ntE = tile - mtE * 3;
              bfrag ga = *(const bfrag*)(G_b + (mtE * 16 + lrow) * 528 + k * 2);
              bfrag sb = *(const bfrag*)(seA_b + (ntE * 16 + lrow) * 528 + k * 2);
              aE[ti] = MFMA(ga, sb, aE[ti]);
            }
          }
        }
#pragma unroll
        for (int ti = 0; ti < 3; ++ti) {
          int tile = w + ti * 4;
          if (tile < 9) {
            int mtE = tile / 3, ntE = tile - mtE * 3;
            int n0 = mtE * 16 + rsub, m = ntE * 16 + lrow;
#pragma unroll
            for (int r = 0; r < 4; ++r)
              if (n0 + r < NN && m < NN) Ef[(n0 + r) * 36 + m] = aE[ti][r] + vbuf[m];
          }
        }
      }
      __syncthreads();
      // row softmax of E
      if (tid < NN) {
        float mx = -1e30f;
        for (int mm = 0; mm < NN; ++mm) mx = fmaxf(mx, Ef[tid * 36 + mm]);
        float sum = 0.f;
        for (int mm = 0; mm < NN; ++mm) {
          float e = expf(Ef[tid * 36 + mm] - mx);
          Ef[tid * 36 + mm] = e;
          sum += e;
        }
        float rs = 1.0f / sum;
        for (int mm = 0; mm < NN; ++mm) Ef[tid * 36 + mm] *= rs;
      }
      __syncthreads();
      // E_bf16 build (zero pads) + XT strip zero (m in [48,72))
      for (int idx = tid; idx < 48 * 36; idx += 256) {
        int n = idx / 36, mp = (idx - n * 36) * 2;
        unsigned int lo = (n < NN && mp < NN) ? (unsigned int)f2b(Ef[n * 36 + mp]) : 0u;
        unsigned int hi = (n < NN && mp + 1 < NN) ? (unsigned int)f2b(Ef[n * 36 + mp + 1]) : 0u;
        *(unsigned int*)(Eb + n * 144 + mp * 2) = lo | (hi << 16);
      }
      for (int idx = tid; idx < 256 * 12; idx += 256) {
        int s2 = idx / 12, c4 = idx - s2 * 12;
        *(unsigned int*)(XT_b + s2 * 144 + 96 + c4 * 4) = 0;
      }
      __syncthreads();
      // X = seA @ Wg -> XT (transposed store); overwrites G region
      {
        f32x4 aX[3][4] = {};
        for (int kc = 0; kc < 8; ++kc) {
          int k = kc * 32 + lk;
          bfrag af[3];
#pragma unroll
          for (int mt = 0; mt < 3; ++mt)
            af[mt] = *(const bfrag*)(seA_b + (mt * 16 + lrow) * 528 + k * 2);
#pragma unroll
          for (int i = 0; i < 4; ++i) {
            bfrag bb = *(const bfrag*)(wstep + (size_t)((w * 4 + i) * 16 + lrow) * SS + k);
#pragma unroll
            for (int mt = 0; mt < 3; ++mt) aX[mt][i] = MFMA(af[mt], bb, aX[mt][i]);
          }
        }
#pragma unroll
        for (int mt = 0; mt < 3; ++mt)
#pragma unroll
          for (int i = 0; i < 4; ++i) {
            int s = (w * 4 + i) * 16 + lrow, m0 = mt * 16 + rsub;
            unsigned int lo = (unsigned int)f2b(aX[mt][i][0]) | ((unsigned int)f2b(aX[mt][i][1]) << 16);
            unsigned int hi = (unsigned int)f2b(aX[mt][i][2]) | ((unsigned int)f2b(aX[mt][i][3]) << 16);
            *(uint2*)(XT_b + s * 144 + m0 * 2) = make_uint2(lo, hi);
          }
      }
      __syncthreads();
      // out^T = X^T @ E^T ; seA = relu(out + bg)
      {
        f32x4 aO[4][3] = {};
        for (int kc = 0; kc < 2; ++kc) {
          int k = kc * 32 + lk;
          bfrag eb[3];
#pragma unroll
          for (int nt = 0; nt < 3; ++nt)
            eb[nt] = *(const bfrag*)(Eb + (nt * 16 + lrow) * 144 + k * 2);
#pragma unroll
          for (int i = 0; i < 4; ++i) {
            bfrag xa = *(const bfrag*)(XT_b + ((w * 4 + i) * 16 + lrow) * 144 + k * 2);
#pragma unroll
            for (int nt = 0; nt < 3; ++nt) aO[i][nt] = MFMA(xa, eb[nt], aO[i][nt]);
          }
        }
#pragma unroll
        for (int i = 0; i < 4; ++i) {
          int sbase = (w * 4 + i) * 16 + rsub;
          float4 bgv = *(const float4*)&bg3[step * SS + sbase];
          float bga[4] = {bgv.x, bgv.y, bgv.z, bgv.w};
#pragma unroll
          for (int nt = 0; nt < 3; ++nt) {
            int n = nt * 16 + lrow;
            if (n < NN) {
#pragma unroll
              for (int r = 0; r < 4; ++r) {
                float v = aO[i][nt][r] + bga[r];
                v = v > 0.f ? v : 0.f;
                *(unsigned short*)(seA_b + n * 528 + (sbase + r) * 2) = f2b(v);
              }
            }
          }
        }
      }
      __syncthreads();
    }
  }

  // ================ eval: sigmoid(seA[0] @ W_eval + b_eval)
  if (tid < 64) {
    const char* seA_b = smem + OFF_SEA;
    uint2 u = *(const uint2*)(seA_b + tid * 8);
    float4 w4 = *(const float4*)&W_eval[tid * 4];
    float s = b2f(u.x & 0xffff) * w4.x + b2f(u.x >> 16) * w4.y +
              b2f(u.y & 0xffff) * w4.z + b2f(u.y >> 16) * w4.w;
    s = warp_reduce_sum64(s);
    if (tid == 0) out[b * 64 + c] = 1.0f / (1.0f + expf(-(s + b_eval[0])));
  }
}

extern "C" void kernel_launch(void* const* d_in, const int* in_sizes, int n_in,
                              void* d_out, int out_size, void* d_ws, size_t ws_size,
                              hipStream_t stream) {
  (void)in_sizes; (void)n_in; (void)out_size; (void)ws_size;
  const float* img = (const float*)d_in[0];
  const float* cap = (const float*)d_in[1];
  const float* vG_Wl = (const float*)d_in[3];
  const float* vG_bl = (const float*)d_in[4];
  const float* vG_Wg = (const float*)d_in[5];
  const float* vG_bg = (const float*)d_in[6];
  const float* vG_Wc = (const float*)d_in[7];
  const float* vG_bc = (const float*)d_in[8];
  const float* tG_Wl = (const float*)d_in[9];
  const float* tG_bl = (const float*)d_in[10];
  const float* tG_Wg = (const float*)d_in[11];
  const float* tG_bg = (const float*)d_in[12];
  const float* tG_Wc = (const float*)d_in[13];
  const float* tG_bc = (const float*)d_in[14];
  const float* W_loc = (const float*)d_in[15];
  const float* b_loc = (const float*)d_in[16];
  const float* W_glo = (const float*)d_in[17];
  const float* b_glo = (const float*)d_in[18];
  const float* W_eval = (const float*)d_in[19];
  const float* b_eval = (const float*)d_in[20];
  const float* sgr_Wq = (const float*)d_in[21];
  const float* sgr_bq = (const float*)d_in[22];
  const float* sgr_Wk = (const float*)d_in[23];
  const float* sgr_Wg = (const float*)d_in[25];
  const float* sgr_bg = (const float*)d_in[26];
  float* out = (float*)d_out;
  float* ws = (float*)d_ws;
  float* img_avg = ws;
  float* cap_avg = ws + 65536;
  float* h_img = ws + 131072;
  float* h_cap = ws + 196608;
  float* part_img = ws + 262144;
  float* part_cap = ws + 462848;
  float* img_glob = ws + 495616;
  float* cap_glob = ws + 561152;
  float* simglo = ws + 626688;
  float* wkbqv = ws + 1675264;
  // bf16 region (u16 units) starts at float offset 1676032 (16B aligned)
  unsigned short* ub = (unsigned short*)(ws + 1676032);
  unsigned short* mt_bf = ub;                  // 3*256*256    = 196608
  unsigned short* wgT_bf = ub + 196608;        // 3*256*256    = 196608
  unsigned short* wlocT_bf = ub + 393216;      // 256*1024     = 262144
  unsigned short* cap_bf = ub + 655360;        // 64*32*1024   = 2097152
  unsigned short* gram_bf = ub + 2752512;      // 64*208*224   = 2981888
  unsigned short* imgT_bf = ub + 5734400;      // 64*1024*224  = 14680064
  // total ws use ~47.5 MB

  k_avg<<<128, 256, 0, stream>>>(img, cap, img_avg, cap_avg);
  k_hvec<<<256, 256, 0, stream>>>(img_avg, vG_Wg, vG_bg, vG_Wc, h_img);
  k_hvec<<<256, 256, 0, stream>>>(cap_avg, tG_Wg, tG_bg, tG_Wc, h_cap);
  k_logits_partial<<<dim3(196, 16), 256, 0, stream>>>(img + DD, (long)NTOK * DD, TT, vG_Wl,
                                                      vG_bl, h_img, part_img);
  k_logits_partial<<<dim3(32, 16), 256, 0, stream>>>(cap, (long)CL * DD, CL, tG_Wl, tG_bl,
                                                     h_cap, part_cap);
  k_finish_global<<<64, 256, 0, stream>>>(part_img, vG_bc, img + DD, (long)NTOK * DD, TT,
                                          img_glob);
  k_finish_global<<<64, 256, 0, stream>>>(part_cap, tG_bc, cap, (long)CL * DD, CL, cap_glob);
  k_simglo<<<256, 256, 0, stream>>>(img_glob, cap_glob, W_glo, b_glo, simglo);
  k_mmatb<<<48, 256, 0, stream>>>(sgr_Wk, sgr_Wq, mt_bf);  // MT = Wk@Wq^T = (Wq@Wk^T)^T
  k_wkbq<<<3, 256, 0, stream>>>(sgr_Wk, sgr_bq, wkbqv);
  k_gramb<<<dim3(64, 4, 4), 256, 0, stream>>>(img, gram_bf);
  k_castb<<<2048, 256, 0, stream>>>(cap, cap_bf, 524288);
  k_tcast<<<dim3(8, 8, 3), 256, 0, stream>>>(sgr_Wg, wgT_bf, 256, 256, 65536, 65536);
  k_tcast<<<dim3(8, 32, 1), 256, 0, stream>>>(W_loc, wlocT_bf, 1024, 256, 0, 0);
  k_imgt<<<dim3(32, 7, 64), 256, 0, stream>>>(img, imgT_bf);
  hipFuncSetAttribute((const void*)k_pair, hipFuncAttributeMaxDynamicSharedMemorySize,
                      SMEM_BYTES);
  k_pair<<<4096, 256, SMEM_BYTES, stream>>>(img, cap, b_loc, simglo, wkbqv, sgr_bg, W_eval,
                                            b_eval, cap_bf, imgT_bf, gram_bf, wlocT_bf,
                                            mt_bf, wgT_bf, out);
}

// Round 6
// 2086.610 us; speedup vs baseline: 11.0872x; 1.3309x over previous
//
#include <hip/hip_runtime.h>
#include <hip/hip_bf16.h>
#include <math.h>

#define NI 64
#define NC 64
#define NTOK 197
#define TT 196
#define CL 32
#define DD 1024
#define SS 256
#define NN 33
#define EPSN 1e-12f
#define SMOOTHF 9.0f
#define TP 224   // padded token dim for MFMA K

typedef __attribute__((ext_vector_type(8))) short bfrag;
typedef __attribute__((ext_vector_type(4))) float f32x4;
#define MFMA(a, b, c) __builtin_amdgcn_mfma_f32_16x16x32_bf16((a), (b), (c), 0, 0, 0)

// LDS layout (byte offsets) — phase A/W region
#define OFF_ATTN   0        // [196][34] f32 = 26656
#define OFF_ATTNT  26656    // [32][232] u16 = 14848 -> 41504
#define OFF_WTILE  41504    // [32][136] u16 = 8704 -> 50208
#define OFF_NRMS   50208    // [32] f32 -> 50336
#define OFF_QN     50336    // [128] f32 -> 50848
#define OFF_RNQ    50848    // [32] f32 -> 50976
// SGR overlays
#define OFF_SEA    0        // [48][264] u16 = 25344
#define OFF_GC     25344    // Gchunk [48][72] u16 = 6912 ; XT chunk [64][72] u16 = 9216 -> 34560
#define OFF_EF     34560    // [33][34] f32 = 4488 -> 39048
#define OFF_EB     39048    // [48][72] u16 = 6912 -> 45960
#define OFF_WKQ    45960    // [256] f32 -> 46984
#define OFF_VBUF   46984    // [36] f32 -> 47128
#define SMEM_BYTES 50976

__device__ __forceinline__ float warp_reduce_sum64(float v) {
#pragma unroll
  for (int m = 32; m > 0; m >>= 1) v += __shfl_xor(v, m, 64);
  return v;
}
__device__ __forceinline__ unsigned short f2b(float f) {
  __hip_bfloat16 h = __float2bfloat16(f);
  return *reinterpret_cast<unsigned short*>(&h);
}
__device__ __forceinline__ float b2f(unsigned short u) {
  union { unsigned int i; float f; } v;
  v.i = ((unsigned int)u) << 16;
  return v.f;
}

// ---------------------------------------------------------------- K1: means
__global__ void k_avg(const float* __restrict__ img, const float* __restrict__ cap,
                      float* __restrict__ img_avg, float* __restrict__ cap_avg) {
  int bid = blockIdx.x;
  int tid = threadIdx.x;
  if (bid < NI) {
    int b = bid;
    for (int d = tid; d < DD; d += 256) {
      float acc = 0.f;
      const float* p = img + ((size_t)b * NTOK + 1) * DD + d;
      for (int t = 0; t < TT; ++t) acc += p[(size_t)t * DD];
      img_avg[b * DD + d] = acc * (1.0f / TT);
    }
  } else {
    int c = bid - NI;
    for (int d = tid; d < DD; d += 256) {
      float acc = 0.f;
      const float* p = cap + (size_t)c * CL * DD + d;
      for (int t = 0; t < CL; ++t) acc += p[(size_t)t * DD];
      cap_avg[c * DD + d] = acc * (1.0f / CL);
    }
  }
}

// ------------------------------------------------- K2: h = tanh(avg@Wg+bg)*Wc
__global__ void k_hvec(const float* __restrict__ avg, const float* __restrict__ Wg,
                       const float* __restrict__ bg, const float* __restrict__ Wc,
                       float* __restrict__ h) {
  __shared__ float av[DD];
  int b = blockIdx.x >> 2;
  int dc = blockIdx.x & 3;
  int tid = threadIdx.x;
  for (int i = tid; i < DD; i += 256) av[i] = avg[b * DD + i];
  __syncthreads();
  int d = dc * 256 + tid;
  float acc = 0.f;
  for (int k = 0; k < DD; k += 4) {
    float4 a4 = *(const float4*)&av[k];
    acc += a4.x * Wg[(size_t)(k + 0) * DD + d];
    acc += a4.y * Wg[(size_t)(k + 1) * DD + d];
    acc += a4.z * Wg[(size_t)(k + 2) * DD + d];
    acc += a4.w * Wg[(size_t)(k + 3) * DD + d];
  }
  h[b * DD + d] = tanhf(acc + bg[d]) * Wc[d];
}

// ---------------- K3 (MFMA): partial[row,ct] = sum_{c in tile} tanh((A@Wl)[row,c]+bl)*h[b,c]
__global__ void k_logits_mfma(const unsigned short* __restrict__ Abf, int rowsPerBatch,
                              const unsigned short* __restrict__ WT,
                              const float* __restrict__ bl, const float* __restrict__ h,
                              float* __restrict__ partial) {
  int tid = threadIdx.x;
  int lane = tid & 63, w = tid >> 6;
  int lrow = lane & 15, lk = (lane >> 4) * 8, rsub = (lane >> 4) * 4;
  int rb = blockIdx.x * 64, c0 = blockIdx.y * 64;
  const unsigned short* ap = Abf + (size_t)(rb + w * 16 + lrow) * DD;
  f32x4 acc[4] = {};
  for (int k0 = 0; k0 < DD; k0 += 32) {
    bfrag a = *(const bfrag*)(ap + k0 + lk);
#pragma unroll
    for (int i = 0; i < 4; ++i) {
      bfrag bb = *(const bfrag*)(WT + (size_t)(c0 + i * 16 + lrow) * DD + k0 + lk);
      acc[i] = MFMA(a, bb, acc[i]);
    }
  }
#pragma unroll
  for (int r = 0; r < 4; ++r) {
    int row = rb + w * 16 + rsub + r;
    int bb2 = row / rowsPerBatch;
    float s = 0.f;
#pragma unroll
    for (int i = 0; i < 4; ++i) {
      int col = c0 + i * 16 + lrow;
      s += tanhf(acc[i][r] + bl[col]) * h[bb2 * DD + col];
    }
    s += __shfl_xor(s, 1, 64);
    s += __shfl_xor(s, 2, 64);
    s += __shfl_xor(s, 4, 64);
    s += __shfl_xor(s, 8, 64);
    if (lrow == 0) partial[(size_t)row * 16 + blockIdx.y] = s;
  }
}

// -------- K4: finish global attention pooling
__global__ void k_finish_global(const float* __restrict__ partial, const float* __restrict__ bc,
                                const float* __restrict__ Xbase, long batchStride, int R,
                                float* __restrict__ outG) {
  __shared__ float w[200];
  __shared__ float red[8];
  int b = blockIdx.x, tid = threadIdx.x;
  for (int t = tid; t < R; t += 256) {
    const float* pp = &partial[((size_t)b * R + t) * 16];
    float s = bc[0];
#pragma unroll
    for (int u = 0; u < 16; ++u) s += pp[u];
    w[t] = s;
  }
  __syncthreads();
  float m = -1e30f;
  for (int t = tid; t < R; t += 256) m = fmaxf(m, w[t]);
#pragma unroll
  for (int mm = 32; mm; mm >>= 1) m = fmaxf(m, __shfl_xor(m, mm, 64));
  if ((tid & 63) == 0) red[tid >> 6] = m;
  __syncthreads();
  m = fmaxf(fmaxf(red[0], red[1]), fmaxf(red[2], red[3]));
  __syncthreads();
  for (int t = tid; t < R; t += 256) w[t] = expf(w[t] - m);
  __syncthreads();
  const float* xb = Xbase + (size_t)b * batchStride;
  float acc[4];
  float ss = 0.f;
#pragma unroll
  for (int c4 = 0; c4 < 4; ++c4) {
    int d = tid + c4 * 256;
    float a = 0.f;
    for (int t = 0; t < R; ++t) a += w[t] * xb[(size_t)t * DD + d];
    acc[c4] = a;
    ss += a * a;
  }
  ss = warp_reduce_sum64(ss);
  if ((tid & 63) == 0) red[tid >> 6] = ss;
  __syncthreads();
  ss = red[0] + red[1] + red[2] + red[3];
  float rn = 1.0f / fmaxf(sqrtf(ss), EPSN);
#pragma unroll
  for (int c4 = 0; c4 < 4; ++c4) outG[(size_t)b * DD + tid + c4 * 256] = acc[c4] * rn;
}

// -------- K5: sim_glo
__global__ void k_simglo(const float* __restrict__ ig, const float* __restrict__ cg,
                         const float* __restrict__ W, const float* __restrict__ bgl,
                         float* __restrict__ simglo) {
  __shared__ float a_lds[32][20];
  __shared__ float b_lds[32][260];
  int tid = threadIdx.x;
  int p0 = blockIdx.x * 16;
  int ty = tid >> 6, tx = tid & 63;
  int s_rr = tid >> 3, s_kq = tid & 7;
  float acc[4][4] = {};
  for (int k0 = 0; k0 < DD; k0 += 32) {
    float d2[4] = {};
    if (tid < 128) {
      int p = p0 + s_rr;
      int b = p >> 6, c = p & 63;
      float4 giv = *(const float4*)&ig[b * DD + k0 + s_kq * 4];
      float4 cgv = *(const float4*)&cg[c * DD + k0 + s_kq * 4];
      float dx = giv.x - cgv.x, dy = giv.y - cgv.y, dz = giv.z - cgv.z, dw = giv.w - cgv.w;
      d2[0] = dx * dx; d2[1] = dy * dy; d2[2] = dz * dz; d2[3] = dw * dw;
    }
    float4 wv[8];
#pragma unroll
    for (int u = 0; u < 8; ++u)
      wv[u] = *(const float4*)&W[(size_t)(k0 + s_rr) * SS + s_kq * 32 + u * 4];
    __syncthreads();
    if (tid < 128) {
#pragma unroll
      for (int u = 0; u < 4; ++u) a_lds[s_kq * 4 + u][s_rr] = d2[u];
    }
#pragma unroll
    for (int u = 0; u < 8; ++u)
      *(float4*)&b_lds[s_rr][s_kq * 32 + u * 4] = wv[u];
    __syncthreads();
#pragma unroll
    for (int kk = 0; kk < 32; ++kk) {
      float4 a4 = *(const float4*)&a_lds[kk][ty * 4];
      float4 b4 = *(const float4*)&b_lds[kk][tx * 4];
      float av[4] = {a4.x, a4.y, a4.z, a4.w};
      float bv[4] = {b4.x, b4.y, b4.z, b4.w};
#pragma unroll
      for (int i = 0; i < 4; ++i)
#pragma unroll
        for (int j = 0; j < 4; ++j) acc[i][j] += av[i] * bv[j];
    }
  }
#pragma unroll
  for (int i = 0; i < 4; ++i) {
    float v[4];
    float ssq = 0.f;
#pragma unroll
    for (int j = 0; j < 4; ++j) {
      v[j] = acc[i][j] + bgl[tx * 4 + j];
      ssq += v[j] * v[j];
    }
    ssq = warp_reduce_sum64(ssq);
    float rn = 1.0f / fmaxf(sqrtf(ssq), EPSN);
    int p = p0 + ty * 4 + i;
    *(float4*)&simglo[(size_t)p * SS + tx * 4] =
        make_float4(v[0] * rn, v[1] * rn, v[2] * rn, v[3] * rn);
  }
}

// -------- K6: MT_bf16[t] = A_t @ B_t^T (256x256), bf16 out.
__global__ void k_mmatb(const float* __restrict__ Wa, const float* __restrict__ Wb,
                        unsigned short* __restrict__ M) {
  __shared__ float a_lds[32][68];
  __shared__ float b_lds[32][68];
  int tid = threadIdx.x;
  int t = blockIdx.x >> 4;
  int dt = (blockIdx.x >> 2) & 3, et = blockIdx.x & 3;
  int d0 = dt * 64, e0 = et * 64;
  const float* wq = Wa + (size_t)t * SS * SS;
  const float* wk = Wb + (size_t)t * SS * SS;
  int ty = tid >> 4, tx = tid & 15;
  int s_rr = tid >> 2, s_kq = tid & 3;
  float acc[4][4] = {};
  for (int j0 = 0; j0 < SS; j0 += 32) {
    float4 q0 = *(const float4*)&wq[(size_t)(d0 + s_rr) * SS + j0 + s_kq * 8];
    float4 q1 = *(const float4*)&wq[(size_t)(d0 + s_rr) * SS + j0 + s_kq * 8 + 4];
    float4 k0v = *(const float4*)&wk[(size_t)(e0 + s_rr) * SS + j0 + s_kq * 8];
    float4 k1v = *(const float4*)&wk[(size_t)(e0 + s_rr) * SS + j0 + s_kq * 8 + 4];
    __syncthreads();
    float qa[8] = {q0.x, q0.y, q0.z, q0.w, q1.x, q1.y, q1.z, q1.w};
    float ka[8] = {k0v.x, k0v.y, k0v.z, k0v.w, k1v.x, k1v.y, k1v.z, k1v.w};
#pragma unroll
    for (int u = 0; u < 8; ++u) {
      a_lds[s_kq * 8 + u][s_rr] = qa[u];
      b_lds[s_kq * 8 + u][s_rr] = ka[u];
    }
    __syncthreads();
#pragma unroll
    for (int kk = 0; kk < 32; ++kk) {
      float4 a4 = *(const float4*)&a_lds[kk][ty * 4];
      float4 b4 = *(const float4*)&b_lds[kk][tx * 4];
      float av[4] = {a4.x, a4.y, a4.z, a4.w};
      float bv[4] = {b4.x, b4.y, b4.z, b4.w};
#pragma unroll
      for (int i = 0; i < 4; ++i)
#pragma unroll
        for (int j = 0; j < 4; ++j) acc[i][j] += av[i] * bv[j];
    }
  }
#pragma unroll
  for (int i = 0; i < 4; ++i) {
    unsigned int lo = (unsigned int)f2b(acc[i][0]) | ((unsigned int)f2b(acc[i][1]) << 16);
    unsigned int hi = (unsigned int)f2b(acc[i][2]) | ((unsigned int)f2b(acc[i][3]) << 16);
    uint2 o = make_uint2(lo, hi);
    *(uint2*)(M + (size_t)t * SS * SS + (size_t)(d0 + ty * 4 + i) * SS + e0 + tx * 4) = o;
  }
}

// -------- K6b: wkbq[t] = Wk_t @ bq_t
__global__ void k_wkbq(const float* __restrict__ Wk, const float* __restrict__ bq,
                       float* __restrict__ out) {
  __shared__ float bv[SS];
  int t = blockIdx.x, tid = threadIdx.x;
  const float* wk = Wk + (size_t)t * SS * SS;
  bv[tid] = bq[t * SS + tid];
  __syncthreads();
  float acc = 0.f;
  for (int j = 0; j < SS; j += 4) {
    float4 wv = *(const float4*)&wk[(size_t)tid * SS + j];
    float4 b4 = *(const float4*)&bv[j];
    acc += wv.x * b4.x + wv.y * b4.y + wv.z * b4.z + wv.w * b4.w;
  }
  out[t * SS + tid] = acc;
}

// -------- img_bf[b][t][d] = bf16(img[b][1+t][d]), contiguous rows
__global__ void k_imgbf(const float* __restrict__ img, unsigned short* __restrict__ dst) {
  int r = blockIdx.x;  // 12544
  int b = r / TT, t = r - b * TT;
  const float* s = img + ((size_t)b * NTOK + 1 + t) * DD + threadIdx.x * 4;
  float4 v = *(const float4*)s;
  uint2 o;
  o.x = (unsigned int)f2b(v.x) | ((unsigned int)f2b(v.y) << 16);
  o.y = (unsigned int)f2b(v.z) | ((unsigned int)f2b(v.w) << 16);
  *(uint2*)(dst + (size_t)r * DD + threadIdx.x * 4) = o;
}

// -------- K6c (MFMA): gram_bf16[b] = imgTok_b @ imgTok_b^T in [208][224] zero-padded
__global__ void k_gram_mfma(const unsigned short* __restrict__ img_bf,
                            unsigned short* __restrict__ gram) {
  int tid = threadIdx.x;
  int lane = tid & 63, w = tid >> 6;
  int lrow = lane & 15, lk = (lane >> 4) * 8, rsub = (lane >> 4) * 4;
  int bimg = blockIdx.x;
  int rb = blockIdx.y * 64, cb = blockIdx.z * 64;
  const unsigned short* X = img_bf + (size_t)bimg * TT * DD;
  int ra = rb + w * 16 + lrow;
  if (ra > TT - 1) ra = TT - 1;
  f32x4 acc[4] = {};
  for (int k0 = 0; k0 < DD; k0 += 32) {
    bfrag a = *(const bfrag*)(X + (size_t)ra * DD + k0 + lk);
#pragma unroll
    for (int i = 0; i < 4; ++i) {
      int cc = cb + i * 16 + lrow;
      if (cc > TT - 1) cc = TT - 1;
      bfrag bb = *(const bfrag*)(X + (size_t)cc * DD + k0 + lk);
      acc[i] = MFMA(a, bb, acc[i]);
    }
  }
  unsigned short* Gp = gram + (size_t)bimg * 208 * TP;
#pragma unroll
  for (int i = 0; i < 4; ++i) {
    int cc = cb + i * 16 + lrow;
#pragma unroll
    for (int r = 0; r < 4; ++r) {
      int rr = rb + w * 16 + rsub + r;
      if (rr < 208 && cc < TP)
        Gp[(size_t)rr * TP + cc] = (rr < TT && cc < TT) ? f2b(acc[i][r]) : 0;
    }
  }
}

// -------- cast f32 -> bf16 (same layout)
__global__ void k_castb(const float* __restrict__ s, unsigned short* __restrict__ d, int n4) {
  int i = blockIdx.x * 256 + threadIdx.x;
  if (i < n4) {
    float4 v = *(const float4*)(s + (size_t)i * 4);
    uint2 o;
    o.x = (unsigned int)f2b(v.x) | ((unsigned int)f2b(v.y) << 16);
    o.y = (unsigned int)f2b(v.z) | ((unsigned int)f2b(v.w) << 16);
    *(uint2*)(d + (size_t)i * 4) = o;
  }
}

// -------- transpose-cast: src[R][C] f32 -> dst[C][R] bf16 (batched via z)
__global__ void k_tcast(const float* __restrict__ src, unsigned short* __restrict__ dst,
                        int R, int C, long sB, long dB) {
  __shared__ float t[32][33];
  const float* s = src + (size_t)blockIdx.z * sB;
  unsigned short* d = dst + (size_t)blockIdx.z * dB;
  int r0 = blockIdx.y * 32, c0 = blockIdx.x * 32;
  int tx = threadIdx.x & 31, ty = threadIdx.x >> 5;
#pragma unroll
  for (int u = 0; u < 4; ++u)
    t[ty + u * 8][tx] = s[(size_t)(r0 + ty + u * 8) * C + c0 + tx];
  __syncthreads();
#pragma unroll
  for (int u = 0; u < 4; ++u)
    d[(size_t)(c0 + ty + u * 8) * R + r0 + tx] = f2b(t[tx][ty + u * 8]);
}

// -------- imgT_bf16[b][d][t(224 pad0)] = img[b][1+t][d]
__global__ void k_imgt(const float* __restrict__ img, unsigned short* __restrict__ dst) {
  __shared__ float t[32][33];
  int b = blockIdx.z;
  int t0 = blockIdx.y * 32, d0 = blockIdx.x * 32;
  int tx = threadIdx.x & 31, ty = threadIdx.x >> 5;
#pragma unroll
  for (int u = 0; u < 4; ++u) {
    int tt = t0 + ty + u * 8;
    t[ty + u * 8][tx] = (tt < TT) ? img[((size_t)b * NTOK + 1 + tt) * DD + d0 + tx] : 0.f;
  }
  __syncthreads();
#pragma unroll
  for (int u = 0; u < 4; ++u)
    dst[((size_t)b * DD + d0 + ty + u * 8) * TP + t0 + tx] = f2b(t[tx][ty + u * 8]);
}

// -------- K7: per-(img,cap) pair mega kernel (v6: bf16 loads, 51KB LDS, chunked SGR)
__global__ __launch_bounds__(256) void k_pair(
    const float* __restrict__ b_loc, const float* __restrict__ simglo,
    const float* __restrict__ wkbq, const float* __restrict__ bg3,
    const float* __restrict__ W_eval, const float* __restrict__ b_eval,
    const unsigned short* __restrict__ cap_bf, const unsigned short* __restrict__ img_bf,
    const unsigned short* __restrict__ imgT_bf, const unsigned short* __restrict__ gram_bf,
    const unsigned short* __restrict__ wlocT_bf, const unsigned short* __restrict__ mt_bf,
    const unsigned short* __restrict__ wgT_bf, float* __restrict__ out) {
  extern __shared__ char smem[];
  float* attn = (float*)(smem + OFF_ATTN);

  int tid = threadIdx.x;
  int lane = tid & 63, w = tid >> 6;
  int lrow = lane & 15;        // MFMA row/col select
  int lk = (lane >> 4) * 8;    // MFMA k-offset
  int rsub = (lane >> 4) * 4;  // D-frag row base
  int p = blockIdx.x;
  int b = p >> 6, c = p & 63;
  const unsigned short* imgR = img_bf + (size_t)b * TT * DD;
  const unsigned short* capB = cap_bf + (size_t)c * CL * DD;

  // ================ Phase A: S[t][q] = leaky(imgTok . cap) via MFMA (bf16 direct loads)
  {
    f32x4 acc[4][2] = {};
    for (int k0 = 0; k0 < DD; k0 += 32) {
      bfrag bq0 = *(const bfrag*)(capB + (size_t)lrow * DD + k0 + lk);
      bfrag bq1 = *(const bfrag*)(capB + (size_t)(16 + lrow) * DD + k0 + lk);
#pragma unroll
      for (int i = 0; i < 4; ++i) {
        int tt = w + 4 * i;
        if (tt < 13) {
          int t = tt * 16 + lrow;
          bfrag a = {0, 0, 0, 0, 0, 0, 0, 0};
          if (t < TT) a = *(const bfrag*)(imgR + (size_t)t * DD + k0 + lk);
          acc[i][0] = MFMA(a, bq0, acc[i][0]);
          acc[i][1] = MFMA(a, bq1, acc[i][1]);
        }
      }
    }
#pragma unroll
    for (int i = 0; i < 4; ++i) {
      int tt = w + 4 * i;
      if (tt < 13) {
#pragma unroll
        for (int qt = 0; qt < 2; ++qt)
#pragma unroll
          for (int r = 0; r < 4; ++r) {
            int t = tt * 16 + rsub + r;
            if (t < TT) {
              float v = acc[i][qt][r];
              attn[t * 34 + qt * 16 + lrow] = v < 0.f ? 0.1f * v : v;
            }
          }
      }
    }
  }
  __syncthreads();

  // ================ A2: l2norm over q per token row
  if (tid < TT) {
    float ss = 0.f;
#pragma unroll
    for (int q = 0; q < 32; ++q) {
      float v = attn[tid * 34 + q];
      ss += v * v;
    }
    float rn = 1.0f / fmaxf(sqrtf(ss), EPSN);
#pragma unroll
    for (int q = 0; q < 32; ++q) attn[tid * 34 + q] *= rn;
  }
  __syncthreads();

  // ================ A3: softmax-exp (x9) over t per q (denominator dropped)
  {
    int q = tid >> 3, sub = tid & 7;
    float m = -1e30f;
    for (int t = sub; t < TT; t += 8) m = fmaxf(m, attn[t * 34 + q]);
    m = fmaxf(m, __shfl_xor(m, 1, 64));
    m = fmaxf(m, __shfl_xor(m, 2, 64));
    m = fmaxf(m, __shfl_xor(m, 4, 64));
    for (int t = sub; t < TT; t += 8)
      attn[t * 34 + q] = expf(SMOOTHF * (attn[t * 34 + q] - m));
  }
  __syncthreads();

  // ================ build attnT_bf16[q][t] (exp weights, zero-padded to 224)
  {
    char* attnT_b = smem + OFF_ATTNT;
    for (int idx = tid; idx < 32 * 116; idx += 256) {
      int q = idx / 116, tp2 = (idx - q * 116) * 2;
      unsigned int lo = (tp2 < TT) ? (unsigned int)f2b(attn[tp2 * 34 + q]) : 0u;
      unsigned int hi = (tp2 + 1 < TT) ? (unsigned int)f2b(attn[(tp2 + 1) * 34 + q]) : 0u;
      *(unsigned int*)(attnT_b + q * 464 + tp2 * 2) = lo | (hi << 16);
    }
  }
  __syncthreads();

  // ================ norm via Gram (MFMA): Y = G@E, norm2[q] = sum_t w[t][q]*Y[t][q]
  {
    const char* attnT_b = smem + OFF_ATTNT;
    float* qn = (float*)(smem + OFF_QN);
    float* nrmS = (float*)(smem + OFF_NRMS);
    const unsigned short* gb = gram_bf + (size_t)b * 208 * TP;
    float part0 = 0.f, part1 = 0.f;
#pragma unroll
    for (int i = 0; i < 4; ++i) {
      int tt = w + 4 * i;
      if (tt < 13) {
        f32x4 y0 = {0.f, 0.f, 0.f, 0.f}, y1 = {0.f, 0.f, 0.f, 0.f};
        for (int t0 = 0; t0 < TP; t0 += 32) {
          bfrag a = *(const bfrag*)(gb + (size_t)(tt * 16 + lrow) * TP + t0 + lk);
          bfrag b0 = *(const bfrag*)(attnT_b + lrow * 464 + (t0 + lk) * 2);
          bfrag b1 = *(const bfrag*)(attnT_b + (16 + lrow) * 464 + (t0 + lk) * 2);
          y0 = MFMA(a, b0, y0);
          y1 = MFMA(a, b1, y1);
        }
#pragma unroll
        for (int r = 0; r < 4; ++r) {
          int t = tt * 16 + rsub + r;
          if (t < TT) {
            part0 += y0[r] * attn[t * 34 + lrow];
            part1 += y1[r] * attn[t * 34 + 16 + lrow];
          }
        }
      }
    }
    part0 += __shfl_xor(part0, 16, 64); part0 += __shfl_xor(part0, 32, 64);
    part1 += __shfl_xor(part1, 16, 64); part1 += __shfl_xor(part1, 32, 64);
    if ((lane >> 4) == 0) {
      qn[w * 32 + lrow] = part0;
      qn[w * 32 + 16 + lrow] = part1;
    }
    __syncthreads();
    if (tid < 32)
      nrmS[tid] = 1.0f / fmaxf(sqrtf(qn[tid] + qn[32 + tid] + qn[64 + tid] + qn[96 + tid]), EPSN);
    __syncthreads();
  }

  // ================ Phase W: ctx (MFMA) -> diff^2 -> @W_loc (MFMA)
  f32x4 accW[2][4] = {};
  {
    const char* attnT_b = smem + OFF_ATTNT;
    char* wtile_b = smem + OFF_WTILE;
    float* nrmS = (float*)(smem + OFF_NRMS);
    float nrm0 = nrmS[lrow], nrm1 = nrmS[16 + lrow];
    for (int d0 = 0; d0 < DD; d0 += 128) {
      f32x4 c2[2][2] = {};
      for (int t0 = 0; t0 < TP; t0 += 32) {
        bfrag b0 = *(const bfrag*)(attnT_b + lrow * 464 + (t0 + lk) * 2);
        bfrag b1 = *(const bfrag*)(attnT_b + (16 + lrow) * 464 + (t0 + lk) * 2);
#pragma unroll
        for (int i = 0; i < 2; ++i) {
          int dt = w + 4 * i;
          bfrag a = *(const bfrag*)(imgT_bf + ((size_t)b * DD + d0 + dt * 16 + lrow) * TP + t0 + lk);
          c2[i][0] = MFMA(a, b0, c2[i][0]);
          c2[i][1] = MFMA(a, b1, c2[i][1]);
        }
      }
      __syncthreads();  // prev W_loc readers of wtile done
#pragma unroll
      for (int i = 0; i < 2; ++i) {
        int dl = (w + 4 * i) * 16 + rsub;
#pragma unroll
        for (int qt = 0; qt < 2; ++qt) {
          int q = qt * 16 + lrow;
          uint2 cu = *(const uint2*)(capB + (size_t)q * DD + d0 + dl);
          float cf0 = b2f(cu.x & 0xffff), cf1 = b2f(cu.x >> 16);
          float cf2 = b2f(cu.y & 0xffff), cf3 = b2f(cu.y >> 16);
          float rn = qt ? nrm1 : nrm0;
          float v0 = c2[i][qt][0] * rn - cf0;
          float v1 = c2[i][qt][1] * rn - cf1;
          float v2 = c2[i][qt][2] * rn - cf2;
          float v3 = c2[i][qt][3] * rn - cf3;
          unsigned int lo = (unsigned int)f2b(v0 * v0) | ((unsigned int)f2b(v1 * v1) << 16);
          unsigned int hi = (unsigned int)f2b(v2 * v2) | ((unsigned int)f2b(v3 * v3) << 16);
          *(uint2*)(wtile_b + q * 272 + dl * 2) = make_uint2(lo, hi);
        }
      }
      __syncthreads();
      for (int kc = 0; kc < 4; ++kc) {
        bfrag a0 = *(const bfrag*)(wtile_b + lrow * 272 + (kc * 32 + lk) * 2);
        bfrag a1 = *(const bfrag*)(wtile_b + (16 + lrow) * 272 + (kc * 32 + lk) * 2);
#pragma unroll
        for (int sti = 0; sti < 4; ++sti) {
          int s = (w * 4 + sti) * 16 + lrow;
          bfrag bb = *(const bfrag*)(wlocT_bf + (size_t)s * DD + d0 + kc * 32 + lk);
          accW[0][sti] = MFMA(a0, bb, accW[0][sti]);
          accW[1][sti] = MFMA(a1, bb, accW[1][sti]);
        }
      }
    }
  }

  // ================ assembly: l2norm(sim_loc)+bias -> seA_bf16 rows 1..32; row 0 simglo
  {
    char* seA_b = smem + OFF_SEA;
    float* qn = (float*)(smem + OFF_QN);
    float* rnq = (float*)(smem + OFF_RNQ);
    __syncthreads();
    for (int i2 = tid; i2 < 6336; i2 += 256) ((unsigned int*)smem)[i2] = 0;  // zero seA
    __syncthreads();
    float blv[4];
#pragma unroll
    for (int sti = 0; sti < 4; ++sti) blv[sti] = b_loc[(w * 4 + sti) * 16 + lrow];
    float ss[2][4];
#pragma unroll
    for (int qt = 0; qt < 2; ++qt)
#pragma unroll
      for (int r = 0; r < 4; ++r) {
        float s2 = 0.f;
#pragma unroll
        for (int sti = 0; sti < 4; ++sti) {
          float v = accW[qt][sti][r] + blv[sti];
          s2 += v * v;
        }
        s2 += __shfl_xor(s2, 1, 64);
        s2 += __shfl_xor(s2, 2, 64);
        s2 += __shfl_xor(s2, 4, 64);
        s2 += __shfl_xor(s2, 8, 64);
        ss[qt][r] = s2;
      }
    if (lrow == 0) {
#pragma unroll
      for (int qt = 0; qt < 2; ++qt)
#pragma unroll
        for (int r = 0; r < 4; ++r)
          qn[w * 32 + qt * 16 + rsub + r] = ss[qt][r];
    }
    __syncthreads();
    if (tid < 32)
      rnq[tid] = 1.0f / fmaxf(sqrtf(qn[tid] + qn[32 + tid] + qn[64 + tid] + qn[96 + tid]), EPSN);
    __syncthreads();
#pragma unroll
    for (int qt = 0; qt < 2; ++qt)
#pragma unroll
      for (int r = 0; r < 4; ++r) {
        int q = qt * 16 + rsub + r;
        float rn = rnq[q];
#pragma unroll
        for (int sti = 0; sti < 4; ++sti) {
          int s = (w * 4 + sti) * 16 + lrow;
          float v = (accW[qt][sti][r] + blv[sti]) * rn;
          *(unsigned short*)(seA_b + (1 + q) * 528 + s * 2) = f2b(v);
        }
      }
    if (tid < 64) {
      float4 g4 = *(const float4*)&simglo[(size_t)p * SS + tid * 4];
      unsigned int lo = (unsigned int)f2b(g4.x) | ((unsigned int)f2b(g4.y) << 16);
      unsigned int hi = (unsigned int)f2b(g4.z) | ((unsigned int)f2b(g4.w) << 16);
      *(uint2*)(seA_b + tid * 8) = make_uint2(lo, hi);
    }
    __syncthreads();
  }

  // ================ SGR x3 (chunked G for E; chunked XT with register O)
  {
    char* seA_b = smem + OFF_SEA;
    char* Gc_b = smem + OFF_GC;   // [48][72] u16 per e-chunk
    char* XT_b = smem + OFF_GC;   // [64][72] u16 per s-chunk (overlays Gc, G dead)
    float* Ef = (float*)(smem + OFF_EF);
    char* Eb = smem + OFF_EB;
    float* wkq = (float*)(smem + OFF_WKQ);
    float* vbuf = (float*)(smem + OFF_VBUF);

    for (int step = 0; step < 3; ++step) {
      const unsigned short* mstep = mt_bf + (size_t)step * SS * SS;
      const unsigned short* wstep = wgT_bf + (size_t)step * SS * SS;
      wkq[tid] = wkbq[step * SS + tid];
      __syncthreads();
      // vbuf[m] = seA[m] . (Wk@bq)
      if (tid < 132) {
        int m = tid >> 2, qq = tid & 3;
        float a = 0.f;
        for (int e = qq * 64; e < qq * 64 + 64; e += 2) {
          unsigned int u = *(const unsigned int*)(seA_b + m * 528 + e * 2);
          a += b2f(u & 0xffff) * wkq[e] + b2f(u >> 16) * wkq[e + 1];
        }
        a += __shfl_xor(a, 1, 64);
        a += __shfl_xor(a, 2, 64);
        if (qq == 0) vbuf[m] = a;
      }
      // E = (seA@M) @ seA^T, e-chunked (G chunk [48][64] in LDS)
      f32x4 aE[3] = {};
      for (int ec = 0; ec < 4; ++ec) {
        f32x4 aGc[3] = {};
        for (int kc = 0; kc < 8; ++kc) {
          int k = kc * 32 + lk;
          bfrag bb = *(const bfrag*)(mstep + (size_t)(ec * 64 + w * 16 + lrow) * SS + k);
#pragma unroll
          for (int mt = 0; mt < 3; ++mt) {
            bfrag af = *(const bfrag*)(seA_b + (mt * 16 + lrow) * 528 + k * 2);
            aGc[mt] = MFMA(af, bb, aGc[mt]);
          }
        }
        __syncthreads();  // prior chunk's Gc readers done
#pragma unroll
        for (int mt = 0; mt < 3; ++mt)
#pragma unroll
          for (int r = 0; r < 4; ++r)
            *(unsigned short*)(Gc_b + (mt * 16 + rsub + r) * 144 + (w * 16 + lrow) * 2) =
                f2b(aGc[mt][r]);
        __syncthreads();
#pragma unroll
        for (int kc = 0; kc < 2; ++kc) {
          int k = kc * 32 + lk;
#pragma unroll
          for (int ti = 0; ti < 3; ++ti) {
            int tile = w + ti * 4;
            if (tile < 9) {
              int mtE = tile / 3, ntE = tile - mtE * 3;
              bfrag ga = *(const bfrag*)(Gc_b + (mtE * 16 + lrow) * 144 + k * 2);
              bfrag sb = *(const bfrag*)(seA_b + (ntE * 16 + lrow) * 528 + (ec * 64 + k) * 2);
              aE[ti] = MFMA(ga, sb, aE[ti]);
            }
          }
        }
      }
#pragma unroll
      for (int ti = 0; ti < 3; ++ti) {
        int tile = w + ti * 4;
        if (tile < 9) {
          int mtE = tile / 3, ntE = tile - mtE * 3;
          int n0 = mtE * 16 + rsub, m = ntE * 16 + lrow;
#pragma unroll
          for (int r = 0; r < 4; ++r)
            if (n0 + r < NN && m < NN) Ef[(n0 + r) * 34 + m] = aE[ti][r] + vbuf[m];
        }
      }
      __syncthreads();
      // row softmax of E
      if (tid < NN) {
        float mx = -1e30f;
        for (int mm = 0; mm < NN; ++mm) mx = fmaxf(mx, Ef[tid * 34 + mm]);
        float sum = 0.f;
        for (int mm = 0; mm < NN; ++mm) {
          float e = expf(Ef[tid * 34 + mm] - mx);
          Ef[tid * 34 + mm] = e;
          sum += e;
        }
        float rs = 1.0f / sum;
        for (int mm = 0; mm < NN; ++mm) Ef[tid * 34 + mm] *= rs;
      }
      __syncthreads();
      // E_bf16 build (zero pads to [48][72])
      for (int idx = tid; idx < 48 * 36; idx += 256) {
        int n = idx / 36, mp = (idx - n * 36) * 2;
        unsigned int lo = (n < NN && mp < NN) ? (unsigned int)f2b(Ef[n * 34 + mp]) : 0u;
        unsigned int hi = (n < NN && mp + 1 < NN) ? (unsigned int)f2b(Ef[n * 34 + mp + 1]) : 0u;
        *(unsigned int*)(Eb + n * 144 + mp * 2) = lo | (hi << 16);
      }
      __syncthreads();  // Eb ready; Gc/Ef dead -> XT may overlay
      // X = seA @ Wg per 64-col s-chunk; O^T = X^T @ E^T accumulated in regs
      f32x4 aO[4][3] = {};
#pragma unroll
      for (int sc = 0; sc < 4; ++sc) {
        f32x4 aX[3] = {};
        for (int kc = 0; kc < 8; ++kc) {
          int k = kc * 32 + lk;
          bfrag bb = *(const bfrag*)(wstep + (size_t)(sc * 64 + w * 16 + lrow) * SS + k);
#pragma unroll
          for (int mt = 0; mt < 3; ++mt) {
            bfrag af = *(const bfrag*)(seA_b + (mt * 16 + lrow) * 528 + k * 2);
            aX[mt] = MFMA(af, bb, aX[mt]);
          }
        }
        __syncthreads();  // prior chunk's XT readers done (sc=0: Eb barrier above)
#pragma unroll
        for (int mt = 0; mt < 3; ++mt) {
          unsigned int lo = (unsigned int)f2b(aX[mt][0]) | ((unsigned int)f2b(aX[mt][1]) << 16);
          unsigned int hi = (unsigned int)f2b(aX[mt][2]) | ((unsigned int)f2b(aX[mt][3]) << 16);
          *(uint2*)(XT_b + (w * 16 + lrow) * 144 + (mt * 16 + rsub) * 2) = make_uint2(lo, hi);
        }
        *(uint2*)(XT_b + (w * 16 + lrow) * 144 + (48 + rsub) * 2) = make_uint2(0, 0);
        __syncthreads();
#pragma unroll
        for (int kc = 0; kc < 2; ++kc) {
          int k = kc * 32 + lk;
          bfrag xa = *(const bfrag*)(XT_b + (w * 16 + lrow) * 144 + k * 2);
#pragma unroll
          for (int nt = 0; nt < 3; ++nt) {
            bfrag eb = *(const bfrag*)(Eb + (nt * 16 + lrow) * 144 + k * 2);
            aO[sc][nt] = MFMA(xa, eb, aO[sc][nt]);
          }
        }
      }
      // seA = relu(O + bg) — O reads done per-thread; no other thread reads seA now
#pragma unroll
      for (int sc = 0; sc < 4; ++sc) {
        float bga[4];
#pragma unroll
        for (int r = 0; r < 4; ++r) bga[r] = bg3[step * SS + sc * 64 + w * 16 + rsub + r];
#pragma unroll
        for (int nt = 0; nt < 3; ++nt) {
          int n = nt * 16 + lrow;
          if (n < NN) {
#pragma unroll
            for (int r = 0; r < 4; ++r) {
              int s = sc * 64 + w * 16 + rsub + r;
              float v = aO[sc][nt][r] + bga[r];
              v = v > 0.f ? v : 0.f;
              *(unsigned short*)(seA_b + n * 528 + s * 2) = f2b(v);
            }
          }
        }
      }
      __syncthreads();
    }
  }

  // ================ eval: sigmoid(seA[0] @ W_eval + b_eval)
  if (tid < 64) {
    const char* seA_b = smem + OFF_SEA;
    uint2 u = *(const uint2*)(seA_b + tid * 8);
    float4 w4 = *(const float4*)&W_eval[tid * 4];
    float s = b2f(u.x & 0xffff) * w4.x + b2f(u.x >> 16) * w4.y +
              b2f(u.y & 0xffff) * w4.z + b2f(u.y >> 16) * w4.w;
    s = warp_reduce_sum64(s);
    if (tid == 0) out[b * 64 + c] = 1.0f / (1.0f + expf(-(s + b_eval[0])));
  }
}

extern "C" void kernel_launch(void* const* d_in, const int* in_sizes, int n_in,
                              void* d_out, int out_size, void* d_ws, size_t ws_size,
                              hipStream_t stream) {
  (void)in_sizes; (void)n_in; (void)out_size; (void)ws_size;
  const float* img = (const float*)d_in[0];
  const float* cap = (const float*)d_in[1];
  const float* vG_Wl = (const float*)d_in[3];
  const float* vG_bl = (const float*)d_in[4];
  const float* vG_Wg = (const float*)d_in[5];
  const float* vG_bg = (const float*)d_in[6];
  const float* vG_Wc = (const float*)d_in[7];
  const float* vG_bc = (const float*)d_in[8];
  const float* tG_Wl = (const float*)d_in[9];
  const float* tG_bl = (const float*)d_in[10];
  const float* tG_Wg = (const float*)d_in[11];
  const float* tG_bg = (const float*)d_in[12];
  const float* tG_Wc = (const float*)d_in[13];
  const float* tG_bc = (const float*)d_in[14];
  const float* W_loc = (const float*)d_in[15];
  const float* b_loc = (const float*)d_in[16];
  const float* W_glo = (const float*)d_in[17];
  const float* b_glo = (const float*)d_in[18];
  const float* W_eval = (const float*)d_in[19];
  const float* b_eval = (const float*)d_in[20];
  const float* sgr_Wq = (const float*)d_in[21];
  const float* sgr_bq = (const float*)d_in[22];
  const float* sgr_Wk = (const float*)d_in[23];
  const float* sgr_Wg = (const float*)d_in[25];
  const float* sgr_bg = (const float*)d_in[26];
  float* out = (float*)d_out;
  float* ws = (float*)d_ws;
  float* img_avg = ws;
  float* cap_avg = ws + 65536;
  float* h_img = ws + 131072;
  float* h_cap = ws + 196608;
  float* part_img = ws + 262144;
  float* part_cap = ws + 462848;
  float* img_glob = ws + 495616;
  float* cap_glob = ws + 561152;
  float* simglo = ws + 626688;
  float* wkbqv = ws + 1675264;
  // bf16 region (u16 units) starts at float offset 1676032 (16B aligned)
  unsigned short* ub = (unsigned short*)(ws + 1676032);
  unsigned short* mt_bf = ub;                   // 196608
  unsigned short* wgT_bf = ub + 196608;         // 196608 -> 393216
  unsigned short* wlocT_bf = ub + 393216;       // 262144 -> 655360
  unsigned short* cap_bf = ub + 655360;         // 2097152 -> 2752512
  unsigned short* gram_bf = ub + 2752512;       // 2981888 -> 5734400
  unsigned short* imgT_bf = ub + 5734400;       // 14680064 -> 20414464
  unsigned short* img_bf = ub + 20414464;       // 12845056 -> 33259520
  unsigned short* wlT_v = ub + 33259520;        // 1048576 -> 34308096
  unsigned short* wlT_t = ub + 34308096;        // 1048576 -> 35356672

  k_avg<<<128, 256, 0, stream>>>(img, cap, img_avg, cap_avg);
  k_hvec<<<256, 256, 0, stream>>>(img_avg, vG_Wg, vG_bg, vG_Wc, h_img);
  k_hvec<<<256, 256, 0, stream>>>(cap_avg, tG_Wg, tG_bg, tG_Wc, h_cap);
  k_imgbf<<<12544, 256, 0, stream>>>(img, img_bf);
  k_castb<<<2048, 256, 0, stream>>>(cap, cap_bf, 524288);
  k_tcast<<<dim3(32, 32, 1), 256, 0, stream>>>(vG_Wl, wlT_v, 1024, 1024, 0, 0);
  k_tcast<<<dim3(32, 32, 1), 256, 0, stream>>>(tG_Wl, wlT_t, 1024, 1024, 0, 0);
  k_logits_mfma<<<dim3(196, 16), 256, 0, stream>>>(img_bf, TT, wlT_v, vG_bl, h_img, part_img);
  k_logits_mfma<<<dim3(32, 16), 256, 0, stream>>>(cap_bf, CL, wlT_t, tG_bl, h_cap, part_cap);
  k_finish_global<<<64, 256, 0, stream>>>(part_img, vG_bc, img + DD, (long)NTOK * DD, TT,
                                          img_glob);
  k_finish_global<<<64, 256, 0, stream>>>(part_cap, tG_bc, cap, (long)CL * DD, CL, cap_glob);
  k_simglo<<<256, 256, 0, stream>>>(img_glob, cap_glob, W_glo, b_glo, simglo);
  k_mmatb<<<48, 256, 0, stream>>>(sgr_Wk, sgr_Wq, mt_bf);  // MT = Wk@Wq^T = (Wq@Wk^T)^T
  k_wkbq<<<3, 256, 0, stream>>>(sgr_Wk, sgr_bq, wkbqv);
  k_gram_mfma<<<dim3(64, 4, 4), 256, 0, stream>>>(img_bf, gram_bf);
  k_tcast<<<dim3(8, 8, 3), 256, 0, stream>>>(sgr_Wg, wgT_bf, 256, 256, 65536, 65536);
  k_tcast<<<dim3(8, 32, 1), 256, 0, stream>>>(W_loc, wlocT_bf, 1024, 256, 0, 0);
  k_imgt<<<dim3(32, 7, 64), 256, 0, stream>>>(img, imgT_bf);
  hipFuncSetAttribute((const void*)k_pair, hipFuncAttributeMaxDynamicSharedMemorySize,
                      SMEM_BYTES);
  k_pair<<<4096, 256, SMEM_BYTES, stream>>>(b_loc, simglo, wkbqv, sgr_bg, W_eval, b_eval,
                                            cap_bf, img_bf, imgT_bf, gram_bf, wlocT_bf,
                                            mt_bf, wgT_bf, out);
}

// Round 7
// 1952.578 us; speedup vs baseline: 11.8482x; 1.0686x over previous
//
#include <hip/hip_runtime.h>
#include <hip/hip_bf16.h>
#include <math.h>

#define NI 64
#define NC 64
#define NTOK 197
#define TT 196
#define CL 32
#define DD 1024
#define SS 256
#define NN 33
#define EPSN 1e-12f
#define SMOOTHF 9.0f
#define TP 224   // padded token dim for MFMA K

typedef __attribute__((ext_vector_type(8))) short bfrag;
typedef __attribute__((ext_vector_type(4))) float f32x4;
#define MFMA(a, b, c) __builtin_amdgcn_mfma_f32_16x16x32_bf16((a), (b), (c), 0, 0, 0)

// LDS layout (byte offsets) — phase A/W region (dead before SGR)
#define OFF_ATTNT  0        // [32][232] u16 = 14848
#define OFF_WTILE  14848    // [32][136] u16 = 8704 -> 23552
#define OFF_WMAX   23552    // [4][32] f32 = 512 -> 24064
#define OFF_NRMS   24064    // [32] f32 -> 24192
// SGR overlays (start at 0; attnT/wtile/wmax/nrms dead)
#define OFF_SEA    0        // [48][264] u16 = 25344
#define OFF_R1     25344    // Gc[48][144]B / Ef[33][34]f32 / XT[64][144]B = 9216 -> 34560
#define OFF_EB     34560    // [48][72] u16 = 6912 -> 41472
#define OFF_WKQ    41472    // [256] f32 -> 42496
#define OFF_VBUF   42496    // [36] f32 -> 42640
// persistent small buffers (outside seA range!)
#define OFF_QN     42640    // [128] f32 -> 43152
#define OFF_RNQ    43152    // [32] f32 -> 43280
#define SMEM_BYTES 43280

__device__ __forceinline__ float warp_reduce_sum64(float v) {
#pragma unroll
  for (int m = 32; m > 0; m >>= 1) v += __shfl_xor(v, m, 64);
  return v;
}
__device__ __forceinline__ unsigned short f2b(float f) {
  __hip_bfloat16 h = __float2bfloat16(f);
  return *reinterpret_cast<unsigned short*>(&h);
}
__device__ __forceinline__ float b2f(unsigned short u) {
  union { unsigned int i; float f; } v;
  v.i = ((unsigned int)u) << 16;
  return v.f;
}

// ---------------------------------------------------------------- K1: means
__global__ void k_avg(const float* __restrict__ img, const float* __restrict__ cap,
                      float* __restrict__ img_avg, float* __restrict__ cap_avg) {
  int bid = blockIdx.x;
  int tid = threadIdx.x;
  if (bid < NI) {
    int b = bid;
    for (int d = tid; d < DD; d += 256) {
      float acc = 0.f;
      const float* p = img + ((size_t)b * NTOK + 1) * DD + d;
      for (int t = 0; t < TT; ++t) acc += p[(size_t)t * DD];
      img_avg[b * DD + d] = acc * (1.0f / TT);
    }
  } else {
    int c = bid - NI;
    for (int d = tid; d < DD; d += 256) {
      float acc = 0.f;
      const float* p = cap + (size_t)c * CL * DD + d;
      for (int t = 0; t < CL; ++t) acc += p[(size_t)t * DD];
      cap_avg[c * DD + d] = acc * (1.0f / CL);
    }
  }
}

// ------------------------------------------------- K2: h = tanh(avg@Wg+bg)*Wc
__global__ void k_hvec(const float* __restrict__ avg, const float* __restrict__ Wg,
                       const float* __restrict__ bg, const float* __restrict__ Wc,
                       float* __restrict__ h) {
  __shared__ float av[DD];
  int b = blockIdx.x >> 2;
  int dc = blockIdx.x & 3;
  int tid = threadIdx.x;
  for (int i = tid; i < DD; i += 256) av[i] = avg[b * DD + i];
  __syncthreads();
  int d = dc * 256 + tid;
  float acc = 0.f;
  for (int k = 0; k < DD; k += 4) {
    float4 a4 = *(const float4*)&av[k];
    acc += a4.x * Wg[(size_t)(k + 0) * DD + d];
    acc += a4.y * Wg[(size_t)(k + 1) * DD + d];
    acc += a4.z * Wg[(size_t)(k + 2) * DD + d];
    acc += a4.w * Wg[(size_t)(k + 3) * DD + d];
  }
  h[b * DD + d] = tanhf(acc + bg[d]) * Wc[d];
}

// ---------------- K3 (MFMA): partial logits
__global__ void k_logits_mfma(const unsigned short* __restrict__ Abf, int rowsPerBatch,
                              const unsigned short* __restrict__ WT,
                              const float* __restrict__ bl, const float* __restrict__ h,
                              float* __restrict__ partial) {
  int tid = threadIdx.x;
  int lane = tid & 63, w = tid >> 6;
  int lrow = lane & 15, lk = (lane >> 4) * 8, rsub = (lane >> 4) * 4;
  int rb = blockIdx.x * 64, c0 = blockIdx.y * 64;
  const unsigned short* ap = Abf + (size_t)(rb + w * 16 + lrow) * DD;
  f32x4 acc[4] = {};
  for (int k0 = 0; k0 < DD; k0 += 32) {
    bfrag a = *(const bfrag*)(ap + k0 + lk);
#pragma unroll
    for (int i = 0; i < 4; ++i) {
      bfrag bb = *(const bfrag*)(WT + (size_t)(c0 + i * 16 + lrow) * DD + k0 + lk);
      acc[i] = MFMA(a, bb, acc[i]);
    }
  }
#pragma unroll
  for (int r = 0; r < 4; ++r) {
    int row = rb + w * 16 + rsub + r;
    int bb2 = row / rowsPerBatch;
    float s = 0.f;
#pragma unroll
    for (int i = 0; i < 4; ++i) {
      int col = c0 + i * 16 + lrow;
      s += tanhf(acc[i][r] + bl[col]) * h[bb2 * DD + col];
    }
    s += __shfl_xor(s, 1, 64);
    s += __shfl_xor(s, 2, 64);
    s += __shfl_xor(s, 4, 64);
    s += __shfl_xor(s, 8, 64);
    if (lrow == 0) partial[(size_t)row * 16 + blockIdx.y] = s;
  }
}

// -------- K4: finish global attention pooling
__global__ void k_finish_global(const float* __restrict__ partial, const float* __restrict__ bc,
                                const float* __restrict__ Xbase, long batchStride, int R,
                                float* __restrict__ outG) {
  __shared__ float w[200];
  __shared__ float red[8];
  int b = blockIdx.x, tid = threadIdx.x;
  for (int t = tid; t < R; t += 256) {
    const float* pp = &partial[((size_t)b * R + t) * 16];
    float s = bc[0];
#pragma unroll
    for (int u = 0; u < 16; ++u) s += pp[u];
    w[t] = s;
  }
  __syncthreads();
  float m = -1e30f;
  for (int t = tid; t < R; t += 256) m = fmaxf(m, w[t]);
#pragma unroll
  for (int mm = 32; mm; mm >>= 1) m = fmaxf(m, __shfl_xor(m, mm, 64));
  if ((tid & 63) == 0) red[tid >> 6] = m;
  __syncthreads();
  m = fmaxf(fmaxf(red[0], red[1]), fmaxf(red[2], red[3]));
  __syncthreads();
  for (int t = tid; t < R; t += 256) w[t] = expf(w[t] - m);
  __syncthreads();
  const float* xb = Xbase + (size_t)b * batchStride;
  float acc[4];
  float ss = 0.f;
#pragma unroll
  for (int c4 = 0; c4 < 4; ++c4) {
    int d = tid + c4 * 256;
    float a = 0.f;
    for (int t = 0; t < R; ++t) a += w[t] * xb[(size_t)t * DD + d];
    acc[c4] = a;
    ss += a * a;
  }
  ss = warp_reduce_sum64(ss);
  if ((tid & 63) == 0) red[tid >> 6] = ss;
  __syncthreads();
  ss = red[0] + red[1] + red[2] + red[3];
  float rn = 1.0f / fmaxf(sqrtf(ss), EPSN);
#pragma unroll
  for (int c4 = 0; c4 < 4; ++c4) outG[(size_t)b * DD + tid + c4 * 256] = acc[c4] * rn;
}

// -------- K5: sim_glo
__global__ void k_simglo(const float* __restrict__ ig, const float* __restrict__ cg,
                         const float* __restrict__ W, const float* __restrict__ bgl,
                         float* __restrict__ simglo) {
  __shared__ float a_lds[32][20];
  __shared__ float b_lds[32][260];
  int tid = threadIdx.x;
  int p0 = blockIdx.x * 16;
  int ty = tid >> 6, tx = tid & 63;
  int s_rr = tid >> 3, s_kq = tid & 7;
  float acc[4][4] = {};
  for (int k0 = 0; k0 < DD; k0 += 32) {
    float d2[4] = {};
    if (tid < 128) {
      int p = p0 + s_rr;
      int b = p >> 6, c = p & 63;
      float4 giv = *(const float4*)&ig[b * DD + k0 + s_kq * 4];
      float4 cgv = *(const float4*)&cg[c * DD + k0 + s_kq * 4];
      float dx = giv.x - cgv.x, dy = giv.y - cgv.y, dz = giv.z - cgv.z, dw = giv.w - cgv.w;
      d2[0] = dx * dx; d2[1] = dy * dy; d2[2] = dz * dz; d2[3] = dw * dw;
    }
    float4 wv[8];
#pragma unroll
    for (int u = 0; u < 8; ++u)
      wv[u] = *(const float4*)&W[(size_t)(k0 + s_rr) * SS + s_kq * 32 + u * 4];
    __syncthreads();
    if (tid < 128) {
#pragma unroll
      for (int u = 0; u < 4; ++u) a_lds[s_kq * 4 + u][s_rr] = d2[u];
    }
#pragma unroll
    for (int u = 0; u < 8; ++u)
      *(float4*)&b_lds[s_rr][s_kq * 32 + u * 4] = wv[u];
    __syncthreads();
#pragma unroll
    for (int kk = 0; kk < 32; ++kk) {
      float4 a4 = *(const float4*)&a_lds[kk][ty * 4];
      float4 b4 = *(const float4*)&b_lds[kk][tx * 4];
      float av[4] = {a4.x, a4.y, a4.z, a4.w};
      float bv[4] = {b4.x, b4.y, b4.z, b4.w};
#pragma unroll
      for (int i = 0; i < 4; ++i)
#pragma unroll
        for (int j = 0; j < 4; ++j) acc[i][j] += av[i] * bv[j];
    }
  }
#pragma unroll
  for (int i = 0; i < 4; ++i) {
    float v[4];
    float ssq = 0.f;
#pragma unroll
    for (int j = 0; j < 4; ++j) {
      v[j] = acc[i][j] + bgl[tx * 4 + j];
      ssq += v[j] * v[j];
    }
    ssq = warp_reduce_sum64(ssq);
    float rn = 1.0f / fmaxf(sqrtf(ssq), EPSN);
    int p = p0 + ty * 4 + i;
    *(float4*)&simglo[(size_t)p * SS + tx * 4] =
        make_float4(v[0] * rn, v[1] * rn, v[2] * rn, v[3] * rn);
  }
}

// -------- K6: MT_bf16[t] = A_t @ B_t^T (256x256), bf16 out.
__global__ void k_mmatb(const float* __restrict__ Wa, const float* __restrict__ Wb,
                        unsigned short* __restrict__ M) {
  __shared__ float a_lds[32][68];
  __shared__ float b_lds[32][68];
  int tid = threadIdx.x;
  int t = blockIdx.x >> 4;
  int dt = (blockIdx.x >> 2) & 3, et = blockIdx.x & 3;
  int d0 = dt * 64, e0 = et * 64;
  const float* wq = Wa + (size_t)t * SS * SS;
  const float* wk = Wb + (size_t)t * SS * SS;
  int ty = tid >> 4, tx = tid & 15;
  int s_rr = tid >> 2, s_kq = tid & 3;
  float acc[4][4] = {};
  for (int j0 = 0; j0 < SS; j0 += 32) {
    float4 q0 = *(const float4*)&wq[(size_t)(d0 + s_rr) * SS + j0 + s_kq * 8];
    float4 q1 = *(const float4*)&wq[(size_t)(d0 + s_rr) * SS + j0 + s_kq * 8 + 4];
    float4 k0v = *(const float4*)&wk[(size_t)(e0 + s_rr) * SS + j0 + s_kq * 8];
    float4 k1v = *(const float4*)&wk[(size_t)(e0 + s_rr) * SS + j0 + s_kq * 8 + 4];
    __syncthreads();
    float qa[8] = {q0.x, q0.y, q0.z, q0.w, q1.x, q1.y, q1.z, q1.w};
    float ka[8] = {k0v.x, k0v.y, k0v.z, k0v.w, k1v.x, k1v.y, k1v.z, k1v.w};
#pragma unroll
    for (int u = 0; u < 8; ++u) {
      a_lds[s_kq * 8 + u][s_rr] = qa[u];
      b_lds[s_kq * 8 + u][s_rr] = ka[u];
    }
    __syncthreads();
#pragma unroll
    for (int kk = 0; kk < 32; ++kk) {
      float4 a4 = *(const float4*)&a_lds[kk][ty * 4];
      float4 b4 = *(const float4*)&b_lds[kk][tx * 4];
      float av[4] = {a4.x, a4.y, a4.z, a4.w};
      float bv[4] = {b4.x, b4.y, b4.z, b4.w};
#pragma unroll
      for (int i = 0; i < 4; ++i)
#pragma unroll
        for (int j = 0; j < 4; ++j) acc[i][j] += av[i] * bv[j];
    }
  }
#pragma unroll
  for (int i = 0; i < 4; ++i) {
    unsigned int lo = (unsigned int)f2b(acc[i][0]) | ((unsigned int)f2b(acc[i][1]) << 16);
    unsigned int hi = (unsigned int)f2b(acc[i][2]) | ((unsigned int)f2b(acc[i][3]) << 16);
    uint2 o = make_uint2(lo, hi);
    *(uint2*)(M + (size_t)t * SS * SS + (size_t)(d0 + ty * 4 + i) * SS + e0 + tx * 4) = o;
  }
}

// -------- K6b: wkbq[t] = Wk_t @ bq_t
__global__ void k_wkbq(const float* __restrict__ Wk, const float* __restrict__ bq,
                       float* __restrict__ out) {
  __shared__ float bv[SS];
  int t = blockIdx.x, tid = threadIdx.x;
  const float* wk = Wk + (size_t)t * SS * SS;
  bv[tid] = bq[t * SS + tid];
  __syncthreads();
  float acc = 0.f;
  for (int j = 0; j < SS; j += 4) {
    float4 wv = *(const float4*)&wk[(size_t)tid * SS + j];
    float4 b4 = *(const float4*)&bv[j];
    acc += wv.x * b4.x + wv.y * b4.y + wv.z * b4.z + wv.w * b4.w;
  }
  out[t * SS + tid] = acc;
}

// -------- fused img prep: row-major bf16 + transposed padded bf16 (one img read)
__global__ void k_imgprep(const float* __restrict__ img, unsigned short* __restrict__ row_bf,
                          unsigned short* __restrict__ tr_bf) {
  __shared__ float t[32][33];
  int b = blockIdx.z;
  int t0 = blockIdx.y * 32, d0 = blockIdx.x * 32;
  int tx = threadIdx.x & 31, ty = threadIdx.x >> 5;
#pragma unroll
  for (int u = 0; u < 4; ++u) {
    int tt = t0 + ty + u * 8;
    float v = (tt < TT) ? img[((size_t)b * NTOK + 1 + tt) * DD + d0 + tx] : 0.f;
    t[ty + u * 8][tx] = v;
    if (tt < TT) row_bf[((size_t)b * TT + tt) * DD + d0 + tx] = f2b(v);
  }
  __syncthreads();
#pragma unroll
  for (int u = 0; u < 4; ++u)
    tr_bf[((size_t)b * DD + d0 + ty + u * 8) * TP + t0 + tx] = f2b(t[tx][ty + u * 8]);
}

// -------- K6c (MFMA): gram_bf16[b] = imgTok_b @ imgTok_b^T in [208][224] zero-padded
__global__ void k_gram_mfma(const unsigned short* __restrict__ img_bf,
                            unsigned short* __restrict__ gram) {
  int tid = threadIdx.x;
  int lane = tid & 63, w = tid >> 6;
  int lrow = lane & 15, lk = (lane >> 4) * 8, rsub = (lane >> 4) * 4;
  int bimg = blockIdx.x;
  int rb = blockIdx.y * 64, cb = blockIdx.z * 64;
  const unsigned short* X = img_bf + (size_t)bimg * TT * DD;
  int ra = rb + w * 16 + lrow;
  if (ra > TT - 1) ra = TT - 1;
  f32x4 acc[4] = {};
  for (int k0 = 0; k0 < DD; k0 += 32) {
    bfrag a = *(const bfrag*)(X + (size_t)ra * DD + k0 + lk);
#pragma unroll
    for (int i = 0; i < 4; ++i) {
      int cc = cb + i * 16 + lrow;
      if (cc > TT - 1) cc = TT - 1;
      bfrag bb = *(const bfrag*)(X + (size_t)cc * DD + k0 + lk);
      acc[i] = MFMA(a, bb, acc[i]);
    }
  }
  unsigned short* Gp = gram + (size_t)bimg * 208 * TP;
#pragma unroll
  for (int i = 0; i < 4; ++i) {
    int cc = cb + i * 16 + lrow;
#pragma unroll
    for (int r = 0; r < 4; ++r) {
      int rr = rb + w * 16 + rsub + r;
      if (rr < 208 && cc < TP)
        Gp[(size_t)rr * TP + cc] = (rr < TT && cc < TT) ? f2b(acc[i][r]) : 0;
    }
  }
}

// -------- cast f32 -> bf16 (same layout)
__global__ void k_castb(const float* __restrict__ s, unsigned short* __restrict__ d, int n4) {
  int i = blockIdx.x * 256 + threadIdx.x;
  if (i < n4) {
    float4 v = *(const float4*)(s + (size_t)i * 4);
    uint2 o;
    o.x = (unsigned int)f2b(v.x) | ((unsigned int)f2b(v.y) << 16);
    o.y = (unsigned int)f2b(v.z) | ((unsigned int)f2b(v.w) << 16);
    *(uint2*)(d + (size_t)i * 4) = o;
  }
}

// -------- transpose-cast: src[R][C] f32 -> dst[C][R] bf16 (batched via z)
__global__ void k_tcast(const float* __restrict__ src, unsigned short* __restrict__ dst,
                        int R, int C, long sB, long dB) {
  __shared__ float t[32][33];
  const float* s = src + (size_t)blockIdx.z * sB;
  unsigned short* d = dst + (size_t)blockIdx.z * dB;
  int r0 = blockIdx.y * 32, c0 = blockIdx.x * 32;
  int tx = threadIdx.x & 31, ty = threadIdx.x >> 5;
#pragma unroll
  for (int u = 0; u < 4; ++u)
    t[ty + u * 8][tx] = s[(size_t)(r0 + ty + u * 8) * C + c0 + tx];
  __syncthreads();
#pragma unroll
  for (int u = 0; u < 4; ++u)
    d[(size_t)(c0 + ty + u * 8) * R + r0 + tx] = f2b(t[tx][ty + u * 8]);
}

// -------- K7: per-(img,cap) pair mega kernel (v7: in-reg softmax, 43KB LDS, reg diet)
__global__ __launch_bounds__(256, 3) void k_pair(
    const float* __restrict__ b_loc, const float* __restrict__ simglo,
    const float* __restrict__ wkbq, const float* __restrict__ bg3,
    const float* __restrict__ W_eval, const float* __restrict__ b_eval,
    const unsigned short* __restrict__ cap_bf, const unsigned short* __restrict__ img_bf,
    const unsigned short* __restrict__ imgT_bf, const unsigned short* __restrict__ gram_bf,
    const unsigned short* __restrict__ wlocT_bf, const unsigned short* __restrict__ mt_bf,
    const unsigned short* __restrict__ wgT_bf, float* __restrict__ out) {
  extern __shared__ char smem[];

  int tid = threadIdx.x;
  int lane = tid & 63, w = tid >> 6;
  int lrow = lane & 15;        // MFMA row/col select
  int lk = (lane >> 4) * 8;    // MFMA k-offset
  int rsub = (lane >> 4) * 4;  // D-frag row base
  int p = blockIdx.x;
  int b = p >> 6, c = p & 63;
  const unsigned short* imgR = img_bf + (size_t)b * TT * DD;
  const unsigned short* capB = cap_bf + (size_t)c * CL * DD;
  char* attnT_b = smem + OFF_ATTNT;

  // ================ Phase A: S = leaky(imgTok.cap) MFMA; epilogue in registers
  {
    f32x4 acc[4][2] = {};
    for (int k0 = 0; k0 < DD; k0 += 32) {
      bfrag bq0 = *(const bfrag*)(capB + (size_t)lrow * DD + k0 + lk);
      bfrag bq1 = *(const bfrag*)(capB + (size_t)(16 + lrow) * DD + k0 + lk);
#pragma unroll
      for (int i = 0; i < 4; ++i) {
        int tt = w + 4 * i;
        if (tt < 13) {
          int t = tt * 16 + lrow;
          bfrag a = {0, 0, 0, 0, 0, 0, 0, 0};
          if (t < TT) a = *(const bfrag*)(imgR + (size_t)t * DD + k0 + lk);
          acc[i][0] = MFMA(a, bq0, acc[i][0]);
          acc[i][1] = MFMA(a, bq1, acc[i][1]);
        }
      }
    }
    // leaky + l2norm over q (16-lane butterfly within g-group) + running max over t
    float mx0 = -1e30f, mx1 = -1e30f;
#pragma unroll
    for (int i = 0; i < 4; ++i) {
      int tt = w + 4 * i;
      if (tt < 13) {
#pragma unroll
        for (int r = 0; r < 4; ++r) {
          int t = tt * 16 + rsub + r;
          float v0 = acc[i][0][r];
          v0 = v0 < 0.f ? 0.1f * v0 : v0;
          float v1 = acc[i][1][r];
          v1 = v1 < 0.f ? 0.1f * v1 : v1;
          float s2 = v0 * v0 + v1 * v1;
          s2 += __shfl_xor(s2, 1, 64);
          s2 += __shfl_xor(s2, 2, 64);
          s2 += __shfl_xor(s2, 4, 64);
          s2 += __shfl_xor(s2, 8, 64);
          float rn = 1.0f / fmaxf(sqrtf(s2), EPSN);
          v0 *= rn;
          v1 *= rn;
          acc[i][0][r] = v0;
          acc[i][1][r] = v1;
          if (t < TT) {
            mx0 = fmaxf(mx0, v0);
            mx1 = fmaxf(mx1, v1);
          }
        }
      }
    }
    mx0 = fmaxf(mx0, __shfl_xor(mx0, 16, 64));
    mx0 = fmaxf(mx0, __shfl_xor(mx0, 32, 64));
    mx1 = fmaxf(mx1, __shfl_xor(mx1, 16, 64));
    mx1 = fmaxf(mx1, __shfl_xor(mx1, 32, 64));
    float* wmax = (float*)(smem + OFF_WMAX);
    if ((lane >> 4) == 0) {
      wmax[w * 32 + lrow] = mx0;
      wmax[w * 32 + 16 + lrow] = mx1;
    }
    __syncthreads();
    mx0 = fmaxf(fmaxf(wmax[lrow], wmax[32 + lrow]), fmaxf(wmax[64 + lrow], wmax[96 + lrow]));
    mx1 = fmaxf(fmaxf(wmax[16 + lrow], wmax[48 + lrow]),
                fmaxf(wmax[80 + lrow], wmax[112 + lrow]));
    // exp (denominator dropped; exact since ctx l2-normalized) -> attnT bf16 [32][232]
#pragma unroll
    for (int i = 0; i < 4; ++i) {
      int tt = w + 4 * i;
#pragma unroll
      for (int r = 0; r < 4; ++r) {
        int t = tt * 16 + rsub + r;
        if (t < TP) {
          unsigned short e0 = 0, e1 = 0;
          if (t < TT) {
            e0 = f2b(expf(SMOOTHF * (acc[i][0][r] - mx0)));
            e1 = f2b(expf(SMOOTHF * (acc[i][1][r] - mx1)));
          }
          *(unsigned short*)(attnT_b + lrow * 464 + t * 2) = e0;
          *(unsigned short*)(attnT_b + (16 + lrow) * 464 + t * 2) = e1;
        }
      }
    }
  }
  __syncthreads();

  // ================ norm via Gram (MFMA): Y = G@E, norm2[q] = sum_t w[t][q]*Y[t][q]
  {
    float* qn = (float*)(smem + OFF_QN);
    float* nrmS = (float*)(smem + OFF_NRMS);
    const unsigned short* gb = gram_bf + (size_t)b * 208 * TP;
    float part0 = 0.f, part1 = 0.f;
#pragma unroll
    for (int i = 0; i < 4; ++i) {
      int tt = w + 4 * i;
      if (tt < 13) {
        f32x4 y0 = {0.f, 0.f, 0.f, 0.f}, y1 = {0.f, 0.f, 0.f, 0.f};
        for (int t0 = 0; t0 < TP; t0 += 32) {
          bfrag a = *(const bfrag*)(gb + (size_t)(tt * 16 + lrow) * TP + t0 + lk);
          bfrag b0 = *(const bfrag*)(attnT_b + lrow * 464 + (t0 + lk) * 2);
          bfrag b1 = *(const bfrag*)(attnT_b + (16 + lrow) * 464 + (t0 + lk) * 2);
          y0 = MFMA(a, b0, y0);
          y1 = MFMA(a, b1, y1);
        }
#pragma unroll
        for (int r = 0; r < 4; ++r) {
          int t = tt * 16 + rsub + r;
          if (t < TT) {
            part0 += y0[r] * b2f(*(const unsigned short*)(attnT_b + lrow * 464 + t * 2));
            part1 += y1[r] * b2f(*(const unsigned short*)(attnT_b + (16 + lrow) * 464 + t * 2));
          }
        }
      }
    }
    part0 += __shfl_xor(part0, 16, 64);
    part0 += __shfl_xor(part0, 32, 64);
    part1 += __shfl_xor(part1, 16, 64);
    part1 += __shfl_xor(part1, 32, 64);
    if ((lane >> 4) == 0) {
      qn[w * 32 + lrow] = part0;
      qn[w * 32 + 16 + lrow] = part1;
    }
    __syncthreads();
    if (tid < 32)
      nrmS[tid] = 1.0f / fmaxf(sqrtf(qn[tid] + qn[32 + tid] + qn[64 + tid] + qn[96 + tid]), EPSN);
    __syncthreads();
  }

  // ================ Phase W: ctx (MFMA) -> diff^2 -> @W_loc (MFMA)
  f32x4 accW[2][4] = {};
  {
    char* wtile_b = smem + OFF_WTILE;
    float* nrmS = (float*)(smem + OFF_NRMS);
    float nrm0 = nrmS[lrow], nrm1 = nrmS[16 + lrow];
    for (int d0 = 0; d0 < DD; d0 += 128) {
      f32x4 c2[2][2] = {};
      for (int t0 = 0; t0 < TP; t0 += 32) {
        bfrag b0 = *(const bfrag*)(attnT_b + lrow * 464 + (t0 + lk) * 2);
        bfrag b1 = *(const bfrag*)(attnT_b + (16 + lrow) * 464 + (t0 + lk) * 2);
#pragma unroll
        for (int i = 0; i < 2; ++i) {
          int dt = w + 4 * i;
          bfrag a = *(const bfrag*)(imgT_bf + ((size_t)b * DD + d0 + dt * 16 + lrow) * TP + t0 + lk);
          c2[i][0] = MFMA(a, b0, c2[i][0]);
          c2[i][1] = MFMA(a, b1, c2[i][1]);
        }
      }
      __syncthreads();  // prev W_loc readers of wtile done
#pragma unroll
      for (int i = 0; i < 2; ++i) {
        int dl = (w + 4 * i) * 16 + rsub;
#pragma unroll
        for (int qt = 0; qt < 2; ++qt) {
          int q = qt * 16 + lrow;
          uint2 cu = *(const uint2*)(capB + (size_t)q * DD + d0 + dl);
          float cf0 = b2f(cu.x & 0xffff), cf1 = b2f(cu.x >> 16);
          float cf2 = b2f(cu.y & 0xffff), cf3 = b2f(cu.y >> 16);
          float rn = qt ? nrm1 : nrm0;
          float v0 = c2[i][qt][0] * rn - cf0;
          float v1 = c2[i][qt][1] * rn - cf1;
          float v2 = c2[i][qt][2] * rn - cf2;
          float v3 = c2[i][qt][3] * rn - cf3;
          unsigned int lo = (unsigned int)f2b(v0 * v0) | ((unsigned int)f2b(v1 * v1) << 16);
          unsigned int hi = (unsigned int)f2b(v2 * v2) | ((unsigned int)f2b(v3 * v3) << 16);
          *(uint2*)(wtile_b + q * 272 + dl * 2) = make_uint2(lo, hi);
        }
      }
      __syncthreads();
      for (int kc = 0; kc < 4; ++kc) {
        bfrag a0 = *(const bfrag*)(wtile_b + lrow * 272 + (kc * 32 + lk) * 2);
        bfrag a1 = *(const bfrag*)(wtile_b + (16 + lrow) * 272 + (kc * 32 + lk) * 2);
#pragma unroll
        for (int sti = 0; sti < 4; ++sti) {
          int s = (w * 4 + sti) * 16 + lrow;
          bfrag bb = *(const bfrag*)(wlocT_bf + (size_t)s * DD + d0 + kc * 32 + lk);
          accW[0][sti] = MFMA(a0, bb, accW[0][sti]);
          accW[1][sti] = MFMA(a1, bb, accW[1][sti]);
        }
      }
    }
  }

  // ================ assembly: l2norm(sim_loc)+bias -> seA_bf16 rows 1..32; row 0 simglo
  {
    char* seA_b = smem + OFF_SEA;
    float* qn = (float*)(smem + OFF_QN);
    float* rnq = (float*)(smem + OFF_RNQ);
    __syncthreads();
    for (int i2 = tid; i2 < 6336; i2 += 256) ((unsigned int*)smem)[i2] = 0;  // zero seA
    __syncthreads();
    float blv[4];
#pragma unroll
    for (int sti = 0; sti < 4; ++sti) blv[sti] = b_loc[(w * 4 + sti) * 16 + lrow];
    float ss[2][4];
#pragma unroll
    for (int qt = 0; qt < 2; ++qt)
#pragma unroll
      for (int r = 0; r < 4; ++r) {
        float s2 = 0.f;
#pragma unroll
        for (int sti = 0; sti < 4; ++sti) {
          float v = accW[qt][sti][r] + blv[sti];
          s2 += v * v;
        }
        s2 += __shfl_xor(s2, 1, 64);
        s2 += __shfl_xor(s2, 2, 64);
        s2 += __shfl_xor(s2, 4, 64);
        s2 += __shfl_xor(s2, 8, 64);
        ss[qt][r] = s2;
      }
    if (lrow == 0) {
#pragma unroll
      for (int qt = 0; qt < 2; ++qt)
#pragma unroll
        for (int r = 0; r < 4; ++r)
          qn[w * 32 + qt * 16 + rsub + r] = ss[qt][r];
    }
    __syncthreads();
    if (tid < 32)
      rnq[tid] = 1.0f / fmaxf(sqrtf(qn[tid] + qn[32 + tid] + qn[64 + tid] + qn[96 + tid]), EPSN);
    __syncthreads();
#pragma unroll
    for (int qt = 0; qt < 2; ++qt)
#pragma unroll
      for (int r = 0; r < 4; ++r) {
        int q = qt * 16 + rsub + r;
        float rn = rnq[q];
#pragma unroll
        for (int sti = 0; sti < 4; ++sti) {
          int s = (w * 4 + sti) * 16 + lrow;
          float v = (accW[qt][sti][r] + blv[sti]) * rn;
          *(unsigned short*)(seA_b + (1 + q) * 528 + s * 2) = f2b(v);
        }
      }
    if (tid < 64) {
      float4 g4 = *(const float4*)&simglo[(size_t)p * SS + tid * 4];
      unsigned int lo = (unsigned int)f2b(g4.x) | ((unsigned int)f2b(g4.y) << 16);
      unsigned int hi = (unsigned int)f2b(g4.z) | ((unsigned int)f2b(g4.w) << 16);
      *(uint2*)(seA_b + tid * 8) = make_uint2(lo, hi);
    }
    __syncthreads();
  }

  // ================ SGR x3 (chunked G/Ef/XT in one overlay region; O packed in regs)
  {
    char* seA_b = smem + OFF_SEA;
    char* Gc_b = smem + OFF_R1;   // [48][72] u16 per e-chunk
    char* XT_b = smem + OFF_R1;   // [64][72] u16 per s-chunk
    float* Ef = (float*)(smem + OFF_R1);  // [33][34] f32 (after Gc dead)
    char* Eb = smem + OFF_EB;
    float* wkq = (float*)(smem + OFF_WKQ);
    float* vbuf = (float*)(smem + OFF_VBUF);

    for (int step = 0; step < 3; ++step) {
      const unsigned short* mstep = mt_bf + (size_t)step * SS * SS;
      const unsigned short* wstep = wgT_bf + (size_t)step * SS * SS;
      wkq[tid] = wkbq[step * SS + tid];
      __syncthreads();
      // vbuf[m] = seA[m] . (Wk@bq)
      if (tid < 132) {
        int m = tid >> 2, qq = tid & 3;
        float a = 0.f;
        for (int e = qq * 64; e < qq * 64 + 64; e += 2) {
          unsigned int u = *(const unsigned int*)(seA_b + m * 528 + e * 2);
          a += b2f(u & 0xffff) * wkq[e] + b2f(u >> 16) * wkq[e + 1];
        }
        a += __shfl_xor(a, 1, 64);
        a += __shfl_xor(a, 2, 64);
        if (qq == 0) vbuf[m] = a;
      }
      // E = (seA@M) @ seA^T, e-chunked
      f32x4 aE[3] = {};
      for (int ec = 0; ec < 4; ++ec) {
        f32x4 aGc[3] = {};
        for (int kc = 0; kc < 8; ++kc) {
          int k = kc * 32 + lk;
          bfrag bb = *(const bfrag*)(mstep + (size_t)(ec * 64 + w * 16 + lrow) * SS + k);
#pragma unroll
          for (int mt = 0; mt < 3; ++mt) {
            bfrag af = *(const bfrag*)(seA_b + (mt * 16 + lrow) * 528 + k * 2);
            aGc[mt] = MFMA(af, bb, aGc[mt]);
          }
        }
        __syncthreads();  // prior chunk's Gc readers done
#pragma unroll
        for (int mt = 0; mt < 3; ++mt)
#pragma unroll
          for (int r = 0; r < 4; ++r)
            *(unsigned short*)(Gc_b + (mt * 16 + rsub + r) * 144 + (w * 16 + lrow) * 2) =
                f2b(aGc[mt][r]);
        __syncthreads();
#pragma unroll
        for (int kc = 0; kc < 2; ++kc) {
          int k = kc * 32 + lk;
#pragma unroll
          for (int ti = 0; ti < 3; ++ti) {
            int tile = w + ti * 4;
            if (tile < 9) {
              int mtE = tile / 3, ntE = tile - mtE * 3;
              bfrag ga = *(const bfrag*)(Gc_b + (mtE * 16 + lrow) * 144 + k * 2);
              bfrag sb = *(const bfrag*)(seA_b + (ntE * 16 + lrow) * 528 + (ec * 64 + k) * 2);
              aE[ti] = MFMA(ga, sb, aE[ti]);
            }
          }
        }
      }
      __syncthreads();  // all Gc reads done before Ef overlays it
#pragma unroll
      for (int ti = 0; ti < 3; ++ti) {
        int tile = w + ti * 4;
        if (tile < 9) {
          int mtE = tile / 3, ntE = tile - mtE * 3;
          int n0 = mtE * 16 + rsub, m = ntE * 16 + lrow;
#pragma unroll
          for (int r = 0; r < 4; ++r)
            if (n0 + r < NN && m < NN) Ef[(n0 + r) * 34 + m] = aE[ti][r] + vbuf[m];
        }
      }
      __syncthreads();
      // row softmax of E
      if (tid < NN) {
        float mx = -1e30f;
        for (int mm = 0; mm < NN; ++mm) mx = fmaxf(mx, Ef[tid * 34 + mm]);
        float sum = 0.f;
        for (int mm = 0; mm < NN; ++mm) {
          float e = expf(Ef[tid * 34 + mm] - mx);
          Ef[tid * 34 + mm] = e;
          sum += e;
        }
        float rs = 1.0f / sum;
        for (int mm = 0; mm < NN; ++mm) Ef[tid * 34 + mm] *= rs;
      }
      __syncthreads();
      // E_bf16 build (zero pads to [48][72])
      for (int idx = tid; idx < 48 * 36; idx += 256) {
        int n = idx / 36, mp = (idx - n * 36) * 2;
        unsigned int lo = (n < NN && mp < NN) ? (unsigned int)f2b(Ef[n * 34 + mp]) : 0u;
        unsigned int hi = (n < NN && mp + 1 < NN) ? (unsigned int)f2b(Ef[n * 34 + mp + 1]) : 0u;
        *(unsigned int*)(Eb + n * 144 + mp * 2) = lo | (hi << 16);
      }
      __syncthreads();  // Eb ready; Ef dead -> XT may overlay
      // X = seA @ Wg per 64-col s-chunk; O = X^T@E^T per chunk, bias+relu+pack to regs
      unsigned int oPk[4][3][2];
#pragma unroll
      for (int sc = 0; sc < 4; ++sc) {
        f32x4 aX[3] = {};
        for (int kc = 0; kc < 8; ++kc) {
          int k = kc * 32 + lk;
          bfrag bb = *(const bfrag*)(wstep + (size_t)(sc * 64 + w * 16 + lrow) * SS + k);
#pragma unroll
          for (int mt = 0; mt < 3; ++mt) {
            bfrag af = *(const bfrag*)(seA_b + (mt * 16 + lrow) * 528 + k * 2);
            aX[mt] = MFMA(af, bb, aX[mt]);
          }
        }
        __syncthreads();  // prior chunk's XT readers done (sc=0: Eb barrier above)
#pragma unroll
        for (int mt = 0; mt < 3; ++mt) {
          unsigned int lo = (unsigned int)f2b(aX[mt][0]) | ((unsigned int)f2b(aX[mt][1]) << 16);
          unsigned int hi = (unsigned int)f2b(aX[mt][2]) | ((unsigned int)f2b(aX[mt][3]) << 16);
          *(uint2*)(XT_b + (w * 16 + lrow) * 144 + (mt * 16 + rsub) * 2) = make_uint2(lo, hi);
        }
        *(uint2*)(XT_b + (w * 16 + lrow) * 144 + (48 + rsub) * 2) = make_uint2(0, 0);
        __syncthreads();
        f32x4 aO[3] = {};
#pragma unroll
        for (int kc = 0; kc < 2; ++kc) {
          int k = kc * 32 + lk;
          bfrag xa = *(const bfrag*)(XT_b + (w * 16 + lrow) * 144 + k * 2);
#pragma unroll
          for (int nt = 0; nt < 3; ++nt) {
            bfrag eb = *(const bfrag*)(Eb + (nt * 16 + lrow) * 144 + k * 2);
            aO[nt] = MFMA(xa, eb, aO[nt]);
          }
        }
        float bga[4];
#pragma unroll
        for (int r = 0; r < 4; ++r) bga[r] = bg3[step * SS + sc * 64 + w * 16 + rsub + r];
#pragma unroll
        for (int nt = 0; nt < 3; ++nt) {
          float v0 = fmaxf(aO[nt][0] + bga[0], 0.f);
          float v1 = fmaxf(aO[nt][1] + bga[1], 0.f);
          float v2 = fmaxf(aO[nt][2] + bga[2], 0.f);
          float v3 = fmaxf(aO[nt][3] + bga[3], 0.f);
          oPk[sc][nt][0] = (unsigned int)f2b(v0) | ((unsigned int)f2b(v1) << 16);
          oPk[sc][nt][1] = (unsigned int)f2b(v2) | ((unsigned int)f2b(v3) << 16);
        }
      }
      // seA = relu(O + bg): all sc chunks' X reads of seA completed (barriers above)
#pragma unroll
      for (int sc = 0; sc < 4; ++sc)
#pragma unroll
        for (int nt = 0; nt < 3; ++nt) {
          int n = nt * 16 + lrow;
          if (n < NN)
            *(uint2*)(seA_b + n * 528 + (sc * 64 + w * 16 + rsub) * 2) =
                make_uint2(oPk[sc][nt][0], oPk[sc][nt][1]);
        }
      __syncthreads();
    }
  }

  // ================ eval: sigmoid(seA[0] @ W_eval + b_eval)
  if (tid < 64) {
    const char* seA_b = smem + OFF_SEA;
    uint2 u = *(const uint2*)(seA_b + tid * 8);
    float4 w4 = *(const float4*)&W_eval[tid * 4];
    float s = b2f(u.x & 0xffff) * w4.x + b2f(u.x >> 16) * w4.y +
              b2f(u.y & 0xffff) * w4.z + b2f(u.y >> 16) * w4.w;
    s = warp_reduce_sum64(s);
    if (tid == 0) out[b * 64 + c] = 1.0f / (1.0f + expf(-(s + b_eval[0])));
  }
}

extern "C" void kernel_launch(void* const* d_in, const int* in_sizes, int n_in,
                              void* d_out, int out_size, void* d_ws, size_t ws_size,
                              hipStream_t stream) {
  (void)in_sizes; (void)n_in; (void)out_size; (void)ws_size;
  const float* img = (const float*)d_in[0];
  const float* cap = (const float*)d_in[1];
  const float* vG_Wl = (const float*)d_in[3];
  const float* vG_bl = (const float*)d_in[4];
  const float* vG_Wg = (const float*)d_in[5];
  const float* vG_bg = (const float*)d_in[6];
  const float* vG_Wc = (const float*)d_in[7];
  const float* vG_bc = (const float*)d_in[8];
  const float* tG_Wl = (const float*)d_in[9];
  const float* tG_bl = (const float*)d_in[10];
  const float* tG_Wg = (const float*)d_in[11];
  const float* tG_bg = (const float*)d_in[12];
  const float* tG_Wc = (const float*)d_in[13];
  const float* tG_bc = (const float*)d_in[14];
  const float* W_loc = (const float*)d_in[15];
  const float* b_loc = (const float*)d_in[16];
  const float* W_glo = (const float*)d_in[17];
  const float* b_glo = (const float*)d_in[18];
  const float* W_eval = (const float*)d_in[19];
  const float* b_eval = (const float*)d_in[20];
  const float* sgr_Wq = (const float*)d_in[21];
  const float* sgr_bq = (const float*)d_in[22];
  const float* sgr_Wk = (const float*)d_in[23];
  const float* sgr_Wg = (const float*)d_in[25];
  const float* sgr_bg = (const float*)d_in[26];
  float* out = (float*)d_out;
  float* ws = (float*)d_ws;
  float* img_avg = ws;
  float* cap_avg = ws + 65536;
  float* h_img = ws + 131072;
  float* h_cap = ws + 196608;
  float* part_img = ws + 262144;
  float* part_cap = ws + 462848;
  float* img_glob = ws + 495616;
  float* cap_glob = ws + 561152;
  float* simglo = ws + 626688;
  float* wkbqv = ws + 1675264;
  // bf16 region (u16 units) starts at float offset 1676032 (16B aligned)
  unsigned short* ub = (unsigned short*)(ws + 1676032);
  unsigned short* mt_bf = ub;                   // 196608
  unsigned short* wgT_bf = ub + 196608;         // 196608 -> 393216
  unsigned short* wlocT_bf = ub + 393216;       // 262144 -> 655360
  unsigned short* cap_bf = ub + 655360;         // 2097152 -> 2752512
  unsigned short* gram_bf = ub + 2752512;       // 2981888 -> 5734400
  unsigned short* imgT_bf = ub + 5734400;       // 14680064 -> 20414464
  unsigned short* img_bf = ub + 20414464;       // 12845056 -> 33259520
  unsigned short* wlT_v = ub + 33259520;        // 1048576 -> 34308096
  unsigned short* wlT_t = ub + 34308096;        // 1048576 -> 35356672

  k_avg<<<128, 256, 0, stream>>>(img, cap, img_avg, cap_avg);
  k_hvec<<<256, 256, 0, stream>>>(img_avg, vG_Wg, vG_bg, vG_Wc, h_img);
  k_hvec<<<256, 256, 0, stream>>>(cap_avg, tG_Wg, tG_bg, tG_Wc, h_cap);
  k_imgprep<<<dim3(32, 7, 64), 256, 0, stream>>>(img, img_bf, imgT_bf);
  k_castb<<<2048, 256, 0, stream>>>(cap, cap_bf, 524288);
  k_tcast<<<dim3(32, 32, 1), 256, 0, stream>>>(vG_Wl, wlT_v, 1024, 1024, 0, 0);
  k_tcast<<<dim3(32, 32, 1), 256, 0, stream>>>(tG_Wl, wlT_t, 1024, 1024, 0, 0);
  k_logits_mfma<<<dim3(196, 16), 256, 0, stream>>>(img_bf, TT, wlT_v, vG_bl, h_img, part_img);
  k_logits_mfma<<<dim3(32, 16), 256, 0, stream>>>(cap_bf, CL, wlT_t, tG_bl, h_cap, part_cap);
  k_finish_global<<<64, 256, 0, stream>>>(part_img, vG_bc, img + DD, (long)NTOK * DD, TT,
                                          img_glob);
  k_finish_global<<<64, 256, 0, stream>>>(part_cap, tG_bc, cap, (long)CL * DD, CL, cap_glob);
  k_simglo<<<256, 256, 0, stream>>>(img_glob, cap_glob, W_glo, b_glo, simglo);
  k_mmatb<<<48, 256, 0, stream>>>(sgr_Wk, sgr_Wq, mt_bf);  // MT = Wk@Wq^T = (Wq@Wk^T)^T
  k_wkbq<<<3, 256, 0, stream>>>(sgr_Wk, sgr_bq, wkbqv);
  k_gram_mfma<<<dim3(64, 4, 4), 256, 0, stream>>>(img_bf, gram_bf);
  k_tcast<<<dim3(8, 8, 3), 256, 0, stream>>>(sgr_Wg, wgT_bf, 256, 256, 65536, 65536);
  k_tcast<<<dim3(8, 32, 1), 256, 0, stream>>>(W_loc, wlocT_bf, 1024, 256, 0, 0);
  hipFuncSetAttribute((const void*)k_pair, hipFuncAttributeMaxDynamicSharedMemorySize,
                      SMEM_BYTES);
  k_pair<<<4096, 256, SMEM_BYTES, stream>>>(b_loc, simglo, wkbqv, sgr_bg, W_eval, b_eval,
                                            cap_bf, img_bf, imgT_bf, gram_bf, wlocT_bf,
                                            mt_bf, wgT_bf, out);
}

// Round 8
// 1825.520 us; speedup vs baseline: 12.6729x; 1.0696x over previous
//
#include <hip/hip_runtime.h>
#include <hip/hip_bf16.h>
#include <math.h>

#define NI 64
#define NC 64
#define NTOK 197
#define TT 196
#define CL 32
#define DD 1024
#define SS 256
#define NN 33
#define EPSN 1e-12f
#define SMOOTHF 9.0f
#define TP 224   // padded token dim for MFMA K

typedef __attribute__((ext_vector_type(8))) short bfrag;
typedef __attribute__((ext_vector_type(4))) float f32x4;
#define MFMA(a, b, c) __builtin_amdgcn_mfma_f32_16x16x32_bf16((a), (b), (c), 0, 0, 0)

// LDS layout (byte offsets) — phase A/W region (dead before SGR)
#define OFF_ATTNT  0        // [32][232] u16 = 14848
#define OFF_WTILE  14848    // [32][136] u16 = 8704 -> 23552
#define OFF_WMAX   23552    // [4][32] f32 = 512 -> 24064
#define OFF_NRMS   24064    // [32] f32 -> 24192
// assembly-time buffers: overlap SGR-only region (dead once SGR starts)
#define OFF_QN     25344    // [128] f32 -> 25856
#define OFF_RNQ    25856    // [32] f32 -> 25984
// SGR overlays
#define OFF_SEA    0        // [48][264] u16 = 25344
#define OFF_EB     25344    // rows 0..32 x 144B = 4752; MFMA reads rows to 47 (alias into R1 head,
                            // garbage only feeds discarded output cols n>=33)
#define OFF_R1     30096    // Gc 48*144=6912 / XT 64*144=9216 / Ef 33*34*4=4488 -> 39312
#define OFF_WKQ    37008    // [256] f32 = 1024 -> 38032 (R1 tail; coexists with Gc only)
#define OFF_VBUF   38032    // [36] f32 = 144 -> 38176 (ditto)
#define SMEM_BYTES 39312

__device__ __forceinline__ float warp_reduce_sum64(float v) {
#pragma unroll
  for (int m = 32; m > 0; m >>= 1) v += __shfl_xor(v, m, 64);
  return v;
}
__device__ __forceinline__ unsigned short f2b(float f) {
  __hip_bfloat16 h = __float2bfloat16(f);
  return *reinterpret_cast<unsigned short*>(&h);
}
__device__ __forceinline__ float b2f(unsigned short u) {
  union { unsigned int i; float f; } v;
  v.i = ((unsigned int)u) << 16;
  return v.f;
}

// ---------------------------------------------------------------- K1: means
__global__ void k_avg(const float* __restrict__ img, const float* __restrict__ cap,
                      float* __restrict__ img_avg, float* __restrict__ cap_avg) {
  int bid = blockIdx.x;
  int tid = threadIdx.x;
  if (bid < NI) {
    int b = bid;
    for (int d = tid; d < DD; d += 256) {
      float acc = 0.f;
      const float* p = img + ((size_t)b * NTOK + 1) * DD + d;
      for (int t = 0; t < TT; ++t) acc += p[(size_t)t * DD];
      img_avg[b * DD + d] = acc * (1.0f / TT);
    }
  } else {
    int c = bid - NI;
    for (int d = tid; d < DD; d += 256) {
      float acc = 0.f;
      const float* p = cap + (size_t)c * CL * DD + d;
      for (int t = 0; t < CL; ++t) acc += p[(size_t)t * DD];
      cap_avg[c * DD + d] = acc * (1.0f / CL);
    }
  }
}

// ------------------------------------------------- K2: h = tanh(avg@Wg+bg)*Wc
__global__ void k_hvec(const float* __restrict__ avg, const float* __restrict__ Wg,
                       const float* __restrict__ bg, const float* __restrict__ Wc,
                       float* __restrict__ h) {
  __shared__ float av[DD];
  int b = blockIdx.x >> 2;
  int dc = blockIdx.x & 3;
  int tid = threadIdx.x;
  for (int i = tid; i < DD; i += 256) av[i] = avg[b * DD + i];
  __syncthreads();
  int d = dc * 256 + tid;
  float acc = 0.f;
  for (int k = 0; k < DD; k += 4) {
    float4 a4 = *(const float4*)&av[k];
    acc += a4.x * Wg[(size_t)(k + 0) * DD + d];
    acc += a4.y * Wg[(size_t)(k + 1) * DD + d];
    acc += a4.z * Wg[(size_t)(k + 2) * DD + d];
    acc += a4.w * Wg[(size_t)(k + 3) * DD + d];
  }
  h[b * DD + d] = tanhf(acc + bg[d]) * Wc[d];
}

// ---------------- K3 (MFMA, merged img+cap): partial logits
__global__ void k_logits2(const unsigned short* __restrict__ Ai, const unsigned short* __restrict__ Wi,
                          const float* __restrict__ bli, const float* __restrict__ hi,
                          float* __restrict__ pi,
                          const unsigned short* __restrict__ Ac, const unsigned short* __restrict__ Wc2,
                          const float* __restrict__ blc, const float* __restrict__ hc,
                          float* __restrict__ pc) {
  int tid = threadIdx.x;
  int lane = tid & 63, w = tid >> 6;
  int lrow = lane & 15, lk = (lane >> 4) * 8, rsub = (lane >> 4) * 4;
  int bx = blockIdx.x;
  const unsigned short* Abf;
  const unsigned short* WT;
  const float* bl;
  const float* h;
  float* partial;
  int rb, rowsPerBatch;
  if (bx < 196) {
    Abf = Ai; WT = Wi; bl = bli; h = hi; partial = pi; rb = bx * 64; rowsPerBatch = TT;
  } else {
    Abf = Ac; WT = Wc2; bl = blc; h = hc; partial = pc; rb = (bx - 196) * 64; rowsPerBatch = CL;
  }
  int c0 = blockIdx.y * 64;
  const unsigned short* ap = Abf + (size_t)(rb + w * 16 + lrow) * DD;
  f32x4 acc[4] = {};
  for (int k0 = 0; k0 < DD; k0 += 32) {
    bfrag a = *(const bfrag*)(ap + k0 + lk);
#pragma unroll
    for (int i = 0; i < 4; ++i) {
      bfrag bb = *(const bfrag*)(WT + (size_t)(c0 + i * 16 + lrow) * DD + k0 + lk);
      acc[i] = MFMA(a, bb, acc[i]);
    }
  }
#pragma unroll
  for (int r = 0; r < 4; ++r) {
    int row = rb + w * 16 + rsub + r;
    int bb2 = row / rowsPerBatch;
    float s = 0.f;
#pragma unroll
    for (int i = 0; i < 4; ++i) {
      int col = c0 + i * 16 + lrow;
      s += tanhf(acc[i][r] + bl[col]) * h[bb2 * DD + col];
    }
    s += __shfl_xor(s, 1, 64);
    s += __shfl_xor(s, 2, 64);
    s += __shfl_xor(s, 4, 64);
    s += __shfl_xor(s, 8, 64);
    if (lrow == 0) partial[(size_t)row * 16 + blockIdx.y] = s;
  }
}

// -------- K4 (merged img+cap): finish global attention pooling
__global__ void k_finish2(const float* __restrict__ pi, const float* __restrict__ bci,
                          const float* __restrict__ Xi, long bsi, int Ri, float* __restrict__ oi,
                          const float* __restrict__ pc, const float* __restrict__ bcc,
                          const float* __restrict__ Xc, long bsc, int Rc, float* __restrict__ oc) {
  __shared__ float w[200];
  __shared__ float red[8];
  int bid = blockIdx.x, tid = threadIdx.x;
  const float* partial;
  const float* bc;
  const float* Xbase;
  long batchStride;
  int R, b;
  float* outG;
  if (bid < 64) {
    partial = pi; bc = bci; Xbase = Xi; batchStride = bsi; R = Ri; outG = oi; b = bid;
  } else {
    partial = pc; bc = bcc; Xbase = Xc; batchStride = bsc; R = Rc; outG = oc; b = bid - 64;
  }
  for (int t = tid; t < R; t += 256) {
    const float* pp = &partial[((size_t)b * R + t) * 16];
    float s = bc[0];
#pragma unroll
    for (int u = 0; u < 16; ++u) s += pp[u];
    w[t] = s;
  }
  __syncthreads();
  float m = -1e30f;
  for (int t = tid; t < R; t += 256) m = fmaxf(m, w[t]);
#pragma unroll
  for (int mm = 32; mm; mm >>= 1) m = fmaxf(m, __shfl_xor(m, mm, 64));
  if ((tid & 63) == 0) red[tid >> 6] = m;
  __syncthreads();
  m = fmaxf(fmaxf(red[0], red[1]), fmaxf(red[2], red[3]));
  __syncthreads();
  for (int t = tid; t < R; t += 256) w[t] = expf(w[t] - m);
  __syncthreads();
  const float* xb = Xbase + (size_t)b * batchStride;
  float acc[4];
  float ss = 0.f;
#pragma unroll
  for (int c4 = 0; c4 < 4; ++c4) {
    int d = tid + c4 * 256;
    float a = 0.f;
    for (int t = 0; t < R; ++t) a += w[t] * xb[(size_t)t * DD + d];
    acc[c4] = a;
    ss += a * a;
  }
  ss = warp_reduce_sum64(ss);
  if ((tid & 63) == 0) red[tid >> 6] = ss;
  __syncthreads();
  ss = red[0] + red[1] + red[2] + red[3];
  float rn = 1.0f / fmaxf(sqrtf(ss), EPSN);
#pragma unroll
  for (int c4 = 0; c4 < 4; ++c4) outG[(size_t)b * DD + tid + c4 * 256] = acc[c4] * rn;
}

// -------- K5: sim_glo
__global__ void k_simglo(const float* __restrict__ ig, const float* __restrict__ cg,
                         const float* __restrict__ W, const float* __restrict__ bgl,
                         float* __restrict__ simglo) {
  __shared__ float a_lds[32][20];
  __shared__ float b_lds[32][260];
  int tid = threadIdx.x;
  int p0 = blockIdx.x * 16;
  int ty = tid >> 6, tx = tid & 63;
  int s_rr = tid >> 3, s_kq = tid & 7;
  float acc[4][4] = {};
  for (int k0 = 0; k0 < DD; k0 += 32) {
    float d2[4] = {};
    if (tid < 128) {
      int p = p0 + s_rr;
      int b = p >> 6, c = p & 63;
      float4 giv = *(const float4*)&ig[b * DD + k0 + s_kq * 4];
      float4 cgv = *(const float4*)&cg[c * DD + k0 + s_kq * 4];
      float dx = giv.x - cgv.x, dy = giv.y - cgv.y, dz = giv.z - cgv.z, dw = giv.w - cgv.w;
      d2[0] = dx * dx; d2[1] = dy * dy; d2[2] = dz * dz; d2[3] = dw * dw;
    }
    float4 wv[8];
#pragma unroll
    for (int u = 0; u < 8; ++u)
      wv[u] = *(const float4*)&W[(size_t)(k0 + s_rr) * SS + s_kq * 32 + u * 4];
    __syncthreads();
    if (tid < 128) {
#pragma unroll
      for (int u = 0; u < 4; ++u) a_lds[s_kq * 4 + u][s_rr] = d2[u];
    }
#pragma unroll
    for (int u = 0; u < 8; ++u)
      *(float4*)&b_lds[s_rr][s_kq * 32 + u * 4] = wv[u];
    __syncthreads();
#pragma unroll
    for (int kk = 0; kk < 32; ++kk) {
      float4 a4 = *(const float4*)&a_lds[kk][ty * 4];
      float4 b4 = *(const float4*)&b_lds[kk][tx * 4];
      float av[4] = {a4.x, a4.y, a4.z, a4.w};
      float bv[4] = {b4.x, b4.y, b4.z, b4.w};
#pragma unroll
      for (int i = 0; i < 4; ++i)
#pragma unroll
        for (int j = 0; j < 4; ++j) acc[i][j] += av[i] * bv[j];
    }
  }
#pragma unroll
  for (int i = 0; i < 4; ++i) {
    float v[4];
    float ssq = 0.f;
#pragma unroll
    for (int j = 0; j < 4; ++j) {
      v[j] = acc[i][j] + bgl[tx * 4 + j];
      ssq += v[j] * v[j];
    }
    ssq = warp_reduce_sum64(ssq);
    float rn = 1.0f / fmaxf(sqrtf(ssq), EPSN);
    int p = p0 + ty * 4 + i;
    *(float4*)&simglo[(size_t)p * SS + tx * 4] =
        make_float4(v[0] * rn, v[1] * rn, v[2] * rn, v[3] * rn);
  }
}

// -------- K6: MT_bf16[t] = A_t @ B_t^T (256x256), bf16 out.
__global__ void k_mmatb(const float* __restrict__ Wa, const float* __restrict__ Wb,
                        unsigned short* __restrict__ M) {
  __shared__ float a_lds[32][68];
  __shared__ float b_lds[32][68];
  int tid = threadIdx.x;
  int t = blockIdx.x >> 4;
  int dt = (blockIdx.x >> 2) & 3, et = blockIdx.x & 3;
  int d0 = dt * 64, e0 = et * 64;
  const float* wq = Wa + (size_t)t * SS * SS;
  const float* wk = Wb + (size_t)t * SS * SS;
  int ty = tid >> 4, tx = tid & 15;
  int s_rr = tid >> 2, s_kq = tid & 3;
  float acc[4][4] = {};
  for (int j0 = 0; j0 < SS; j0 += 32) {
    float4 q0 = *(const float4*)&wq[(size_t)(d0 + s_rr) * SS + j0 + s_kq * 8];
    float4 q1 = *(const float4*)&wq[(size_t)(d0 + s_rr) * SS + j0 + s_kq * 8 + 4];
    float4 k0v = *(const float4*)&wk[(size_t)(e0 + s_rr) * SS + j0 + s_kq * 8];
    float4 k1v = *(const float4*)&wk[(size_t)(e0 + s_rr) * SS + j0 + s_kq * 8 + 4];
    __syncthreads();
    float qa[8] = {q0.x, q0.y, q0.z, q0.w, q1.x, q1.y, q1.z, q1.w};
    float ka[8] = {k0v.x, k0v.y, k0v.z, k0v.w, k1v.x, k1v.y, k1v.z, k1v.w};
#pragma unroll
    for (int u = 0; u < 8; ++u) {
      a_lds[s_kq * 8 + u][s_rr] = qa[u];
      b_lds[s_kq * 8 + u][s_rr] = ka[u];
    }
    __syncthreads();
#pragma unroll
    for (int kk = 0; kk < 32; ++kk) {
      float4 a4 = *(const float4*)&a_lds[kk][ty * 4];
      float4 b4 = *(const float4*)&b_lds[kk][tx * 4];
      float av[4] = {a4.x, a4.y, a4.z, a4.w};
      float bv[4] = {b4.x, b4.y, b4.z, b4.w};
#pragma unroll
      for (int i = 0; i < 4; ++i)
#pragma unroll
        for (int j = 0; j < 4; ++j) acc[i][j] += av[i] * bv[j];
    }
  }
#pragma unroll
  for (int i = 0; i < 4; ++i) {
    unsigned int lo = (unsigned int)f2b(acc[i][0]) | ((unsigned int)f2b(acc[i][1]) << 16);
    unsigned int hi = (unsigned int)f2b(acc[i][2]) | ((unsigned int)f2b(acc[i][3]) << 16);
    uint2 o = make_uint2(lo, hi);
    *(uint2*)(M + (size_t)t * SS * SS + (size_t)(d0 + ty * 4 + i) * SS + e0 + tx * 4) = o;
  }
}

// -------- K6b: wkbq[t] = Wk_t @ bq_t
__global__ void k_wkbq(const float* __restrict__ Wk, const float* __restrict__ bq,
                       float* __restrict__ out) {
  __shared__ float bv[SS];
  int t = blockIdx.x, tid = threadIdx.x;
  const float* wk = Wk + (size_t)t * SS * SS;
  bv[tid] = bq[t * SS + tid];
  __syncthreads();
  float acc = 0.f;
  for (int j = 0; j < SS; j += 4) {
    float4 wv = *(const float4*)&wk[(size_t)tid * SS + j];
    float4 b4 = *(const float4*)&bv[j];
    acc += wv.x * b4.x + wv.y * b4.y + wv.z * b4.z + wv.w * b4.w;
  }
  out[t * SS + tid] = acc;
}

// -------- fused img prep: row-major bf16 + transposed padded bf16 (one img read)
__global__ void k_imgprep(const float* __restrict__ img, unsigned short* __restrict__ row_bf,
                          unsigned short* __restrict__ tr_bf) {
  __shared__ float t[32][33];
  int b = blockIdx.z;
  int t0 = blockIdx.y * 32, d0 = blockIdx.x * 32;
  int tx = threadIdx.x & 31, ty = threadIdx.x >> 5;
#pragma unroll
  for (int u = 0; u < 4; ++u) {
    int tt = t0 + ty + u * 8;
    float v = (tt < TT) ? img[((size_t)b * NTOK + 1 + tt) * DD + d0 + tx] : 0.f;
    t[ty + u * 8][tx] = v;
    if (tt < TT) row_bf[((size_t)b * TT + tt) * DD + d0 + tx] = f2b(v);
  }
  __syncthreads();
#pragma unroll
  for (int u = 0; u < 4; ++u)
    tr_bf[((size_t)b * DD + d0 + ty + u * 8) * TP + t0 + tx] = f2b(t[tx][ty + u * 8]);
}

// -------- K6c (MFMA): gram_bf16[b] = imgTok_b @ imgTok_b^T in [208][224] zero-padded
__global__ void k_gram_mfma(const unsigned short* __restrict__ img_bf,
                            unsigned short* __restrict__ gram) {
  int tid = threadIdx.x;
  int lane = tid & 63, w = tid >> 6;
  int lrow = lane & 15, lk = (lane >> 4) * 8, rsub = (lane >> 4) * 4;
  int bimg = blockIdx.x;
  int rb = blockIdx.y * 64, cb = blockIdx.z * 64;
  const unsigned short* X = img_bf + (size_t)bimg * TT * DD;
  int ra = rb + w * 16 + lrow;
  if (ra > TT - 1) ra = TT - 1;
  f32x4 acc[4] = {};
  for (int k0 = 0; k0 < DD; k0 += 32) {
    bfrag a = *(const bfrag*)(X + (size_t)ra * DD + k0 + lk);
#pragma unroll
    for (int i = 0; i < 4; ++i) {
      int cc = cb + i * 16 + lrow;
      if (cc > TT - 1) cc = TT - 1;
      bfrag bb = *(const bfrag*)(X + (size_t)cc * DD + k0 + lk);
      acc[i] = MFMA(a, bb, acc[i]);
    }
  }
  unsigned short* Gp = gram + (size_t)bimg * 208 * TP;
#pragma unroll
  for (int i = 0; i < 4; ++i) {
    int cc = cb + i * 16 + lrow;
#pragma unroll
    for (int r = 0; r < 4; ++r) {
      int rr = rb + w * 16 + rsub + r;
      if (rr < 208 && cc < TP)
        Gp[(size_t)rr * TP + cc] = (rr < TT && cc < TT) ? f2b(acc[i][r]) : 0;
    }
  }
}

// -------- cast f32 -> bf16 (same layout)
__global__ void k_castb(const float* __restrict__ s, unsigned short* __restrict__ d, int n4) {
  int i = blockIdx.x * 256 + threadIdx.x;
  if (i < n4) {
    float4 v = *(const float4*)(s + (size_t)i * 4);
    uint2 o;
    o.x = (unsigned int)f2b(v.x) | ((unsigned int)f2b(v.y) << 16);
    o.y = (unsigned int)f2b(v.z) | ((unsigned int)f2b(v.w) << 16);
    *(uint2*)(d + (size_t)i * 4) = o;
  }
}

// -------- transpose-cast: src[R][C] f32 -> dst[C][R] bf16 (batched via z)
__global__ void k_tcast(const float* __restrict__ src, unsigned short* __restrict__ dst,
                        int R, int C, long sB, long dB) {
  __shared__ float t[32][33];
  const float* s = src + (size_t)blockIdx.z * sB;
  unsigned short* d = dst + (size_t)blockIdx.z * dB;
  int r0 = blockIdx.y * 32, c0 = blockIdx.x * 32;
  int tx = threadIdx.x & 31, ty = threadIdx.x >> 5;
#pragma unroll
  for (int u = 0; u < 4; ++u)
    t[ty + u * 8][tx] = s[(size_t)(r0 + ty + u * 8) * C + c0 + tx];
  __syncthreads();
#pragma unroll
  for (int u = 0; u < 4; ++u)
    d[(size_t)(c0 + ty + u * 8) * R + r0 + tx] = f2b(t[tx][ty + u * 8]);
}

// -------- K7: per-(img,cap) pair mega kernel (v8: 39.3KB LDS -> 4 blocks/CU)
__global__ __launch_bounds__(256, 4) void k_pair(
    const float* __restrict__ b_loc, const float* __restrict__ simglo,
    const float* __restrict__ wkbq, const float* __restrict__ bg3,
    const float* __restrict__ W_eval, const float* __restrict__ b_eval,
    const unsigned short* __restrict__ cap_bf, const unsigned short* __restrict__ img_bf,
    const unsigned short* __restrict__ imgT_bf, const unsigned short* __restrict__ gram_bf,
    const unsigned short* __restrict__ wlocT_bf, const unsigned short* __restrict__ mt_bf,
    const unsigned short* __restrict__ wgT_bf, float* __restrict__ out) {
  extern __shared__ char smem[];

  int tid = threadIdx.x;
  int lane = tid & 63, w = tid >> 6;
  int lrow = lane & 15;        // MFMA row/col select
  int lk = (lane >> 4) * 8;    // MFMA k-offset
  int rsub = (lane >> 4) * 4;  // D-frag row base
  int p = blockIdx.x;
  int b = p >> 6, c = p & 63;
  const unsigned short* imgR = img_bf + (size_t)b * TT * DD;
  const unsigned short* capB = cap_bf + (size_t)c * CL * DD;
  char* attnT_b = smem + OFF_ATTNT;

  // ================ Phase A: S = leaky(imgTok.cap) MFMA; epilogue in registers
  {
    f32x4 acc[4][2] = {};
    for (int k0 = 0; k0 < DD; k0 += 32) {
      bfrag bq0 = *(const bfrag*)(capB + (size_t)lrow * DD + k0 + lk);
      bfrag bq1 = *(const bfrag*)(capB + (size_t)(16 + lrow) * DD + k0 + lk);
#pragma unroll
      for (int i = 0; i < 4; ++i) {
        int tt = w + 4 * i;
        if (tt < 13) {
          int t = tt * 16 + lrow;
          bfrag a = {0, 0, 0, 0, 0, 0, 0, 0};
          if (t < TT) a = *(const bfrag*)(imgR + (size_t)t * DD + k0 + lk);
          acc[i][0] = MFMA(a, bq0, acc[i][0]);
          acc[i][1] = MFMA(a, bq1, acc[i][1]);
        }
      }
    }
    // leaky + l2norm over q (16-lane butterfly within g-group) + running max over t
    float mx0 = -1e30f, mx1 = -1e30f;
#pragma unroll
    for (int i = 0; i < 4; ++i) {
      int tt = w + 4 * i;
      if (tt < 13) {
#pragma unroll
        for (int r = 0; r < 4; ++r) {
          int t = tt * 16 + rsub + r;
          float v0 = acc[i][0][r];
          v0 = v0 < 0.f ? 0.1f * v0 : v0;
          float v1 = acc[i][1][r];
          v1 = v1 < 0.f ? 0.1f * v1 : v1;
          float s2 = v0 * v0 + v1 * v1;
          s2 += __shfl_xor(s2, 1, 64);
          s2 += __shfl_xor(s2, 2, 64);
          s2 += __shfl_xor(s2, 4, 64);
          s2 += __shfl_xor(s2, 8, 64);
          float rn = 1.0f / fmaxf(sqrtf(s2), EPSN);
          v0 *= rn;
          v1 *= rn;
          acc[i][0][r] = v0;
          acc[i][1][r] = v1;
          if (t < TT) {
            mx0 = fmaxf(mx0, v0);
            mx1 = fmaxf(mx1, v1);
          }
        }
      }
    }
    mx0 = fmaxf(mx0, __shfl_xor(mx0, 16, 64));
    mx0 = fmaxf(mx0, __shfl_xor(mx0, 32, 64));
    mx1 = fmaxf(mx1, __shfl_xor(mx1, 16, 64));
    mx1 = fmaxf(mx1, __shfl_xor(mx1, 32, 64));
    float* wmax = (float*)(smem + OFF_WMAX);
    if ((lane >> 4) == 0) {
      wmax[w * 32 + lrow] = mx0;
      wmax[w * 32 + 16 + lrow] = mx1;
    }
    __syncthreads();
    mx0 = fmaxf(fmaxf(wmax[lrow], wmax[32 + lrow]), fmaxf(wmax[64 + lrow], wmax[96 + lrow]));
    mx1 = fmaxf(fmaxf(wmax[16 + lrow], wmax[48 + lrow]),
                fmaxf(wmax[80 + lrow], wmax[112 + lrow]));
    // exp (denominator dropped; exact since ctx l2-normalized) -> attnT bf16 [32][232]
#pragma unroll
    for (int i = 0; i < 4; ++i) {
      int tt = w + 4 * i;
#pragma unroll
      for (int r = 0; r < 4; ++r) {
        int t = tt * 16 + rsub + r;
        if (t < TP) {
          unsigned short e0 = 0, e1 = 0;
          if (t < TT) {
            e0 = f2b(expf(SMOOTHF * (acc[i][0][r] - mx0)));
            e1 = f2b(expf(SMOOTHF * (acc[i][1][r] - mx1)));
          }
          *(unsigned short*)(attnT_b + lrow * 464 + t * 2) = e0;
          *(unsigned short*)(attnT_b + (16 + lrow) * 464 + t * 2) = e1;
        }
      }
    }
  }
  __syncthreads();

  // ================ norm via Gram (MFMA): Y = G@E, norm2[q] = sum_t w[t][q]*Y[t][q]
  {
    float* qn = (float*)(smem + OFF_QN);
    float* nrmS = (float*)(smem + OFF_NRMS);
    const unsigned short* gb = gram_bf + (size_t)b * 208 * TP;
    float part0 = 0.f, part1 = 0.f;
#pragma unroll
    for (int i = 0; i < 4; ++i) {
      int tt = w + 4 * i;
      if (tt < 13) {
        f32x4 y0 = {0.f, 0.f, 0.f, 0.f}, y1 = {0.f, 0.f, 0.f, 0.f};
        for (int t0 = 0; t0 < TP; t0 += 32) {
          bfrag a = *(const bfrag*)(gb + (size_t)(tt * 16 + lrow) * TP + t0 + lk);
          bfrag b0 = *(const bfrag*)(attnT_b + lrow * 464 + (t0 + lk) * 2);
          bfrag b1 = *(const bfrag*)(attnT_b + (16 + lrow) * 464 + (t0 + lk) * 2);
          y0 = MFMA(a, b0, y0);
          y1 = MFMA(a, b1, y1);
        }
#pragma unroll
        for (int r = 0; r < 4; ++r) {
          int t = tt * 16 + rsub + r;
          if (t < TT) {
            part0 += y0[r] * b2f(*(const unsigned short*)(attnT_b + lrow * 464 + t * 2));
            part1 += y1[r] * b2f(*(const unsigned short*)(attnT_b + (16 + lrow) * 464 + t * 2));
          }
        }
      }
    }
    part0 += __shfl_xor(part0, 16, 64);
    part0 += __shfl_xor(part0, 32, 64);
    part1 += __shfl_xor(part1, 16, 64);
    part1 += __shfl_xor(part1, 32, 64);
    if ((lane >> 4) == 0) {
      qn[w * 32 + lrow] = part0;
      qn[w * 32 + 16 + lrow] = part1;
    }
    __syncthreads();
    if (tid < 32)
      nrmS[tid] = 1.0f / fmaxf(sqrtf(qn[tid] + qn[32 + tid] + qn[64 + tid] + qn[96 + tid]), EPSN);
    __syncthreads();
  }

  // ================ Phase W: ctx (MFMA) -> diff^2 -> @W_loc (MFMA)
  f32x4 accW[2][4] = {};
  {
    char* wtile_b = smem + OFF_WTILE;
    float* nrmS = (float*)(smem + OFF_NRMS);
    float nrm0 = nrmS[lrow], nrm1 = nrmS[16 + lrow];
    for (int d0 = 0; d0 < DD; d0 += 128) {
      f32x4 c2[2][2] = {};
      for (int t0 = 0; t0 < TP; t0 += 32) {
        bfrag b0 = *(const bfrag*)(attnT_b + lrow * 464 + (t0 + lk) * 2);
        bfrag b1 = *(const bfrag*)(attnT_b + (16 + lrow) * 464 + (t0 + lk) * 2);
#pragma unroll
        for (int i = 0; i < 2; ++i) {
          int dt = w + 4 * i;
          bfrag a = *(const bfrag*)(imgT_bf + ((size_t)b * DD + d0 + dt * 16 + lrow) * TP + t0 + lk);
          c2[i][0] = MFMA(a, b0, c2[i][0]);
          c2[i][1] = MFMA(a, b1, c2[i][1]);
        }
      }
      __syncthreads();  // prev W_loc readers of wtile done
#pragma unroll
      for (int i = 0; i < 2; ++i) {
        int dl = (w + 4 * i) * 16 + rsub;
#pragma unroll
        for (int qt = 0; qt < 2; ++qt) {
          int q = qt * 16 + lrow;
          uint2 cu = *(const uint2*)(capB + (size_t)q * DD + d0 + dl);
          float cf0 = b2f(cu.x & 0xffff), cf1 = b2f(cu.x >> 16);
          float cf2 = b2f(cu.y & 0xffff), cf3 = b2f(cu.y >> 16);
          float rn = qt ? nrm1 : nrm0;
          float v0 = c2[i][qt][0] * rn - cf0;
          float v1 = c2[i][qt][1] * rn - cf1;
          float v2 = c2[i][qt][2] * rn - cf2;
          float v3 = c2[i][qt][3] * rn - cf3;
          unsigned int lo = (unsigned int)f2b(v0 * v0) | ((unsigned int)f2b(v1 * v1) << 16);
          unsigned int hi = (unsigned int)f2b(v2 * v2) | ((unsigned int)f2b(v3 * v3) << 16);
          *(uint2*)(wtile_b + q * 272 + dl * 2) = make_uint2(lo, hi);
        }
      }
      __syncthreads();
      for (int kc = 0; kc < 4; ++kc) {
        bfrag a0 = *(const bfrag*)(wtile_b + lrow * 272 + (kc * 32 + lk) * 2);
        bfrag a1 = *(const bfrag*)(wtile_b + (16 + lrow) * 272 + (kc * 32 + lk) * 2);
#pragma unroll
        for (int sti = 0; sti < 4; ++sti) {
          int s = (w * 4 + sti) * 16 + lrow;
          bfrag bb = *(const bfrag*)(wlocT_bf + (size_t)s * DD + d0 + kc * 32 + lk);
          accW[0][sti] = MFMA(a0, bb, accW[0][sti]);
          accW[1][sti] = MFMA(a1, bb, accW[1][sti]);
        }
      }
    }
  }

  // ================ assembly: l2norm(sim_loc)+bias -> seA_bf16 rows 1..32; row 0 simglo
  {
    char* seA_b = smem + OFF_SEA;
    float* qn = (float*)(smem + OFF_QN);
    float* rnq = (float*)(smem + OFF_RNQ);
    __syncthreads();
    for (int i2 = tid; i2 < 6336; i2 += 256) ((unsigned int*)smem)[i2] = 0;  // zero seA
    __syncthreads();
    float blv[4];
#pragma unroll
    for (int sti = 0; sti < 4; ++sti) blv[sti] = b_loc[(w * 4 + sti) * 16 + lrow];
    float ss[2][4];
#pragma unroll
    for (int qt = 0; qt < 2; ++qt)
#pragma unroll
      for (int r = 0; r < 4; ++r) {
        float s2 = 0.f;
#pragma unroll
        for (int sti = 0; sti < 4; ++sti) {
          float v = accW[qt][sti][r] + blv[sti];
          s2 += v * v;
        }
        s2 += __shfl_xor(s2, 1, 64);
        s2 += __shfl_xor(s2, 2, 64);
        s2 += __shfl_xor(s2, 4, 64);
        s2 += __shfl_xor(s2, 8, 64);
        ss[qt][r] = s2;
      }
    if (lrow == 0) {
#pragma unroll
      for (int qt = 0; qt < 2; ++qt)
#pragma unroll
        for (int r = 0; r < 4; ++r)
          qn[w * 32 + qt * 16 + rsub + r] = ss[qt][r];
    }
    __syncthreads();
    if (tid < 32)
      rnq[tid] = 1.0f / fmaxf(sqrtf(qn[tid] + qn[32 + tid] + qn[64 + tid] + qn[96 + tid]), EPSN);
    __syncthreads();
#pragma unroll
    for (int qt = 0; qt < 2; ++qt)
#pragma unroll
      for (int r = 0; r < 4; ++r) {
        int q = qt * 16 + rsub + r;
        float rn = rnq[q];
#pragma unroll
        for (int sti = 0; sti < 4; ++sti) {
          int s = (w * 4 + sti) * 16 + lrow;
          float v = (accW[qt][sti][r] + blv[sti]) * rn;
          *(unsigned short*)(seA_b + (1 + q) * 528 + s * 2) = f2b(v);
        }
      }
    if (tid < 64) {
      float4 g4 = *(const float4*)&simglo[(size_t)p * SS + tid * 4];
      unsigned int lo = (unsigned int)f2b(g4.x) | ((unsigned int)f2b(g4.y) << 16);
      unsigned int hi = (unsigned int)f2b(g4.z) | ((unsigned int)f2b(g4.w) << 16);
      *(uint2*)(seA_b + tid * 8) = make_uint2(lo, hi);
    }
    __syncthreads();
  }

  // ================ SGR x3 (Eb 33 rows; pad-row reads alias R1 head -> discarded cols)
  {
    char* seA_b = smem + OFF_SEA;
    char* Gc_b = smem + OFF_R1;           // [48][144]B per e-chunk
    char* XT_b = smem + OFF_R1;           // [64][144]B per s-chunk
    float* Ef = (float*)(smem + OFF_R1);  // [33][34] f32 (after Gc dead)
    char* Eb = smem + OFF_EB;             // rows 0..32 x 144B physical
    float* wkq = (float*)(smem + OFF_WKQ);
    float* vbuf = (float*)(smem + OFF_VBUF);

    for (int step = 0; step < 3; ++step) {
      const unsigned short* mstep = mt_bf + (size_t)step * SS * SS;
      const unsigned short* wstep = wgT_bf + (size_t)step * SS * SS;
      wkq[tid] = wkbq[step * SS + tid];
      __syncthreads();
      // vbuf[m] = seA[m] . (Wk@bq)
      if (tid < 132) {
        int m = tid >> 2, qq = tid & 3;
        float a = 0.f;
        for (int e = qq * 64; e < qq * 64 + 64; e += 2) {
          unsigned int u = *(const unsigned int*)(seA_b + m * 528 + e * 2);
          a += b2f(u & 0xffff) * wkq[e] + b2f(u >> 16) * wkq[e + 1];
        }
        a += __shfl_xor(a, 1, 64);
        a += __shfl_xor(a, 2, 64);
        if (qq == 0) vbuf[m] = a;
      }
      // E = (seA@M) @ seA^T, e-chunked
      f32x4 aE[3] = {};
      for (int ec = 0; ec < 4; ++ec) {
        f32x4 aGc[3] = {};
        for (int kc = 0; kc < 8; ++kc) {
          int k = kc * 32 + lk;
          bfrag bb = *(const bfrag*)(mstep + (size_t)(ec * 64 + w * 16 + lrow) * SS + k);
#pragma unroll
          for (int mt = 0; mt < 3; ++mt) {
            bfrag af = *(const bfrag*)(seA_b + (mt * 16 + lrow) * 528 + k * 2);
            aGc[mt] = MFMA(af, bb, aGc[mt]);
          }
        }
        __syncthreads();  // prior chunk's Gc readers done
#pragma unroll
        for (int mt = 0; mt < 3; ++mt)
#pragma unroll
          for (int r = 0; r < 4; ++r)
            *(unsigned short*)(Gc_b + (mt * 16 + rsub + r) * 144 + (w * 16 + lrow) * 2) =
                f2b(aGc[mt][r]);
        __syncthreads();
#pragma unroll
        for (int kc = 0; kc < 2; ++kc) {
          int k = kc * 32 + lk;
#pragma unroll
          for (int ti = 0; ti < 3; ++ti) {
            int tile = w + ti * 4;
            if (tile < 9) {
              int mtE = tile / 3, ntE = tile - mtE * 3;
              bfrag ga = *(const bfrag*)(Gc_b + (mtE * 16 + lrow) * 144 + k * 2);
              bfrag sb = *(const bfrag*)(seA_b + (ntE * 16 + lrow) * 528 + (ec * 64 + k) * 2);
              aE[ti] = MFMA(ga, sb, aE[ti]);
            }
          }
        }
      }
      __syncthreads();  // all Gc reads done before Ef overlays it
#pragma unroll
      for (int ti = 0; ti < 3; ++ti) {
        int tile = w + ti * 4;
        if (tile < 9) {
          int mtE = tile / 3, ntE = tile - mtE * 3;
          int n0 = mtE * 16 + rsub, m = ntE * 16 + lrow;
#pragma unroll
          for (int r = 0; r < 4; ++r)
            if (n0 + r < NN && m < NN) Ef[(n0 + r) * 34 + m] = aE[ti][r] + vbuf[m];
        }
      }
      __syncthreads();
      // row softmax of E
      if (tid < NN) {
        float mx = -1e30f;
        for (int mm = 0; mm < NN; ++mm) mx = fmaxf(mx, Ef[tid * 34 + mm]);
        float sum = 0.f;
        for (int mm = 0; mm < NN; ++mm) {
          float e = expf(Ef[tid * 34 + mm] - mx);
          Ef[tid * 34 + mm] = e;
          sum += e;
        }
        float rs = 1.0f / sum;
        for (int mm = 0; mm < NN; ++mm) Ef[tid * 34 + mm] *= rs;
      }
      __syncthreads();
      // E_bf16 build: physical rows 0..32 only (reads of rows 33..47 hit R1 head,
      // producing garbage only in discarded output cols n>=33)
      for (int idx = tid; idx < 33 * 36; idx += 256) {
        int n = idx / 36, mp = (idx - n * 36) * 2;
        unsigned int lo = (mp < NN) ? (unsigned int)f2b(Ef[n * 34 + mp]) : 0u;
        unsigned int hi = (mp + 1 < NN) ? (unsigned int)f2b(Ef[n * 34 + mp + 1]) : 0u;
        *(unsigned int*)(Eb + n * 144 + mp * 2) = lo | (hi << 16);
      }
      __syncthreads();  // Eb ready; Ef dead -> XT may overlay
      // X = seA @ Wg per 64-col s-chunk; O = X^T@E^T per chunk, bias+relu+pack to regs
      unsigned int oPk[4][3][2];
#pragma unroll
      for (int sc = 0; sc < 4; ++sc) {
        f32x4 aX[3] = {};
        for (int kc = 0; kc < 8; ++kc) {
          int k = kc * 32 + lk;
          bfrag bb = *(const bfrag*)(wstep + (size_t)(sc * 64 + w * 16 + lrow) * SS + k);
#pragma unroll
          for (int mt = 0; mt < 3; ++mt) {
            bfrag af = *(const bfrag*)(seA_b + (mt * 16 + lrow) * 528 + k * 2);
            aX[mt] = MFMA(af, bb, aX[mt]);
          }
        }
        __syncthreads();  // prior chunk's XT readers done (sc=0: Eb barrier above)
#pragma unroll
        for (int mt = 0; mt < 3; ++mt) {
          unsigned int lo = (unsigned int)f2b(aX[mt][0]) | ((unsigned int)f2b(aX[mt][1]) << 16);
          unsigned int hi = (unsigned int)f2b(aX[mt][2]) | ((unsigned int)f2b(aX[mt][3]) << 16);
          *(uint2*)(XT_b + (w * 16 + lrow) * 144 + (mt * 16 + rsub) * 2) = make_uint2(lo, hi);
        }
        *(uint2*)(XT_b + (w * 16 + lrow) * 144 + (48 + rsub) * 2) = make_uint2(0, 0);
        __syncthreads();
        f32x4 aO[3] = {};
#pragma unroll
        for (int kc = 0; kc < 2; ++kc) {
          int k = kc * 32 + lk;
          bfrag xa = *(const bfrag*)(XT_b + (w * 16 + lrow) * 144 + k * 2);
#pragma unroll
          for (int nt = 0; nt < 3; ++nt) {
            bfrag eb = *(const bfrag*)(Eb + (nt * 16 + lrow) * 144 + k * 2);
            aO[nt] = MFMA(xa, eb, aO[nt]);
          }
        }
        float bga[4];
#pragma unroll
        for (int r = 0; r < 4; ++r) bga[r] = bg3[step * SS + sc * 64 + w * 16 + rsub + r];
#pragma unroll
        for (int nt = 0; nt < 3; ++nt) {
          float v0 = fmaxf(aO[nt][0] + bga[0], 0.f);
          float v1 = fmaxf(aO[nt][1] + bga[1], 0.f);
          float v2 = fmaxf(aO[nt][2] + bga[2], 0.f);
          float v3 = fmaxf(aO[nt][3] + bga[3], 0.f);
          oPk[sc][nt][0] = (unsigned int)f2b(v0) | ((unsigned int)f2b(v1) << 16);
          oPk[sc][nt][1] = (unsigned int)f2b(v2) | ((unsigned int)f2b(v3) << 16);
        }
      }
      // seA = relu(O + bg): all sc chunks' X reads of seA completed (barriers above)
#pragma unroll
      for (int sc = 0; sc < 4; ++sc)
#pragma unroll
        for (int nt = 0; nt < 3; ++nt) {
          int n = nt * 16 + lrow;
          if (n < NN)
            *(uint2*)(seA_b + n * 528 + (sc * 64 + w * 16 + rsub) * 2) =
                make_uint2(oPk[sc][nt][0], oPk[sc][nt][1]);
        }
      __syncthreads();
    }
  }

  // ================ eval: sigmoid(seA[0] @ W_eval + b_eval)
  if (tid < 64) {
    const char* seA_b = smem + OFF_SEA;
    uint2 u = *(const uint2*)(seA_b + tid * 8);
    float4 w4 = *(const float4*)&W_eval[tid * 4];
    float s = b2f(u.x & 0xffff) * w4.x + b2f(u.x >> 16) * w4.y +
              b2f(u.y & 0xffff) * w4.z + b2f(u.y >> 16) * w4.w;
    s = warp_reduce_sum64(s);
    if (tid == 0) out[b * 64 + c] = 1.0f / (1.0f + expf(-(s + b_eval[0])));
  }
}

extern "C" void kernel_launch(void* const* d_in, const int* in_sizes, int n_in,
                              void* d_out, int out_size, void* d_ws, size_t ws_size,
                              hipStream_t stream) {
  (void)in_sizes; (void)n_in; (void)out_size; (void)ws_size;
  const float* img = (const float*)d_in[0];
  const float* cap = (const float*)d_in[1];
  const float* vG_Wl = (const float*)d_in[3];
  const float* vG_bl = (const float*)d_in[4];
  const float* vG_Wg = (const float*)d_in[5];
  const float* vG_bg = (const float*)d_in[6];
  const float* vG_Wc = (const float*)d_in[7];
  const float* vG_bc = (const float*)d_in[8];
  const float* tG_Wl = (const float*)d_in[9];
  const float* tG_bl = (const float*)d_in[10];
  const float* tG_Wg = (const float*)d_in[11];
  const float* tG_bg = (const float*)d_in[12];
  const float* tG_Wc = (const float*)d_in[13];
  const float* tG_bc = (const float*)d_in[14];
  const float* W_loc = (const float*)d_in[15];
  const float* b_loc = (const float*)d_in[16];
  const float* W_glo = (const float*)d_in[17];
  const float* b_glo = (const float*)d_in[18];
  const float* W_eval = (const float*)d_in[19];
  const float* b_eval = (const float*)d_in[20];
  const float* sgr_Wq = (const float*)d_in[21];
  const float* sgr_bq = (const float*)d_in[22];
  const float* sgr_Wk = (const float*)d_in[23];
  const float* sgr_Wg = (const float*)d_in[25];
  const float* sgr_bg = (const float*)d_in[26];
  float* out = (float*)d_out;
  float* ws = (float*)d_ws;
  float* img_avg = ws;
  float* cap_avg = ws + 65536;
  float* h_img = ws + 131072;
  float* h_cap = ws + 196608;
  float* part_img = ws + 262144;
  float* part_cap = ws + 462848;
  float* img_glob = ws + 495616;
  float* cap_glob = ws + 561152;
  float* simglo = ws + 626688;
  float* wkbqv = ws + 1675264;
  // bf16 region (u16 units) starts at float offset 1676032 (16B aligned)
  unsigned short* ub = (unsigned short*)(ws + 1676032);
  unsigned short* mt_bf = ub;                   // 196608
  unsigned short* wgT_bf = ub + 196608;         // 196608 -> 393216
  unsigned short* wlocT_bf = ub + 393216;       // 262144 -> 655360
  unsigned short* cap_bf = ub + 655360;         // 2097152 -> 2752512
  unsigned short* gram_bf = ub + 2752512;       // 2981888 -> 5734400
  unsigned short* imgT_bf = ub + 5734400;       // 14680064 -> 20414464
  unsigned short* img_bf = ub + 20414464;       // 12845056 -> 33259520
  unsigned short* wlT_v = ub + 33259520;        // 1048576 -> 34308096
  unsigned short* wlT_t = ub + 34308096;        // 1048576 -> 35356672

  k_avg<<<128, 256, 0, stream>>>(img, cap, img_avg, cap_avg);
  k_hvec<<<256, 256, 0, stream>>>(img_avg, vG_Wg, vG_bg, vG_Wc, h_img);
  k_hvec<<<256, 256, 0, stream>>>(cap_avg, tG_Wg, tG_bg, tG_Wc, h_cap);
  k_imgprep<<<dim3(32, 7, 64), 256, 0, stream>>>(img, img_bf, imgT_bf);
  k_castb<<<2048, 256, 0, stream>>>(cap, cap_bf, 524288);
  k_tcast<<<dim3(32, 32, 1), 256, 0, stream>>>(vG_Wl, wlT_v, 1024, 1024, 0, 0);
  k_tcast<<<dim3(32, 32, 1), 256, 0, stream>>>(tG_Wl, wlT_t, 1024, 1024, 0, 0);
  k_logits2<<<dim3(228, 16), 256, 0, stream>>>(img_bf, wlT_v, vG_bl, h_img, part_img,
                                               cap_bf, wlT_t, tG_bl, h_cap, part_cap);
  k_finish2<<<128, 256, 0, stream>>>(part_img, vG_bc, img + DD, (long)NTOK * DD, TT, img_glob,
                                     part_cap, tG_bc, cap, (long)CL * DD, CL, cap_glob);
  k_simglo<<<256, 256, 0, stream>>>(img_glob, cap_glob, W_glo, b_glo, simglo);
  k_mmatb<<<48, 256, 0, stream>>>(sgr_Wk, sgr_Wq, mt_bf);  // MT = Wk@Wq^T = (Wq@Wk^T)^T
  k_wkbq<<<3, 256, 0, stream>>>(sgr_Wk, sgr_bq, wkbqv);
  k_gram_mfma<<<dim3(64, 4, 4), 256, 0, stream>>>(img_bf, gram_bf);
  k_tcast<<<dim3(8, 8, 3), 256, 0, stream>>>(sgr_Wg, wgT_bf, 256, 256, 65536, 65536);
  k_tcast<<<dim3(8, 32, 1), 256, 0, stream>>>(W_loc, wlocT_bf, 1024, 256, 0, 0);
  hipFuncSetAttribute((const void*)k_pair, hipFuncAttributeMaxDynamicSharedMemorySize,
                      SMEM_BYTES);
  k_pair<<<4096, 256, SMEM_BYTES, stream>>>(b_loc, simglo, wkbqv, sgr_bg, W_eval, b_eval,
                                            cap_bf, img_bf, imgT_bf, gram_bf, wlocT_bf,
                                            mt_bf, wgT_bf, out);
}